// Round 7
// baseline (867.742 us; speedup 1.0000x reference)
//
#include <hip/hip_runtime.h>
#include <hip/hip_fp16.h>
#include <math.h>

#define B_ 128
#define T_ 128
#define NF 76
#define HD 64
#define LQ 77

typedef __attribute__((ext_vector_type(8))) short short8v;
typedef __attribute__((ext_vector_type(4))) short short4v;
typedef __attribute__((ext_vector_type(4))) float f32x4;

__device__ __forceinline__ float sigmf(float x) { return 1.0f / (1.0f + __expf(-x)); }
__device__ __forceinline__ float tanh_fast(float x) { return 2.0f / (1.0f + __expf(-2.0f * x)) - 1.0f; }
__device__ __forceinline__ short tobf(float x) {
    unsigned u = __float_as_uint(x);
    u += 0x7FFF + ((u >> 16) & 1);   // RNE to bf16
    return (short)(u >> 16);
}
__device__ __forceinline__ float2 h2f2(unsigned u) {
    return __half22float2(*(__half2*)&u);
}

// ---------------------------------------------------------------------------
// K1a: GRU recurrence via MFMA. grid (16,76) = (8-batch chunk, nf), block 256
// (4 waves; wave w owns hidden channels [16w,16w+16) for all 3 gates).
// MFMA A rows 8..15 mirror rows 0..7 (quad2/3 threads duplicate quad0/1) so
// the 16x16 MFMA shape is kept with 8 batches. 1216 blocks -> ~4.75 blocks/CU.
// Streams h_t (fp16) to Hsg[nf][b][t][ch]; writes qx/qb.
// ---------------------------------------------------------------------------
__global__ __launch_bounds__(256) void k_gru0(
    const float* __restrict__ X, const float* __restrict__ Wih,
    const float* __restrict__ Whh, const float* __restrict__ bih,
    const float* __restrict__ bhh,
    const float* __restrict__ Wt, const float* __restrict__ bt,
    const float* __restrict__ Wx, const float* __restrict__ bx,
    __half* __restrict__ Hsg, float* __restrict__ qxg, float* __restrict__ qbg)
{
    __shared__ short As[2][16 * 68];      // bf16 A-frags (rows 8-15 mirror 0-7)
    __shared__ __half Hs16[2][8 * 68];    // fp16 store staging (valid rows only)
    __shared__ float xs[8 * 129];
    __shared__ float q1[8 * 65];
    __shared__ float q2[8 * 65];

    const int nf = blockIdx.y;
    const int chunk = blockIdx.x;
    const int cbase = chunk * 8;
    const int tid = threadIdx.x;
    const int w = tid >> 6;               // wave: channel slice [16w,16w+16)
    const int lane = tid & 63;
    const int col = lane & 15;
    const int quad = lane >> 4;

    for (int i = tid; i < 8 * T_; i += 256) {
        int b = i >> 7, t = i & 127;
        xs[b * 129 + t] = X[((size_t)(cbase + b) * T_ + t) * NF + nf];
    }

    short8v bfr[3][2];
    const float* wbase = Whh + (size_t)nf * 12288;
#pragma unroll
    for (int g3 = 0; g3 < 3; ++g3)
#pragma unroll
        for (int k2 = 0; k2 < 2; ++k2) {
            int g = 64 * g3 + 16 * w + col;
            const float* src = wbase + g * 64 + 32 * k2 + quad * 8;
            float4 f0 = *(const float4*)src;
            float4 f1 = *(const float4*)(src + 4);
            short8v fr;
            fr[0] = tobf(f0.x); fr[1] = tobf(f0.y); fr[2] = tobf(f0.z); fr[3] = tobf(f0.w);
            fr[4] = tobf(f1.x); fr[5] = tobf(f1.y); fr[6] = tobf(f1.z); fr[7] = tobf(f1.w);
            bfr[g3][k2] = fr;
        }

    const int c = 16 * w + col;
    const int base = nf * 192;
    const float wr = Wih[base + c], wz = Wih[base + 64 + c], wn = Wih[base + 128 + c];
    const float br = bih[base + c] + bhh[base + c];
    const float bz = bih[base + 64 + c] + bhh[base + 64 + c];
    const float bnn = bih[base + 128 + c], bhn = bhh[base + 128 + c];

    for (int i = tid; i < 16 * 68; i += 256) As[0][i] = 0;
    float hold[4];
#pragma unroll
    for (int r = 0; r < 4; ++r) hold[r] = 0.0f;
    __syncthreads();

    const int crow = tid >> 4, cs = tid & 15;   // store roles (tid<128)

    for (int t = 0; t < T_; ++t) {
        const int rb = t & 1;
        const int wb = 1 - rb;
        const short* ap = &As[rb][col * 68 + quad * 8];
        short4v a0 = *(const short4v*)ap;
        short4v a1 = *(const short4v*)(ap + 4);
        short4v a2 = *(const short4v*)(ap + 32);
        short4v a3 = *(const short4v*)(ap + 36);
        short8v A0 = {a0[0], a0[1], a0[2], a0[3], a1[0], a1[1], a1[2], a1[3]};
        short8v A1 = {a2[0], a2[1], a2[2], a2[3], a3[0], a3[1], a3[2], a3[3]};

        f32x4 acc[3];
#pragma unroll
        for (int g3 = 0; g3 < 3; ++g3) {
            f32x4 a = {0.0f, 0.0f, 0.0f, 0.0f};
            a = __builtin_amdgcn_mfma_f32_16x16x32_bf16(A0, bfr[g3][0], a, 0, 0, 0);
            a = __builtin_amdgcn_mfma_f32_16x16x32_bf16(A1, bfr[g3][1], a, 0, 0, 0);
            acc[g3] = a;
        }

#pragma unroll
        for (int r = 0; r < 4; ++r) {
            float xv = xs[((quad & 1) * 4 + r) * 129 + t];   // quad2/3 mirror 0/1
            float rr = sigmf(xv * wr + br + acc[0][r]);
            float zz = sigmf(xv * wz + bz + acc[1][r]);
            float nn = tanh_fast(xv * wn + bnn + rr * (acc[2][r] + bhn));
            hold[r] = (1.0f - zz) * nn + zz * hold[r];
        }

#pragma unroll
        for (int r = 0; r < 4; ++r) {
            int row = quad * 4 + r;
            As[wb][row * 68 + c] = tobf(hold[r]);
            if (quad < 2) Hs16[wb][row * 68 + c] = __float2half(hold[r]);
        }
        __syncthreads();
        if (tid < 128) {   // stream h_t (8 rows x 64 ch fp16) to Hsg
            const unsigned* hsrc = (const unsigned*)&Hs16[wb][0];
            int li = crow * 34 + cs * 2;
            uint2 pk = *(const uint2*)&hsrc[li];
            size_t go = (((size_t)nf * 128 + cbase + crow) * 128 + t) * 64 + cs * 4;
            *(uint2*)(Hsg + go) = pk;
        }
    }

    // epilogue: q = bt + h127 Wt^T ; qx = Wx^T q ; qb = q . bx
    if (quad < 2) {
#pragma unroll
        for (int r = 0; r < 4; ++r)
            q1[(quad * 4 + r) * 65 + c] = hold[r];
    }
    __syncthreads();
    for (int o = tid; o < 8 * 64; o += 256) {
        int b = o >> 6, k = o & 63;
        const float* wrow = Wt + ((size_t)nf * 64 + k) * 64;
        float a = bt[nf * 64 + k];
#pragma unroll 8
        for (int h = 0; h < 64; h += 4) {
            float4 wv = *(const float4*)&wrow[h];
            a += q1[b * 65 + h] * wv.x + q1[b * 65 + h + 1] * wv.y
               + q1[b * 65 + h + 2] * wv.z + q1[b * 65 + h + 3] * wv.w;
        }
        q2[b * 65 + k] = a;
    }
    __syncthreads();
    for (int o = tid; o < 8 * 64; o += 256) {
        int b = o >> 6, h = o & 63;
        float a = 0.0f;
#pragma unroll 8
        for (int k = 0; k < 64; ++k)
            a += q2[b * 65 + k] * Wx[((size_t)nf * 64 + k) * 64 + h];
        qxg[((size_t)nf * 128 + cbase + b) * 64 + h] = a;
    }
    for (int b = tid; b < 8; b += 256) {
        float a = 0.0f;
        for (int k = 0; k < 64; ++k) a += q2[b * 65 + k] * bx[nf * 64 + k];
        qbg[nf * 128 + cbase + b] = a;
    }
}

// ---------------------------------------------------------------------------
// K1b: time attention + demo row + S zeroing. grid (77,128), block 128.
// nf<76: thread = t, h-row in registers, LDS reduce. nf==76: demo + zero S.
// ---------------------------------------------------------------------------
__global__ __launch_bounds__(128) void k_att(
    const __half* __restrict__ Hsg, const float* __restrict__ qxg,
    const float* __restrict__ qbg, const float* __restrict__ rate,
    const float* __restrict__ D, const float* __restrict__ dW,
    const float* __restrict__ db, float* __restrict__ Sz,
    float* __restrict__ Fin)
{
    const int nf = blockIdx.x, b = blockIdx.y;
    const int tid = threadIdx.x;

    if (nf == NF) {   // demo row + zero decov accumulators
        if (tid < 64) {
            float acc = db[tid];
            for (int j = 0; j < 12; ++j) acc += D[b * 12 + j] * dW[tid * 12 + j];
            Fin[((size_t)b * LQ + 76) * HD + tid] = tanh_fast(acc);
        }
        int s0 = b * 33;
        for (int k = tid; k < 33; k += 128) {
            int idx = s0 + k;
            if (idx < 4160) Sz[idx] = 0.0f;
        }
        return;
    }

    __shared__ float wsum[128 * 69];
    __shared__ float wl[128];
    __shared__ float qxl[64];
    __shared__ float pn[2][68];
    __shared__ float pd[2];
    if (tid < 64) qxl[tid] = qxg[((size_t)nf * 128 + b) * 64 + tid];
    const float qb = qbg[nf * 128 + b];
    const float sigr = sigmf(rate[nf]);

    uint4 rv[8];
    const uint4* src = (const uint4*)(Hsg + (((size_t)nf * 128 + b) * 128 + tid) * 64);
#pragma unroll
    for (int k = 0; k < 8; ++k) rv[k] = src[k];
    __syncthreads();

    float a = qb;
#pragma unroll
    for (int k = 0; k < 8; ++k) {
        float2 h0 = h2f2(rv[k].x), h1 = h2f2(rv[k].y);
        float2 h2v = h2f2(rv[k].z), h3 = h2f2(rv[k].w);
        a += h0.x * qxl[k * 8 + 0] + h0.y * qxl[k * 8 + 1]
           + h1.x * qxl[k * 8 + 2] + h1.y * qxl[k * 8 + 3]
           + h2v.x * qxl[k * 8 + 4] + h2v.y * qxl[k * 8 + 5]
           + h3.x * qxl[k * 8 + 6] + h3.y * qxl[k * 8 + 7];
    }
    float ds = sigmf(a);
    float dn = fmaxf(sigr * __logf(2.72f + (1.0f - ds)) * (float)(tid + 1), 1e-6f);
    float e = fmaxf(ds / dn, 0.0f);
    float w = __expf(e);                  // e in [0,2]: no max-shift needed
    wl[tid] = w;
#pragma unroll
    for (int k = 0; k < 8; ++k) {
        float2 h0 = h2f2(rv[k].x), h1 = h2f2(rv[k].y);
        float2 h2v = h2f2(rv[k].z), h3 = h2f2(rv[k].w);
        float* d = &wsum[tid * 69 + k * 8];
        d[0] = w * h0.x; d[1] = w * h0.y; d[2] = w * h1.x; d[3] = w * h1.y;
        d[4] = w * h2v.x; d[5] = w * h2v.y; d[6] = w * h3.x; d[7] = w * h3.y;
    }
    __syncthreads();
    {
        int ch = tid & 63, half = tid >> 6;
        float acc = 0.0f, den = 0.0f;
        int t0 = half * 64;
        for (int t = t0; t < t0 + 64; ++t) {
            acc += wsum[t * 69 + ch];
            den += wl[t];
        }
        pn[half][ch] = acc;
        if (ch == 0) pd[half] = den;
    }
    __syncthreads();
    if (tid < 64) {
        float num = pn[0][tid] + pn[1][tid];
        float den = pd[0] + pd[1];
        Fin[((size_t)b * LQ + nf) * HD + tid] = num / den;
    }
}

// ---------------------------------------------------------------------------
// K4: MHA per (b, head, variant). grid (128,4,2), block 256.
// variant 0: raw F_in -> M1. variant 1: LN(F_in) -> M2.
// ---------------------------------------------------------------------------
__global__ __launch_bounds__(256) void k_mha2(
    const float* __restrict__ Fin,
    const float* __restrict__ Wq, const float* __restrict__ bq,
    const float* __restrict__ Wk, const float* __restrict__ bk,
    const float* __restrict__ Wv, const float* __restrict__ bv,
    const float* __restrict__ g1, const float* __restrict__ b1,
    float* __restrict__ M1, float* __restrict__ M2)
{
    __shared__ float xl[LQ * 68];
    __shared__ float qh[LQ * 17], kh[LQ * 17], vh[LQ * 17];
    __shared__ float os[2][LQ][17];
    const int b = blockIdx.x, hd = blockIdx.y, v = blockIdx.z;
    const int tid = threadIdx.x;
    const float* xsrc = Fin + (size_t)b * LQ * HD;

    for (int idx = tid; idx < LQ * HD; idx += 256)
        xl[(idx >> 6) * 68 + (idx & 63)] = xsrc[idx];
    __syncthreads();
    if (v == 1) {
        if (tid < LQ) {
            float mu = 0.0f;
            for (int h = 0; h < 64; ++h) mu += xl[tid * 68 + h];
            mu *= (1.0f / 64.0f);
            float var = 0.0f;
            for (int h = 0; h < 64; ++h) { float d = xl[tid * 68 + h] - mu; var += d * d; }
            var *= (1.0f / 64.0f);
            float rs = rsqrtf(var + 1e-7f);
            for (int h = 0; h < 64; ++h)
                xl[tid * 68 + h] = (xl[tid * 68 + h] - mu) * rs * g1[h] + b1[h];
        }
        __syncthreads();
    }

    for (int idx = tid; idx < LQ * 16; idx += 256) {
        int l = idx >> 4, d = idx & 15, ch = hd * 16 + d;
        float aq = bq[ch], ak = bk[ch], av = bv[ch];
        const float4* wq = (const float4*)(Wq + ch * 64);
        const float4* wk = (const float4*)(Wk + ch * 64);
        const float4* wv = (const float4*)(Wv + ch * 64);
        const float4* xr = (const float4*)&xl[l * 68];
#pragma unroll 4
        for (int c4 = 0; c4 < 16; ++c4) {
            float4 xv = xr[c4];
            float4 a = wq[c4], bb = wk[c4], cc = wv[c4];
            aq += xv.x * a.x + xv.y * a.y + xv.z * a.z + xv.w * a.w;
            ak += xv.x * bb.x + xv.y * bb.y + xv.z * bb.z + xv.w * bb.w;
            av += xv.x * cc.x + xv.y * cc.y + xv.z * cc.z + xv.w * cc.w;
        }
        qh[l * 17 + d] = aq; kh[l * 17 + d] = ak; vh[l * 17 + d] = av;
    }
    __syncthreads();

    {
        int l = tid & 127, half = tid >> 7;
        if (l < LQ) {
            float qf[16];
#pragma unroll
            for (int d = 0; d < 16; ++d) qf[d] = qh[l * 17 + d];
            int j0 = half ? 39 : 0, j1 = half ? LQ : 39;
            float o[16];
#pragma unroll
            for (int d = 0; d < 16; ++d) o[d] = 0.0f;
            float ss = 0.0f;
            for (int j = j0; j < j1; ++j) {
                float sc = 0.0f;
#pragma unroll
                for (int d = 0; d < 16; ++d) sc += qf[d] * kh[j * 17 + d];
                float p = __expf(sc * 0.25f);   // scores tiny: no max-shift
                ss += p;
#pragma unroll
                for (int d = 0; d < 16; ++d) o[d] += p * vh[j * 17 + d];
            }
#pragma unroll
            for (int d = 0; d < 16; ++d) os[half][l][d] = o[d];
            os[half][l][16] = ss;
        }
    }
    __syncthreads();
    if (tid < LQ) {
        float inv = 1.0f / (os[0][tid][16] + os[1][tid][16]);
        float* Mout = (v == 1) ? M2 : M1;
#pragma unroll
        for (int d = 0; d < 16; ++d)
            Mout[((size_t)b * LQ + tid) * HD + hd * 16 + d]
                = (os[0][tid][d] + os[1][tid][d]) * inv;
    }
}

// ---------------------------------------------------------------------------
// K5: fused tail per batch: Wo epilogue + cov atomics + LN2 + FFN + final
// attention + head. grid 128, block 256. Three 77x68 LDS buffers aliased.
// ---------------------------------------------------------------------------
__global__ __launch_bounds__(256) void k_tail(
    const float* __restrict__ Fin, const float* __restrict__ M1,
    const float* __restrict__ M2, const float* __restrict__ Wo,
    const float* __restrict__ bo,
    const float* __restrict__ g2, const float* __restrict__ b2,
    const float* __restrict__ W1, const float* __restrict__ bb1,
    const float* __restrict__ W2, const float* __restrict__ bb2,
    const float* __restrict__ faWq, const float* __restrict__ fabq,
    const float* __restrict__ faWk, const float* __restrict__ fabk,
    const float* __restrict__ faWv, const float* __restrict__ fabv,
    const float* __restrict__ faWout, const float* __restrict__ fabout,
    const float* __restrict__ o0W, const float* __restrict__ o0b,
    const float* __restrict__ o1W, const float* __restrict__ o1b,
    float* __restrict__ S, float* __restrict__ MU, float* __restrict__ out)
{
    __shared__ float buf0[LQ * 68];   // M1 -> zl -> V
    __shared__ float buf1[LQ * 68];   // M2 -> ul(FFN) -> qk scores
    __shared__ float yl[LQ * 68];     // Y -> Z
    __shared__ float sc[LQ + 3];
    __shared__ float sv[64], h1[64];
    __shared__ float red0;
    const int b = blockIdx.x, tid = threadIdx.x;

    for (int idx = tid; idx < LQ * HD; idx += 256) {
        int l = idx >> 6, h = idx & 63;
        buf0[l * 68 + h] = M1[(size_t)b * LQ * HD + idx];
        buf1[l * 68 + h] = M2[(size_t)b * LQ * HD + idx];
    }
    __syncthreads();
    // Wo epilogue: yl = Fin + M2 Wo^T + bo
    for (int idx = tid; idx < LQ * HD; idx += 256) {
        int l = idx >> 6, h = idx & 63;
        float acc = bo[h];
        const float4* wo = (const float4*)(Wo + h * 64);
        const float4* mr = (const float4*)&buf1[l * 68];
#pragma unroll 4
        for (int c4 = 0; c4 < 16; ++c4) {
            float4 wv = wo[c4], mv = mr[c4];
            acc += mv.x * wv.x + mv.y * wv.y + mv.z * wv.z + mv.w * wv.w;
        }
        yl[l * 68 + h] = Fin[(size_t)b * LQ * HD + idx] + acc;
    }
    // cov atomics from M1 (buf0)
    for (int idx = tid; idx < 4096; idx += 256) {
        int i = idx >> 6, j = idx & 63;
        float acc = 0.0f;
        for (int l = 0; l < LQ; ++l) acc += buf0[l * 68 + i] * buf0[l * 68 + j];
        atomicAdd(&S[idx], acc);
    }
    if (tid < 64) {
        float acc = 0.0f;
        for (int l = 0; l < LQ; ++l) acc += buf0[l * 68 + tid];
        atomicAdd(&MU[tid], acc);
    }
    __syncthreads();
    // LN2: yl -> buf0 (zl)
    if (tid < LQ) {
        float mu = 0.0f;
        for (int h = 0; h < 64; ++h) mu += yl[tid * 68 + h];
        mu *= (1.0f / 64.0f);
        float var = 0.0f;
        for (int h = 0; h < 64; ++h) { float d = yl[tid * 68 + h] - mu; var += d * d; }
        var *= (1.0f / 64.0f);
        float rs = rsqrtf(var + 1e-7f);
        for (int h = 0; h < 64; ++h)
            buf0[tid * 68 + h] = (yl[tid * 68 + h] - mu) * rs * g2[h] + b2[h];
    }
    __syncthreads();
    // FFN in chunks of 16 rows; ul lives in buf1
    for (int l0 = 0; l0 < LQ; l0 += 16) {
        int nl = (LQ - l0 < 16) ? (LQ - l0) : 16;
        {   // W1: thread = f
            const int f = tid;
            float acc[16];
#pragma unroll
            for (int r = 0; r < 16; ++r) acc[r] = bb1[f];
            const float4* w1r = (const float4*)(W1 + f * 64);
#pragma unroll
            for (int c = 0; c < 4; ++c) {
                float4 w0 = w1r[c * 4 + 0], w1 = w1r[c * 4 + 1];
                float4 w2 = w1r[c * 4 + 2], w3 = w1r[c * 4 + 3];
#pragma unroll
                for (int r = 0; r < 16; ++r) {
                    int lr = l0 + r;
                    if (lr >= LQ) lr = LQ - 1;   // clamp: garbage rows unused
                    const float4* zr = (const float4*)&buf0[lr * 68 + c * 16];
                    float4 z0 = zr[0], z1 = zr[1], z2 = zr[2], z3 = zr[3];
                    acc[r] += z0.x * w0.x + z0.y * w0.y + z0.z * w0.z + z0.w * w0.w
                            + z1.x * w1.x + z1.y * w1.y + z1.z * w1.z + z1.w * w1.w
                            + z2.x * w2.x + z2.y * w2.y + z2.z * w2.z + z2.w * w2.w
                            + z3.x * w3.x + z3.y * w3.y + z3.z * w3.z + z3.w * w3.w;
                }
            }
#pragma unroll
            for (int r = 0; r < 16; ++r) buf1[r * 260 + f] = fmaxf(acc[r], 0.0f);
        }
        __syncthreads();
        {   // W2: thread = (h, 4 rows)
            const int h = tid & 63, rq = tid >> 6;
            float acc[4];
#pragma unroll
            for (int rr = 0; rr < 4; ++rr) acc[rr] = bb2[h];
            const float4* w2r = (const float4*)(W2 + h * 256);
#pragma unroll 4
            for (int c = 0; c < 16; ++c) {
                float4 w0 = w2r[c * 4 + 0], w1 = w2r[c * 4 + 1];
                float4 w2 = w2r[c * 4 + 2], w3 = w2r[c * 4 + 3];
#pragma unroll
                for (int rr = 0; rr < 4; ++rr) {
                    const float4* ur = (const float4*)&buf1[(rq * 4 + rr) * 260 + c * 16];
                    float4 u0 = ur[0], u1 = ur[1], u2 = ur[2], u3 = ur[3];
                    acc[rr] += u0.x * w0.x + u0.y * w0.y + u0.z * w0.z + u0.w * w0.w
                             + u1.x * w1.x + u1.y * w1.y + u1.z * w1.z + u1.w * w1.w
                             + u2.x * w2.x + u2.y * w2.y + u2.z * w2.z + u2.w * w2.w
                             + u3.x * w3.x + u3.y * w3.y + u3.z * w3.z + u3.w * w3.w;
                }
            }
#pragma unroll
            for (int rr = 0; rr < 4; ++rr) {
                int r = rq * 4 + rr;
                if (r < nl) yl[(l0 + r) * 68 + h] += acc[rr];   // Z = Y + FFN
            }
        }
        __syncthreads();
    }

    // FinalAttentionQKV from yl (=Z); scores -> buf1, V -> buf0
    for (int idx = tid; idx < LQ * HD; idx += 256) {
        int l = idx >> 6, h = idx & 63;
        float q = fabq[h], k = fabk[h], v = fabv[h];
        const float4* wq = (const float4*)(faWq + h * 64);
        const float4* wk = (const float4*)(faWk + h * 64);
        const float4* wv = (const float4*)(faWv + h * 64);
        const float4* zr = (const float4*)&yl[l * 68];
#pragma unroll 4
        for (int c4 = 0; c4 < 16; ++c4) {
            float4 zv = zr[c4];
            float4 a = wq[c4], bb = wk[c4], cc = wv[c4];
            q += zv.x * a.x + zv.y * a.y + zv.z * a.z + zv.w * a.w;
            k += zv.x * bb.x + zv.y * bb.y + zv.z * bb.z + zv.w * bb.w;
            v += zv.x * cc.x + zv.y * cc.y + zv.z * cc.z + zv.w * cc.w;
        }
        buf1[l * 65 + h] = q * k * faWout[h];
        buf0[l * 68 + h] = v;
    }
    __syncthreads();
    if (tid < LQ) {
        float acc = fabout[0];
        for (int h = 0; h < 64; ++h) acc += buf1[tid * 65 + h];
        sc[tid] = acc;
    }
    __syncthreads();
    if (tid < 64) {
        float v0 = sc[tid];
        float v1 = (tid < LQ - 64) ? sc[tid + 64] : -1e30f;
        float m = fmaxf(v0, v1);
        for (int o = 32; o; o >>= 1) m = fmaxf(m, __shfl_xor(m, o, 64));
        float e0 = __expf(v0 - m);
        float e1 = (tid < LQ - 64) ? __expf(v1 - m) : 0.0f;
        float s = e0 + e1;
        for (int o = 32; o; o >>= 1) s += __shfl_xor(s, o, 64);
        sc[tid] = e0;
        if (tid < LQ - 64) sc[tid + 64] = e1;
        if (tid == 0) red0 = s;
    }
    __syncthreads();
    if (tid < 64) {
        float acc = 0.0f;
        for (int l = 0; l < LQ; ++l) acc += sc[l] * buf0[l * 68 + tid];
        sv[tid] = acc / red0;
    }
    __syncthreads();
    if (tid < 64) {
        float acc = o0b[tid];
        const float* w = o0W + tid * 64;
#pragma unroll 8
        for (int c = 0; c < 64; ++c) acc += sv[c] * w[c];
        h1[tid] = fmaxf(acc, 0.0f);
    }
    __syncthreads();
    if (tid < 64) {
        float p = h1[tid] * o1W[tid];
        for (int o = 32; o; o >>= 1) p += __shfl_xor(p, o, 64);
        if (tid == 0) out[b] = sigmf(p + o1b[0]);
    }
}

__global__ void k_decov(const float* __restrict__ S, const float* __restrict__ MU,
                        float* __restrict__ out)
{
    int lane = threadIdx.x;
    const float invM = 1.0f / 9856.0f;
    float asum = 0.0f, dsum = 0.0f;
    for (int idx = lane; idx < 4096; idx += 64) {
        int i = idx >> 6, j = idx & 63;
        float c = S[idx] * invM - (MU[i] * invM) * (MU[j] * invM);
        asum += c * c;
        if (i == j) dsum += c * c;
    }
    for (int o = 32; o; o >>= 1) {
        asum += __shfl_xor(asum, o, 64);
        dsum += __shfl_xor(dsum, o, 64);
    }
    if (lane == 0) out[128] = 0.5f * (asum - dsum);
}

// ---------------------------------------------------------------------------
// Fallback path kernels (ws too small): R3-style fused GRU+attn, demo, zero.
// ---------------------------------------------------------------------------
__global__ void k_demo(const float* __restrict__ D, const float* __restrict__ dW,
                       const float* __restrict__ db, float* __restrict__ Fin)
{
    int b = blockIdx.x, h = threadIdx.x;
    float acc = db[h];
    for (int j = 0; j < 12; ++j) acc += D[b * 12 + j] * dW[h * 12 + j];
    Fin[((size_t)b * LQ + 76) * HD + h] = tanh_fast(acc);
}

__global__ void k_zero(float* __restrict__ p)
{
    for (int i = threadIdx.x; i < 4160; i += 256) p[i] = 0.0f;
}

__global__ __launch_bounds__(128) void k_gru_mfma(
    const float* __restrict__ X, const float* __restrict__ Wih,
    const float* __restrict__ Whh, const float* __restrict__ bih,
    const float* __restrict__ bhh,
    const float* __restrict__ Wt, const float* __restrict__ bt,
    const float* __restrict__ Wx, const float* __restrict__ bx,
    const float* __restrict__ rate, float* __restrict__ Fin)
{
    __shared__ short As[2][16 * 68];
    __shared__ float xs[16 * 129];
    __shared__ float q1[16 * 65];
    __shared__ float q2[16 * 65];
    __shared__ float qbs[16];
    __shared__ float dotw[2][2][16];

    const int nf = blockIdx.y;
    const int cbase = blockIdx.x * 16;
    const int tid = threadIdx.x;
    const int w = tid >> 6;
    const int lane = tid & 63;
    const int col = lane & 15;
    const int quad = lane >> 4;

    for (int i = tid; i < 16 * T_; i += 128) {
        int b = i >> 7, t = i & 127;
        xs[b * 129 + t] = X[((size_t)(cbase + b) * T_ + t) * NF + nf];
    }
    short8v bfr[3][2][2];
    const float* wbase = Whh + (size_t)nf * 12288;
#pragma unroll
    for (int g3 = 0; g3 < 3; ++g3)
#pragma unroll
        for (int s = 0; s < 2; ++s)
#pragma unroll
            for (int k2 = 0; k2 < 2; ++k2) {
                int g = 64 * g3 + 32 * w + 16 * s + col;
                const float* src = wbase + g * 64 + 32 * k2 + quad * 8;
                float4 f0 = *(const float4*)src;
                float4 f1 = *(const float4*)(src + 4);
                short8v fr;
                fr[0] = tobf(f0.x); fr[1] = tobf(f0.y); fr[2] = tobf(f0.z); fr[3] = tobf(f0.w);
                fr[4] = tobf(f1.x); fr[5] = tobf(f1.y); fr[6] = tobf(f1.z); fr[7] = tobf(f1.w);
                bfr[g3][s][k2] = fr;
            }
    float wr[2], wz[2], wn[2], br[2], bz[2], bnn[2], bhn[2];
#pragma unroll
    for (int s = 0; s < 2; ++s) {
        int c = 32 * w + 16 * s + col;
        int base = nf * 192;
        wr[s] = Wih[base + c]; wz[s] = Wih[base + 64 + c]; wn[s] = Wih[base + 128 + c];
        br[s] = bih[base + c] + bhh[base + c];
        bz[s] = bih[base + 64 + c] + bhh[base + 64 + c];
        bnn[s] = bih[base + 128 + c]; bhn[s] = bhh[base + 128 + c];
    }
    const float sigr = sigmf(rate[nf]);
    float hold[2][4], num[2][4], den[4], qxv[2][4], qbv[4];
#pragma unroll
    for (int r = 0; r < 4; ++r) {
        den[r] = 0.0f; qbv[r] = 0.0f;
        num[0][r] = 0.0f; num[1][r] = 0.0f;
        qxv[0][r] = 0.0f; qxv[1][r] = 0.0f;
    }
    for (int pass = 0; pass < 2; ++pass) {
        for (int i = tid; i < 16 * 68; i += 128) As[0][i] = 0;
#pragma unroll
        for (int s = 0; s < 2; ++s)
#pragma unroll
            for (int r = 0; r < 4; ++r) hold[s][r] = 0.0f;
        __syncthreads();
        for (int t = 0; t < T_; ++t) {
            const int rb = t & 1;
            const int wb = 1 - rb;
            const short* ap = &As[rb][col * 68 + quad * 8];
            short4v a0 = *(const short4v*)ap;
            short4v a1 = *(const short4v*)(ap + 4);
            short4v a2 = *(const short4v*)(ap + 32);
            short4v a3 = *(const short4v*)(ap + 36);
            short8v A0 = {a0[0], a0[1], a0[2], a0[3], a1[0], a1[1], a1[2], a1[3]};
            short8v A1 = {a2[0], a2[1], a2[2], a2[3], a3[0], a3[1], a3[2], a3[3]};
            f32x4 acc[3][2];
#pragma unroll
            for (int g3 = 0; g3 < 3; ++g3)
#pragma unroll
                for (int s = 0; s < 2; ++s) {
                    f32x4 a = {0.0f, 0.0f, 0.0f, 0.0f};
                    a = __builtin_amdgcn_mfma_f32_16x16x32_bf16(A0, bfr[g3][s][0], a, 0, 0, 0);
                    a = __builtin_amdgcn_mfma_f32_16x16x32_bf16(A1, bfr[g3][s][1], a, 0, 0, 0);
                    acc[g3][s] = a;
                }
            float xv[4];
#pragma unroll
            for (int r = 0; r < 4; ++r) xv[r] = xs[(quad * 4 + r) * 129 + t];
            float hnew[2][4];
#pragma unroll
            for (int s = 0; s < 2; ++s)
#pragma unroll
                for (int r = 0; r < 4; ++r) {
                    float rr = sigmf(xv[r] * wr[s] + br[s] + acc[0][s][r]);
                    float zz = sigmf(xv[r] * wz[s] + bz[s] + acc[1][s][r]);
                    float nn = tanh_fast(xv[r] * wn[s] + bnn[s] + rr * (acc[2][s][r] + bhn[s]));
                    hnew[s][r] = (1.0f - zz) * nn + zz * hold[s][r];
                    hold[s][r] = hnew[s][r];
                }
#pragma unroll
            for (int s = 0; s < 2; ++s)
#pragma unroll
                for (int r = 0; r < 4; ++r)
                    As[wb][(quad * 4 + r) * 68 + 32 * w + 16 * s + col] = tobf(hnew[s][r]);
            if (pass == 1) {
                float p[4];
#pragma unroll
                for (int r = 0; r < 4; ++r)
                    p[r] = qxv[0][r] * hnew[0][r] + qxv[1][r] * hnew[1][r];
#pragma unroll
                for (int m = 1; m < 16; m <<= 1) {
                    p[0] += __shfl_xor(p[0], m, 64);
                    p[1] += __shfl_xor(p[1], m, 64);
                    p[2] += __shfl_xor(p[2], m, 64);
                    p[3] += __shfl_xor(p[3], m, 64);
                }
                if (col == 0) {
#pragma unroll
                    for (int r = 0; r < 4; ++r) dotw[rb][w][quad * 4 + r] = p[r];
                }
                __syncthreads();
                float tf = (float)(t + 1);
#pragma unroll
                for (int r = 0; r < 4; ++r) {
                    float dot = p[r] + dotw[rb][1 - w][quad * 4 + r] + qbv[r];
                    float ds = sigmf(dot);
                    float dn = fmaxf(sigr * __logf(2.72f + (1.0f - ds)) * tf, 1e-6f);
                    float e = fmaxf(ds / dn, 0.0f);
                    float wt = __expf(e);
                    den[r] += wt;
                    num[0][r] += wt * hnew[0][r];
                    num[1][r] += wt * hnew[1][r];
                }
            } else {
                __syncthreads();
            }
        }
        if (pass == 0) {
#pragma unroll
            for (int s = 0; s < 2; ++s)
#pragma unroll
                for (int r = 0; r < 4; ++r)
                    q1[(quad * 4 + r) * 65 + 32 * w + 16 * s + col] = hold[s][r];
            __syncthreads();
            for (int o = tid; o < 16 * 64; o += 128) {
                int b = o >> 6, k = o & 63;
                const float* wrow = Wt + ((size_t)nf * 64 + k) * 64;
                float a = bt[nf * 64 + k];
#pragma unroll 8
                for (int h = 0; h < 64; h += 4) {
                    float4 wv = *(const float4*)&wrow[h];
                    a += q1[b * 65 + h] * wv.x + q1[b * 65 + h + 1] * wv.y
                       + q1[b * 65 + h + 2] * wv.z + q1[b * 65 + h + 3] * wv.w;
                }
                q2[b * 65 + k] = a;
            }
            __syncthreads();
            for (int o = tid; o < 16 * 64; o += 128) {
                int b = o >> 6, h = o & 63;
                float a = 0.0f;
#pragma unroll 8
                for (int k = 0; k < 64; ++k)
                    a += q2[b * 65 + k] * Wx[((size_t)nf * 64 + k) * 64 + h];
                q1[b * 65 + h] = a;
            }
            for (int b = tid; b < 16; b += 128) {
                float a = 0.0f;
                for (int k = 0; k < 64; ++k) a += q2[b * 65 + k] * bx[nf * 64 + k];
                qbs[b] = a;
            }
            __syncthreads();
#pragma unroll
            for (int r = 0; r < 4; ++r) {
                qbv[r] = qbs[quad * 4 + r];
#pragma unroll
                for (int s = 0; s < 2; ++s)
                    qxv[s][r] = q1[(quad * 4 + r) * 65 + 32 * w + 16 * s + col];
                den[r] = 0.0f; num[0][r] = 0.0f; num[1][r] = 0.0f;
            }
            __syncthreads();
        }
    }
#pragma unroll
    for (int s = 0; s < 2; ++s)
#pragma unroll
        for (int r = 0; r < 4; ++r) {
            int b = cbase + quad * 4 + r;
            int c = 32 * w + 16 * s + col;
            Fin[((size_t)b * LQ + nf) * HD + c] = num[s][r] / den[r];
        }
}

extern "C" void kernel_launch(void* const* d_in, const int* in_sizes, int n_in,
                              void* d_out, int out_size, void* d_ws, size_t ws_size,
                              hipStream_t stream)
{
    (void)in_sizes; (void)n_in; (void)out_size;
    const float* X     = (const float*)d_in[0];
    const float* D     = (const float*)d_in[1];
    const float* gWih  = (const float*)d_in[2];
    const float* gWhh  = (const float*)d_in[3];
    const float* gbih  = (const float*)d_in[4];
    const float* gbhh  = (const float*)d_in[5];
    const float* aWt   = (const float*)d_in[6];
    const float* abt   = (const float*)d_in[7];
    const float* aWx   = (const float*)d_in[8];
    const float* abx   = (const float*)d_in[9];
    const float* arate = (const float*)d_in[10];
    const float* dW    = (const float*)d_in[11];
    const float* db    = (const float*)d_in[12];
    const float* mWq   = (const float*)d_in[13]; const float* mbq = (const float*)d_in[14];
    const float* mWk   = (const float*)d_in[15]; const float* mbk = (const float*)d_in[16];
    const float* mWv   = (const float*)d_in[17]; const float* mbv = (const float*)d_in[18];
    const float* mWo   = (const float*)d_in[19]; const float* mbo = (const float*)d_in[20];
    const float* l1g   = (const float*)d_in[21]; const float* l1b = (const float*)d_in[22];
    const float* fW1   = (const float*)d_in[23]; const float* fb1 = (const float*)d_in[24];
    const float* fW2   = (const float*)d_in[25]; const float* fb2 = (const float*)d_in[26];
    const float* l2g   = (const float*)d_in[27]; const float* l2b = (const float*)d_in[28];
    const float* faWq  = (const float*)d_in[29]; const float* fabq = (const float*)d_in[30];
    const float* faWk  = (const float*)d_in[31]; const float* fabk = (const float*)d_in[32];
    const float* faWv  = (const float*)d_in[33]; const float* fabv = (const float*)d_in[34];
    const float* faWo  = (const float*)d_in[35]; const float* fabo = (const float*)d_in[36];
    const float* o0W   = (const float*)d_in[37]; const float* o0b  = (const float*)d_in[38];
    const float* o1W   = (const float*)d_in[39]; const float* o1b  = (const float*)d_in[40];

    float* ws  = (float*)d_ws;
    float* Fin = ws;                               // 630,784
    float* M1  = Fin + 630784;                     // 630,784
    float* M2  = M1  + 630784;                     // 630,784
    float* S   = M2  + 630784;                     // 4096 (+64 MU)
    float* MU  = S   + 4096;                       // 64
    float* qxg = MU  + 64;                         // 622,592
    float* qbg = qxg + 622592;                     // 9,728
    __half* Hsg = (__half*)(qbg + 9728);           // 79,691,776 halfs
    const size_t need = (size_t)(630784 * 3 + 4096 + 64 + 622592 + 9728) * 4
                        + (size_t)79691776 * 2;
    float* outp = (float*)d_out;

    if (ws_size >= need) {
        k_gru0<<<dim3(16, NF), 256, 0, stream>>>(X, gWih, gWhh, gbih, gbhh,
                                                 aWt, abt, aWx, abx, Hsg, qxg, qbg);
        k_att<<<dim3(NF + 1, B_), 128, 0, stream>>>(Hsg, qxg, qbg, arate,
                                                    D, dW, db, S, Fin);
    } else {
        k_gru_mfma<<<dim3(8, NF), 128, 0, stream>>>(X, gWih, gWhh, gbih, gbhh,
                                                    aWt, abt, aWx, abx, arate, Fin);
        k_demo<<<B_, 64, 0, stream>>>(D, dW, db, Fin);
        k_zero<<<1, 256, 0, stream>>>(S);
    }
    k_mha2<<<dim3(B_, 4, 2), 256, 0, stream>>>(Fin, mWq, mbq, mWk, mbk, mWv, mbv,
                                               l1g, l1b, M1, M2);
    k_tail<<<B_, 256, 0, stream>>>(Fin, M1, M2, mWo, mbo, l2g, l2b,
                                   fW1, fb1, fW2, fb2,
                                   faWq, fabq, faWk, fabk, faWv, fabv,
                                   faWo, fabo, o0W, o0b, o1W, o1b, S, MU, outp);
    k_decov<<<1, 64, 0, stream>>>(S, MU, outp);
}

// Round 8
// 797.025 us; speedup vs baseline: 1.0887x; 1.0887x over previous
//
#include <hip/hip_runtime.h>
#include <math.h>

#define B_ 128
#define T_ 128
#define NF 76
#define HD 64
#define LQ 77

typedef __attribute__((ext_vector_type(8))) short short8v;
typedef __attribute__((ext_vector_type(4))) short short4v;
typedef __attribute__((ext_vector_type(4))) float f32x4;

__device__ __forceinline__ float sigmf(float x) { return 1.0f / (1.0f + __expf(-x)); }
__device__ __forceinline__ float tanh_fast(float x) { return 2.0f / (1.0f + __expf(-2.0f * x)) - 1.0f; }
__device__ __forceinline__ short tobf(float x) {
    unsigned u = __float_as_uint(x);
    u += 0x7FFF + ((u >> 16) & 1);   // RNE to bf16
    return (short)(u >> 16);
}
__device__ __forceinline__ float bflo(unsigned u) { return __uint_as_float(u << 16); }
__device__ __forceinline__ float bfhi(unsigned u) { return __uint_as_float(u & 0xffff0000u); }

// ---------------------------------------------------------------------------
// K1a: GRU recurrence via MFMA. grid (8,76) = (16-batch chunk, nf), block 256
// (4 waves; wave w owns hidden channels [16w,16w+16) for all 3 gates).
// A rows padded to 72 shorts -> aligned ds_read_b128 A-frags. h state bf16 in
// As double buffer; As itself is streamed to Hsg[nf][b][t][ch] (bf16).
// ---------------------------------------------------------------------------
__global__ __launch_bounds__(256) void k_gru0(
    const float* __restrict__ X, const float* __restrict__ Wih,
    const float* __restrict__ Whh, const float* __restrict__ bih,
    const float* __restrict__ bhh,
    const float* __restrict__ Wt, const float* __restrict__ bt,
    const float* __restrict__ Wx, const float* __restrict__ bx,
    short* __restrict__ Hsg, float* __restrict__ qxg, float* __restrict__ qbg)
{
    __shared__ short As[2][16 * 72];      // bf16 A-frags, rows padded to 72
    __shared__ float xs[16 * 129];
    __shared__ float q1[16 * 65];
    __shared__ float q2[16 * 65];

    const int nf = blockIdx.y;
    const int chunk = blockIdx.x;
    const int cbase = chunk * 16;
    const int tid = threadIdx.x;
    const int w = tid >> 6;               // wave: channel slice [16w,16w+16)
    const int lane = tid & 63;
    const int col = lane & 15;
    const int quad = lane >> 4;

    for (int i = tid; i < 16 * T_; i += 256) {
        int b = i >> 7, t = i & 127;
        xs[b * 129 + t] = X[((size_t)(cbase + b) * T_ + t) * NF + nf];
    }

    short8v bfr[3][2];
    const float* wbase = Whh + (size_t)nf * 12288;
#pragma unroll
    for (int g3 = 0; g3 < 3; ++g3)
#pragma unroll
        for (int k2 = 0; k2 < 2; ++k2) {
            int g = 64 * g3 + 16 * w + col;
            const float* src = wbase + g * 64 + 32 * k2 + quad * 8;
            float4 f0 = *(const float4*)src;
            float4 f1 = *(const float4*)(src + 4);
            short8v fr;
            fr[0] = tobf(f0.x); fr[1] = tobf(f0.y); fr[2] = tobf(f0.z); fr[3] = tobf(f0.w);
            fr[4] = tobf(f1.x); fr[5] = tobf(f1.y); fr[6] = tobf(f1.z); fr[7] = tobf(f1.w);
            bfr[g3][k2] = fr;
        }

    const int c = 16 * w + col;
    const int base = nf * 192;
    const float wr = Wih[base + c], wz = Wih[base + 64 + c], wn = Wih[base + 128 + c];
    const float br = bih[base + c] + bhh[base + c];
    const float bz = bih[base + 64 + c] + bhh[base + 64 + c];
    const float bnn = bih[base + 128 + c], bhn = bhh[base + 128 + c];

    for (int i = tid; i < 16 * 72; i += 256) As[0][i] = 0;
    float hold[4];
#pragma unroll
    for (int r = 0; r < 4; ++r) hold[r] = 0.0f;
    __syncthreads();

    const int crow = tid >> 4, cs = tid & 15;   // store roles (all 256 threads)

    for (int t = 0; t < T_; ++t) {
        const int rb = t & 1;
        const int wb = 1 - rb;
        short8v A0 = *(const short8v*)&As[rb][col * 72 + quad * 8];
        short8v A1 = *(const short8v*)&As[rb][col * 72 + 32 + quad * 8];

        f32x4 acc[3];
#pragma unroll
        for (int g3 = 0; g3 < 3; ++g3) {
            f32x4 a = {0.0f, 0.0f, 0.0f, 0.0f};
            a = __builtin_amdgcn_mfma_f32_16x16x32_bf16(A0, bfr[g3][0], a, 0, 0, 0);
            a = __builtin_amdgcn_mfma_f32_16x16x32_bf16(A1, bfr[g3][1], a, 0, 0, 0);
            acc[g3] = a;
        }

#pragma unroll
        for (int r = 0; r < 4; ++r) {
            float xv = xs[(quad * 4 + r) * 129 + t];
            float rr = sigmf(xv * wr + br + acc[0][r]);
            float zz = sigmf(xv * wz + bz + acc[1][r]);
            float nn = tanh_fast(xv * wn + bnn + rr * (acc[2][r] + bhn));
            hold[r] = (1.0f - zz) * nn + zz * hold[r];
        }

#pragma unroll
        for (int r = 0; r < 4; ++r)
            As[wb][(quad * 4 + r) * 72 + c] = tobf(hold[r]);
        __syncthreads();
        {   // stream h_t (bf16, 2 KB) to Hsg, coalesced uint2/thread
            uint2 pk = *(const uint2*)&As[wb][crow * 72 + cs * 4];
            size_t go = (((size_t)nf * 128 + cbase + crow) * 128 + t) * 64 + cs * 4;
            *(uint2*)(Hsg + go) = pk;
        }
    }

    // epilogue: q = bt + h127 Wt^T ; qx = Wx^T q ; qb = q . bx
#pragma unroll
    for (int r = 0; r < 4; ++r)
        q1[(quad * 4 + r) * 65 + c] = hold[r];
    __syncthreads();
    for (int o = tid; o < 16 * 64; o += 256) {
        int b = o >> 6, k = o & 63;
        const float* wrow = Wt + ((size_t)nf * 64 + k) * 64;
        float a = bt[nf * 64 + k];
#pragma unroll 8
        for (int h = 0; h < 64; h += 4) {
            float4 wv = *(const float4*)&wrow[h];
            a += q1[b * 65 + h] * wv.x + q1[b * 65 + h + 1] * wv.y
               + q1[b * 65 + h + 2] * wv.z + q1[b * 65 + h + 3] * wv.w;
        }
        q2[b * 65 + k] = a;
    }
    __syncthreads();
    for (int o = tid; o < 16 * 64; o += 256) {
        int b = o >> 6, h = o & 63;
        float a = 0.0f;
#pragma unroll 8
        for (int k = 0; k < 64; ++k)
            a += q2[b * 65 + k] * Wx[((size_t)nf * 64 + k) * 64 + h];
        qxg[((size_t)nf * 128 + cbase + b) * 64 + h] = a;
    }
    for (int b = tid; b < 16; b += 256) {
        float a = 0.0f;
        for (int k = 0; k < 64; ++k) a += q2[b * 65 + k] * bx[nf * 64 + k];
        qbg[nf * 128 + cbase + b] = a;
    }
}

// ---------------------------------------------------------------------------
// K1b: time attention + demo row + S zeroing. grid (77,128), block 128.
// nf<76: thread = t, bf16 h-row in registers, LDS reduce. nf==76: demo+zero.
// ---------------------------------------------------------------------------
__global__ __launch_bounds__(128) void k_att(
    const short* __restrict__ Hsg, const float* __restrict__ qxg,
    const float* __restrict__ qbg, const float* __restrict__ rate,
    const float* __restrict__ D, const float* __restrict__ dW,
    const float* __restrict__ db, float* __restrict__ Sz,
    float* __restrict__ Fin)
{
    const int nf = blockIdx.x, b = blockIdx.y;
    const int tid = threadIdx.x;

    if (nf == NF) {   // demo row + zero decov accumulators
        if (tid < 64) {
            float acc = db[tid];
            for (int j = 0; j < 12; ++j) acc += D[b * 12 + j] * dW[tid * 12 + j];
            Fin[((size_t)b * LQ + 76) * HD + tid] = tanh_fast(acc);
        }
        int s0 = b * 33;
        for (int k = tid; k < 33; k += 128) {
            int idx = s0 + k;
            if (idx < 4160) Sz[idx] = 0.0f;
        }
        return;
    }

    __shared__ float wsum[128 * 69];
    __shared__ float wl[128];
    __shared__ float qxl[64];
    __shared__ float pn[2][68];
    __shared__ float pd[2];
    if (tid < 64) qxl[tid] = qxg[((size_t)nf * 128 + b) * 64 + tid];
    const float qb = qbg[nf * 128 + b];
    const float sigr = sigmf(rate[nf]);

    uint4 rv[8];
    const uint4* src = (const uint4*)(Hsg + (((size_t)nf * 128 + b) * 128 + tid) * 64);
#pragma unroll
    for (int k = 0; k < 8; ++k) rv[k] = src[k];
    __syncthreads();

    float a = qb;
#pragma unroll
    for (int k = 0; k < 8; ++k) {
        a += bflo(rv[k].x) * qxl[k * 8 + 0] + bfhi(rv[k].x) * qxl[k * 8 + 1]
           + bflo(rv[k].y) * qxl[k * 8 + 2] + bfhi(rv[k].y) * qxl[k * 8 + 3]
           + bflo(rv[k].z) * qxl[k * 8 + 4] + bfhi(rv[k].z) * qxl[k * 8 + 5]
           + bflo(rv[k].w) * qxl[k * 8 + 6] + bfhi(rv[k].w) * qxl[k * 8 + 7];
    }
    float ds = sigmf(a);
    float dn = fmaxf(sigr * __logf(2.72f + (1.0f - ds)) * (float)(tid + 1), 1e-6f);
    float e = fmaxf(ds / dn, 0.0f);
    float w = __expf(e);                  // e in [0,2]: no max-shift needed
    wl[tid] = w;
#pragma unroll
    for (int k = 0; k < 8; ++k) {
        float* d = &wsum[tid * 69 + k * 8];
        d[0] = w * bflo(rv[k].x); d[1] = w * bfhi(rv[k].x);
        d[2] = w * bflo(rv[k].y); d[3] = w * bfhi(rv[k].y);
        d[4] = w * bflo(rv[k].z); d[5] = w * bfhi(rv[k].z);
        d[6] = w * bflo(rv[k].w); d[7] = w * bfhi(rv[k].w);
    }
    __syncthreads();
    {
        int ch = tid & 63, half = tid >> 6;
        float acc = 0.0f, den = 0.0f;
        int t0 = half * 64;
        for (int t = t0; t < t0 + 64; ++t) {
            acc += wsum[t * 69 + ch];
            den += wl[t];
        }
        pn[half][ch] = acc;
        if (ch == 0) pd[half] = den;
    }
    __syncthreads();
    if (tid < 64) {
        float num = pn[0][tid] + pn[1][tid];
        float den = pd[0] + pd[1];
        Fin[((size_t)b * LQ + nf) * HD + tid] = num / den;
    }
}

// ---------------------------------------------------------------------------
// K4: MHA per (b, head, variant). grid (128,4,2), block 256.
// K/V padded to stride 20 -> uniform-j float4 broadcast reads in the j-loop.
// ---------------------------------------------------------------------------
__global__ __launch_bounds__(256) void k_mha2(
    const float* __restrict__ Fin,
    const float* __restrict__ Wq, const float* __restrict__ bq,
    const float* __restrict__ Wk, const float* __restrict__ bk,
    const float* __restrict__ Wv, const float* __restrict__ bv,
    const float* __restrict__ g1, const float* __restrict__ b1,
    float* __restrict__ M1, float* __restrict__ M2)
{
    __shared__ float xl[LQ * 68];
    __shared__ float qh[LQ * 20], kh[LQ * 20], vh[LQ * 20];
    __shared__ float os[2][LQ][17];
    const int b = blockIdx.x, hd = blockIdx.y, v = blockIdx.z;
    const int tid = threadIdx.x;
    const float* xsrc = Fin + (size_t)b * LQ * HD;

    for (int idx = tid; idx < LQ * HD; idx += 256)
        xl[(idx >> 6) * 68 + (idx & 63)] = xsrc[idx];
    __syncthreads();
    if (v == 1) {
        if (tid < LQ) {
            float mu = 0.0f;
            for (int h = 0; h < 64; ++h) mu += xl[tid * 68 + h];
            mu *= (1.0f / 64.0f);
            float var = 0.0f;
            for (int h = 0; h < 64; ++h) { float d = xl[tid * 68 + h] - mu; var += d * d; }
            var *= (1.0f / 64.0f);
            float rs = rsqrtf(var + 1e-7f);
            for (int h = 0; h < 64; ++h)
                xl[tid * 68 + h] = (xl[tid * 68 + h] - mu) * rs * g1[h] + b1[h];
        }
        __syncthreads();
    }

    for (int idx = tid; idx < LQ * 16; idx += 256) {
        int l = idx >> 4, d = idx & 15, ch = hd * 16 + d;
        float aq = bq[ch], ak = bk[ch], av = bv[ch];
        const float4* wq = (const float4*)(Wq + ch * 64);
        const float4* wk = (const float4*)(Wk + ch * 64);
        const float4* wv = (const float4*)(Wv + ch * 64);
        const float4* xr = (const float4*)&xl[l * 68];
#pragma unroll 4
        for (int c4 = 0; c4 < 16; ++c4) {
            float4 xv = xr[c4];
            float4 a = wq[c4], bb = wk[c4], cc = wv[c4];
            aq += xv.x * a.x + xv.y * a.y + xv.z * a.z + xv.w * a.w;
            ak += xv.x * bb.x + xv.y * bb.y + xv.z * bb.z + xv.w * bb.w;
            av += xv.x * cc.x + xv.y * cc.y + xv.z * cc.z + xv.w * cc.w;
        }
        qh[l * 20 + d] = aq; kh[l * 20 + d] = ak; vh[l * 20 + d] = av;
    }
    __syncthreads();

    {
        int l = tid & 127, half = tid >> 7;
        if (l < LQ) {
            float4 qf0 = *(const float4*)&qh[l * 20 + 0];
            float4 qf1 = *(const float4*)&qh[l * 20 + 4];
            float4 qf2 = *(const float4*)&qh[l * 20 + 8];
            float4 qf3 = *(const float4*)&qh[l * 20 + 12];
            int j0 = half ? 39 : 0, j1 = half ? LQ : 39;
            float o[16];
#pragma unroll
            for (int d = 0; d < 16; ++d) o[d] = 0.0f;
            float ss = 0.0f;
            for (int j = j0; j < j1; ++j) {
                const float4* kp = (const float4*)&kh[j * 20];
                float4 k0 = kp[0], k1 = kp[1], k2 = kp[2], k3 = kp[3];
                float sc = qf0.x * k0.x + qf0.y * k0.y + qf0.z * k0.z + qf0.w * k0.w
                         + qf1.x * k1.x + qf1.y * k1.y + qf1.z * k1.z + qf1.w * k1.w
                         + qf2.x * k2.x + qf2.y * k2.y + qf2.z * k2.z + qf2.w * k2.w
                         + qf3.x * k3.x + qf3.y * k3.y + qf3.z * k3.z + qf3.w * k3.w;
                float p = __expf(sc * 0.25f);   // scores tiny: no max-shift
                ss += p;
                const float4* vp = (const float4*)&vh[j * 20];
                float4 v0 = vp[0], v1 = vp[1], v2 = vp[2], v3 = vp[3];
                o[0] += p * v0.x; o[1] += p * v0.y; o[2] += p * v0.z; o[3] += p * v0.w;
                o[4] += p * v1.x; o[5] += p * v1.y; o[6] += p * v1.z; o[7] += p * v1.w;
                o[8] += p * v2.x; o[9] += p * v2.y; o[10] += p * v2.z; o[11] += p * v2.w;
                o[12] += p * v3.x; o[13] += p * v3.y; o[14] += p * v3.z; o[15] += p * v3.w;
            }
#pragma unroll
            for (int d = 0; d < 16; ++d) os[half][l][d] = o[d];
            os[half][l][16] = ss;
        }
    }
    __syncthreads();
    if (tid < LQ) {
        float inv = 1.0f / (os[0][tid][16] + os[1][tid][16]);
        float* Mout = (v == 1) ? M2 : M1;
#pragma unroll
        for (int d = 0; d < 16; ++d)
            Mout[((size_t)b * LQ + tid) * HD + hd * 16 + d]
                = (os[0][tid][d] + os[1][tid][d]) * inv;
    }
}

// ---------------------------------------------------------------------------
// K5: fused tail per batch: Wo epilogue + cov atomics + LN2 + FFN + final
// attention + head. grid 128, block 256.
// ---------------------------------------------------------------------------
__global__ __launch_bounds__(256) void k_tail(
    const float* __restrict__ Fin, const float* __restrict__ M1,
    const float* __restrict__ M2, const float* __restrict__ Wo,
    const float* __restrict__ bo,
    const float* __restrict__ g2, const float* __restrict__ b2,
    const float* __restrict__ W1, const float* __restrict__ bb1,
    const float* __restrict__ W2, const float* __restrict__ bb2,
    const float* __restrict__ faWq, const float* __restrict__ fabq,
    const float* __restrict__ faWk, const float* __restrict__ fabk,
    const float* __restrict__ faWv, const float* __restrict__ fabv,
    const float* __restrict__ faWout, const float* __restrict__ fabout,
    const float* __restrict__ o0W, const float* __restrict__ o0b,
    const float* __restrict__ o1W, const float* __restrict__ o1b,
    float* __restrict__ S, float* __restrict__ MU, float* __restrict__ out)
{
    __shared__ float buf0[LQ * 68];   // M1 -> zl -> V
    __shared__ float buf1[LQ * 68];   // M2 -> ul(FFN) -> qk scores
    __shared__ float yl[LQ * 68];     // Y -> Z
    __shared__ float sc[LQ + 3];
    __shared__ float sv[64], h1[64];
    __shared__ float red0;
    const int b = blockIdx.x, tid = threadIdx.x;

    for (int idx = tid; idx < LQ * HD; idx += 256) {
        int l = idx >> 6, h = idx & 63;
        buf0[l * 68 + h] = M1[(size_t)b * LQ * HD + idx];
        buf1[l * 68 + h] = M2[(size_t)b * LQ * HD + idx];
    }
    __syncthreads();
    // Wo epilogue: yl = Fin + M2 Wo^T + bo
    for (int idx = tid; idx < LQ * HD; idx += 256) {
        int l = idx >> 6, h = idx & 63;
        float acc = bo[h];
        const float4* wo = (const float4*)(Wo + h * 64);
        const float4* mr = (const float4*)&buf1[l * 68];
#pragma unroll 4
        for (int c4 = 0; c4 < 16; ++c4) {
            float4 wv = wo[c4], mv = mr[c4];
            acc += mv.x * wv.x + mv.y * wv.y + mv.z * wv.z + mv.w * wv.w;
        }
        yl[l * 68 + h] = Fin[(size_t)b * LQ * HD + idx] + acc;
    }
    // cov atomics from M1 (buf0): thread owns (i, 16-wide j block)
    {
        int i = tid >> 2;
        int jb = (tid & 3) * 16;
        float acc[16];
#pragma unroll
        for (int k = 0; k < 16; ++k) acc[k] = 0.0f;
        for (int l = 0; l < LQ; ++l) {
            float ui = buf0[l * 68 + i];
            const float4* up = (const float4*)&buf0[l * 68 + jb];
            float4 u0 = up[0], u1 = up[1], u2 = up[2], u3 = up[3];
            acc[0] += ui * u0.x; acc[1] += ui * u0.y; acc[2] += ui * u0.z; acc[3] += ui * u0.w;
            acc[4] += ui * u1.x; acc[5] += ui * u1.y; acc[6] += ui * u1.z; acc[7] += ui * u1.w;
            acc[8] += ui * u2.x; acc[9] += ui * u2.y; acc[10] += ui * u2.z; acc[11] += ui * u2.w;
            acc[12] += ui * u3.x; acc[13] += ui * u3.y; acc[14] += ui * u3.z; acc[15] += ui * u3.w;
        }
#pragma unroll
        for (int k = 0; k < 16; ++k) atomicAdd(&S[i * 64 + jb + k], acc[k]);
    }
    if (tid < 64) {
        float acc = 0.0f;
        for (int l = 0; l < LQ; ++l) acc += buf0[l * 68 + tid];
        atomicAdd(&MU[tid], acc);
    }
    __syncthreads();
    // LN2: yl -> buf0 (zl)
    if (tid < LQ) {
        float mu = 0.0f;
        for (int h = 0; h < 64; ++h) mu += yl[tid * 68 + h];
        mu *= (1.0f / 64.0f);
        float var = 0.0f;
        for (int h = 0; h < 64; ++h) { float d = yl[tid * 68 + h] - mu; var += d * d; }
        var *= (1.0f / 64.0f);
        float rs = rsqrtf(var + 1e-7f);
        for (int h = 0; h < 64; ++h)
            buf0[tid * 68 + h] = (yl[tid * 68 + h] - mu) * rs * g2[h] + b2[h];
    }
    __syncthreads();
    // FFN in chunks of 16 rows; ul lives in buf1
    for (int l0 = 0; l0 < LQ; l0 += 16) {
        int nl = (LQ - l0 < 16) ? (LQ - l0) : 16;
        {   // W1: thread = f
            const int f = tid;
            float acc[16];
#pragma unroll
            for (int r = 0; r < 16; ++r) acc[r] = bb1[f];
            const float4* w1r = (const float4*)(W1 + f * 64);
#pragma unroll
            for (int c = 0; c < 4; ++c) {
                float4 w0 = w1r[c * 4 + 0], w1 = w1r[c * 4 + 1];
                float4 w2 = w1r[c * 4 + 2], w3 = w1r[c * 4 + 3];
#pragma unroll
                for (int r = 0; r < 16; ++r) {
                    int lr = l0 + r;
                    if (lr >= LQ) lr = LQ - 1;   // clamp: garbage rows unused
                    const float4* zr = (const float4*)&buf0[lr * 68 + c * 16];
                    float4 z0 = zr[0], z1 = zr[1], z2 = zr[2], z3 = zr[3];
                    acc[r] += z0.x * w0.x + z0.y * w0.y + z0.z * w0.z + z0.w * w0.w
                            + z1.x * w1.x + z1.y * w1.y + z1.z * w1.z + z1.w * w1.w
                            + z2.x * w2.x + z2.y * w2.y + z2.z * w2.z + z2.w * w2.w
                            + z3.x * w3.x + z3.y * w3.y + z3.z * w3.z + z3.w * w3.w;
                }
            }
#pragma unroll
            for (int r = 0; r < 16; ++r) buf1[r * 260 + f] = fmaxf(acc[r], 0.0f);
        }
        __syncthreads();
        {   // W2: thread = (h, 4 rows)
            const int h = tid & 63, rq = tid >> 6;
            float acc[4];
#pragma unroll
            for (int rr = 0; rr < 4; ++rr) acc[rr] = bb2[h];
            const float4* w2r = (const float4*)(W2 + h * 256);
#pragma unroll 4
            for (int c = 0; c < 16; ++c) {
                float4 w0 = w2r[c * 4 + 0], w1 = w2r[c * 4 + 1];
                float4 w2 = w2r[c * 4 + 2], w3 = w2r[c * 4 + 3];
#pragma unroll
                for (int rr = 0; rr < 4; ++rr) {
                    const float4* ur = (const float4*)&buf1[(rq * 4 + rr) * 260 + c * 16];
                    float4 u0 = ur[0], u1 = ur[1], u2 = ur[2], u3 = ur[3];
                    acc[rr] += u0.x * w0.x + u0.y * w0.y + u0.z * w0.z + u0.w * w0.w
                             + u1.x * w1.x + u1.y * w1.y + u1.z * w1.z + u1.w * w1.w
                             + u2.x * w2.x + u2.y * w2.y + u2.z * w2.z + u2.w * w2.w
                             + u3.x * w3.x + u3.y * w3.y + u3.z * w3.z + u3.w * w3.w;
                }
            }
#pragma unroll
            for (int rr = 0; rr < 4; ++rr) {
                int r = rq * 4 + rr;
                if (r < nl) yl[(l0 + r) * 68 + h] += acc[rr];   // Z = Y + FFN
            }
        }
        __syncthreads();
    }

    // FinalAttentionQKV from yl (=Z); scores -> buf1, V -> buf0
    for (int idx = tid; idx < LQ * HD; idx += 256) {
        int l = idx >> 6, h = idx & 63;
        float q = fabq[h], k = fabk[h], v = fabv[h];
        const float4* wq = (const float4*)(faWq + h * 64);
        const float4* wk = (const float4*)(faWk + h * 64);
        const float4* wv = (const float4*)(faWv + h * 64);
        const float4* zr = (const float4*)&yl[l * 68];
#pragma unroll 4
        for (int c4 = 0; c4 < 16; ++c4) {
            float4 zv = zr[c4];
            float4 a = wq[c4], bb = wk[c4], cc = wv[c4];
            q += zv.x * a.x + zv.y * a.y + zv.z * a.z + zv.w * a.w;
            k += zv.x * bb.x + zv.y * bb.y + zv.z * bb.z + zv.w * bb.w;
            v += zv.x * cc.x + zv.y * cc.y + zv.z * cc.z + zv.w * cc.w;
        }
        buf1[l * 65 + h] = q * k * faWout[h];
        buf0[l * 68 + h] = v;
    }
    __syncthreads();
    if (tid < LQ) {
        float acc = fabout[0];
        for (int h = 0; h < 64; ++h) acc += buf1[tid * 65 + h];
        sc[tid] = acc;
    }
    __syncthreads();
    if (tid < 64) {
        float v0 = sc[tid];
        float v1 = (tid < LQ - 64) ? sc[tid + 64] : -1e30f;
        float m = fmaxf(v0, v1);
        for (int o = 32; o; o >>= 1) m = fmaxf(m, __shfl_xor(m, o, 64));
        float e0 = __expf(v0 - m);
        float e1 = (tid < LQ - 64) ? __expf(v1 - m) : 0.0f;
        float s = e0 + e1;
        for (int o = 32; o; o >>= 1) s += __shfl_xor(s, o, 64);
        sc[tid] = e0;
        if (tid < LQ - 64) sc[tid + 64] = e1;
        if (tid == 0) red0 = s;
    }
    __syncthreads();
    if (tid < 64) {
        float acc = 0.0f;
        for (int l = 0; l < LQ; ++l) acc += sc[l] * buf0[l * 68 + tid];
        sv[tid] = acc / red0;
    }
    __syncthreads();
    if (tid < 64) {
        float acc = o0b[tid];
        const float* w = o0W + tid * 64;
#pragma unroll 8
        for (int c = 0; c < 64; ++c) acc += sv[c] * w[c];
        h1[tid] = fmaxf(acc, 0.0f);
    }
    __syncthreads();
    if (tid < 64) {
        float p = h1[tid] * o1W[tid];
        for (int o = 32; o; o >>= 1) p += __shfl_xor(p, o, 64);
        if (tid == 0) out[b] = sigmf(p + o1b[0]);
    }
}

__global__ void k_decov(const float* __restrict__ S, const float* __restrict__ MU,
                        float* __restrict__ out)
{
    int lane = threadIdx.x;
    const float invM = 1.0f / 9856.0f;
    float asum = 0.0f, dsum = 0.0f;
    for (int idx = lane; idx < 4096; idx += 64) {
        int i = idx >> 6, j = idx & 63;
        float c = S[idx] * invM - (MU[i] * invM) * (MU[j] * invM);
        asum += c * c;
        if (i == j) dsum += c * c;
    }
    for (int o = 32; o; o >>= 1) {
        asum += __shfl_xor(asum, o, 64);
        dsum += __shfl_xor(dsum, o, 64);
    }
    if (lane == 0) out[128] = 0.5f * (asum - dsum);
}

// ---------------------------------------------------------------------------
// Fallback path kernels (ws too small): R3-style fused GRU+attn, demo, zero.
// ---------------------------------------------------------------------------
__global__ void k_demo(const float* __restrict__ D, const float* __restrict__ dW,
                       const float* __restrict__ db, float* __restrict__ Fin)
{
    int b = blockIdx.x, h = threadIdx.x;
    float acc = db[h];
    for (int j = 0; j < 12; ++j) acc += D[b * 12 + j] * dW[h * 12 + j];
    Fin[((size_t)b * LQ + 76) * HD + h] = tanh_fast(acc);
}

__global__ void k_zero(float* __restrict__ p)
{
    for (int i = threadIdx.x; i < 4160; i += 256) p[i] = 0.0f;
}

__global__ __launch_bounds__(128) void k_gru_mfma(
    const float* __restrict__ X, const float* __restrict__ Wih,
    const float* __restrict__ Whh, const float* __restrict__ bih,
    const float* __restrict__ bhh,
    const float* __restrict__ Wt, const float* __restrict__ bt,
    const float* __restrict__ Wx, const float* __restrict__ bx,
    const float* __restrict__ rate, float* __restrict__ Fin)
{
    __shared__ short As[2][16 * 68];
    __shared__ float xs[16 * 129];
    __shared__ float q1[16 * 65];
    __shared__ float q2[16 * 65];
    __shared__ float qbs[16];
    __shared__ float dotw[2][2][16];

    const int nf = blockIdx.y;
    const int cbase = blockIdx.x * 16;
    const int tid = threadIdx.x;
    const int w = tid >> 6;
    const int lane = tid & 63;
    const int col = lane & 15;
    const int quad = lane >> 4;

    for (int i = tid; i < 16 * T_; i += 128) {
        int b = i >> 7, t = i & 127;
        xs[b * 129 + t] = X[((size_t)(cbase + b) * T_ + t) * NF + nf];
    }
    short8v bfr[3][2][2];
    const float* wbase = Whh + (size_t)nf * 12288;
#pragma unroll
    for (int g3 = 0; g3 < 3; ++g3)
#pragma unroll
        for (int s = 0; s < 2; ++s)
#pragma unroll
            for (int k2 = 0; k2 < 2; ++k2) {
                int g = 64 * g3 + 32 * w + 16 * s + col;
                const float* src = wbase + g * 64 + 32 * k2 + quad * 8;
                float4 f0 = *(const float4*)src;
                float4 f1 = *(const float4*)(src + 4);
                short8v fr;
                fr[0] = tobf(f0.x); fr[1] = tobf(f0.y); fr[2] = tobf(f0.z); fr[3] = tobf(f0.w);
                fr[4] = tobf(f1.x); fr[5] = tobf(f1.y); fr[6] = tobf(f1.z); fr[7] = tobf(f1.w);
                bfr[g3][s][k2] = fr;
            }
    float wr[2], wz[2], wn[2], br[2], bz[2], bnn[2], bhn[2];
#pragma unroll
    for (int s = 0; s < 2; ++s) {
        int c = 32 * w + 16 * s + col;
        int base = nf * 192;
        wr[s] = Wih[base + c]; wz[s] = Wih[base + 64 + c]; wn[s] = Wih[base + 128 + c];
        br[s] = bih[base + c] + bhh[base + c];
        bz[s] = bih[base + 64 + c] + bhh[base + 64 + c];
        bnn[s] = bih[base + 128 + c]; bhn[s] = bhh[base + 128 + c];
    }
    const float sigr = sigmf(rate[nf]);
    float hold[2][4], num[2][4], den[4], qxv[2][4], qbv[4];
#pragma unroll
    for (int r = 0; r < 4; ++r) {
        den[r] = 0.0f; qbv[r] = 0.0f;
        num[0][r] = 0.0f; num[1][r] = 0.0f;
        qxv[0][r] = 0.0f; qxv[1][r] = 0.0f;
    }
    for (int pass = 0; pass < 2; ++pass) {
        for (int i = tid; i < 16 * 68; i += 128) As[0][i] = 0;
#pragma unroll
        for (int s = 0; s < 2; ++s)
#pragma unroll
            for (int r = 0; r < 4; ++r) hold[s][r] = 0.0f;
        __syncthreads();
        for (int t = 0; t < T_; ++t) {
            const int rb = t & 1;
            const int wb = 1 - rb;
            const short* ap = &As[rb][col * 68 + quad * 8];
            short4v a0 = *(const short4v*)ap;
            short4v a1 = *(const short4v*)(ap + 4);
            short4v a2 = *(const short4v*)(ap + 32);
            short4v a3 = *(const short4v*)(ap + 36);
            short8v A0 = {a0[0], a0[1], a0[2], a0[3], a1[0], a1[1], a1[2], a1[3]};
            short8v A1 = {a2[0], a2[1], a2[2], a2[3], a3[0], a3[1], a3[2], a3[3]};
            f32x4 acc[3][2];
#pragma unroll
            for (int g3 = 0; g3 < 3; ++g3)
#pragma unroll
                for (int s = 0; s < 2; ++s) {
                    f32x4 a = {0.0f, 0.0f, 0.0f, 0.0f};
                    a = __builtin_amdgcn_mfma_f32_16x16x32_bf16(A0, bfr[g3][s][0], a, 0, 0, 0);
                    a = __builtin_amdgcn_mfma_f32_16x16x32_bf16(A1, bfr[g3][s][1], a, 0, 0, 0);
                    acc[g3][s] = a;
                }
            float xv[4];
#pragma unroll
            for (int r = 0; r < 4; ++r) xv[r] = xs[(quad * 4 + r) * 129 + t];
            float hnew[2][4];
#pragma unroll
            for (int s = 0; s < 2; ++s)
#pragma unroll
                for (int r = 0; r < 4; ++r) {
                    float rr = sigmf(xv[r] * wr[s] + br[s] + acc[0][s][r]);
                    float zz = sigmf(xv[r] * wz[s] + bz[s] + acc[1][s][r]);
                    float nn = tanh_fast(xv[r] * wn[s] + bnn[s] + rr * (acc[2][s][r] + bhn[s]));
                    hnew[s][r] = (1.0f - zz) * nn + zz * hold[s][r];
                    hold[s][r] = hnew[s][r];
                }
#pragma unroll
            for (int s = 0; s < 2; ++s)
#pragma unroll
                for (int r = 0; r < 4; ++r)
                    As[wb][(quad * 4 + r) * 68 + 32 * w + 16 * s + col] = tobf(hnew[s][r]);
            if (pass == 1) {
                float p[4];
#pragma unroll
                for (int r = 0; r < 4; ++r)
                    p[r] = qxv[0][r] * hnew[0][r] + qxv[1][r] * hnew[1][r];
#pragma unroll
                for (int m = 1; m < 16; m <<= 1) {
                    p[0] += __shfl_xor(p[0], m, 64);
                    p[1] += __shfl_xor(p[1], m, 64);
                    p[2] += __shfl_xor(p[2], m, 64);
                    p[3] += __shfl_xor(p[3], m, 64);
                }
                if (col == 0) {
#pragma unroll
                    for (int r = 0; r < 4; ++r) dotw[rb][w][quad * 4 + r] = p[r];
                }
                __syncthreads();
                float tf = (float)(t + 1);
#pragma unroll
                for (int r = 0; r < 4; ++r) {
                    float dot = p[r] + dotw[rb][1 - w][quad * 4 + r] + qbv[r];
                    float ds = sigmf(dot);
                    float dn = fmaxf(sigr * __logf(2.72f + (1.0f - ds)) * tf, 1e-6f);
                    float e = fmaxf(ds / dn, 0.0f);
                    float wt = __expf(e);
                    den[r] += wt;
                    num[0][r] += wt * hnew[0][r];
                    num[1][r] += wt * hnew[1][r];
                }
            } else {
                __syncthreads();
            }
        }
        if (pass == 0) {
#pragma unroll
            for (int s = 0; s < 2; ++s)
#pragma unroll
                for (int r = 0; r < 4; ++r)
                    q1[(quad * 4 + r) * 65 + 32 * w + 16 * s + col] = hold[s][r];
            __syncthreads();
            for (int o = tid; o < 16 * 64; o += 128) {
                int b = o >> 6, k = o & 63;
                const float* wrow = Wt + ((size_t)nf * 64 + k) * 64;
                float a = bt[nf * 64 + k];
#pragma unroll 8
                for (int h = 0; h < 64; h += 4) {
                    float4 wv = *(const float4*)&wrow[h];
                    a += q1[b * 65 + h] * wv.x + q1[b * 65 + h + 1] * wv.y
                       + q1[b * 65 + h + 2] * wv.z + q1[b * 65 + h + 3] * wv.w;
                }
                q2[b * 65 + k] = a;
            }
            __syncthreads();
            for (int o = tid; o < 16 * 64; o += 128) {
                int b = o >> 6, h = o & 63;
                float a = 0.0f;
#pragma unroll 8
                for (int k = 0; k < 64; ++k)
                    a += q2[b * 65 + k] * Wx[((size_t)nf * 64 + k) * 64 + h];
                q1[b * 65 + h] = a;
            }
            for (int b = tid; b < 16; b += 128) {
                float a = 0.0f;
                for (int k = 0; k < 64; ++k) a += q2[b * 65 + k] * bx[nf * 64 + k];
                qbs[b] = a;
            }
            __syncthreads();
#pragma unroll
            for (int r = 0; r < 4; ++r) {
                qbv[r] = qbs[quad * 4 + r];
#pragma unroll
                for (int s = 0; s < 2; ++s)
                    qxv[s][r] = q1[(quad * 4 + r) * 65 + 32 * w + 16 * s + col];
                den[r] = 0.0f; num[0][r] = 0.0f; num[1][r] = 0.0f;
            }
            __syncthreads();
        }
    }
#pragma unroll
    for (int s = 0; s < 2; ++s)
#pragma unroll
        for (int r = 0; r < 4; ++r) {
            int b = cbase + quad * 4 + r;
            int c = 32 * w + 16 * s + col;
            Fin[((size_t)b * LQ + nf) * HD + c] = num[s][r] / den[r];
        }
}

extern "C" void kernel_launch(void* const* d_in, const int* in_sizes, int n_in,
                              void* d_out, int out_size, void* d_ws, size_t ws_size,
                              hipStream_t stream)
{
    (void)in_sizes; (void)n_in; (void)out_size;
    const float* X     = (const float*)d_in[0];
    const float* D     = (const float*)d_in[1];
    const float* gWih  = (const float*)d_in[2];
    const float* gWhh  = (const float*)d_in[3];
    const float* gbih  = (const float*)d_in[4];
    const float* gbhh  = (const float*)d_in[5];
    const float* aWt   = (const float*)d_in[6];
    const float* abt   = (const float*)d_in[7];
    const float* aWx   = (const float*)d_in[8];
    const float* abx   = (const float*)d_in[9];
    const float* arate = (const float*)d_in[10];
    const float* dW    = (const float*)d_in[11];
    const float* db    = (const float*)d_in[12];
    const float* mWq   = (const float*)d_in[13]; const float* mbq = (const float*)d_in[14];
    const float* mWk   = (const float*)d_in[15]; const float* mbk = (const float*)d_in[16];
    const float* mWv   = (const float*)d_in[17]; const float* mbv = (const float*)d_in[18];
    const float* mWo   = (const float*)d_in[19]; const float* mbo = (const float*)d_in[20];
    const float* l1g   = (const float*)d_in[21]; const float* l1b = (const float*)d_in[22];
    const float* fW1   = (const float*)d_in[23]; const float* fb1 = (const float*)d_in[24];
    const float* fW2   = (const float*)d_in[25]; const float* fb2 = (const float*)d_in[26];
    const float* l2g   = (const float*)d_in[27]; const float* l2b = (const float*)d_in[28];
    const float* faWq  = (const float*)d_in[29]; const float* fabq = (const float*)d_in[30];
    const float* faWk  = (const float*)d_in[31]; const float* fabk = (const float*)d_in[32];
    const float* faWv  = (const float*)d_in[33]; const float* fabv = (const float*)d_in[34];
    const float* faWo  = (const float*)d_in[35]; const float* fabo = (const float*)d_in[36];
    const float* o0W   = (const float*)d_in[37]; const float* o0b  = (const float*)d_in[38];
    const float* o1W   = (const float*)d_in[39]; const float* o1b  = (const float*)d_in[40];

    float* ws  = (float*)d_ws;
    float* Fin = ws;                               // 630,784
    float* M1  = Fin + 630784;                     // 630,784
    float* M2  = M1  + 630784;                     // 630,784
    float* S   = M2  + 630784;                     // 4096 (+64 MU)
    float* MU  = S   + 4096;                       // 64
    float* qxg = MU  + 64;                         // 622,592
    float* qbg = qxg + 622592;                     // 9,728
    short* Hsg = (short*)(qbg + 9728);             // 79,691,776 shorts (bf16)
    const size_t need = (size_t)(630784 * 3 + 4096 + 64 + 622592 + 9728) * 4
                        + (size_t)79691776 * 2;
    float* outp = (float*)d_out;

    if (ws_size >= need) {
        k_gru0<<<dim3(8, NF), 256, 0, stream>>>(X, gWih, gWhh, gbih, gbhh,
                                                aWt, abt, aWx, abx, Hsg, qxg, qbg);
        k_att<<<dim3(NF + 1, B_), 128, 0, stream>>>(Hsg, qxg, qbg, arate,
                                                    D, dW, db, S, Fin);
    } else {
        k_gru_mfma<<<dim3(8, NF), 128, 0, stream>>>(X, gWih, gWhh, gbih, gbhh,
                                                    aWt, abt, aWx, abx, arate, Fin);
        k_demo<<<B_, 64, 0, stream>>>(D, dW, db, Fin);
        k_zero<<<1, 256, 0, stream>>>(S);
    }
    k_mha2<<<dim3(B_, 4, 2), 256, 0, stream>>>(Fin, mWq, mbq, mWk, mbk, mWv, mbv,
                                               l1g, l1b, M1, M2);
    k_tail<<<B_, 256, 0, stream>>>(Fin, M1, M2, mWo, mbo, l2g, l2b,
                                   fW1, fb1, fW2, fb2,
                                   faWq, fabq, faWk, fabk, faWv, fabv,
                                   faWo, fabo, o0W, o0b, o1W, o1b, S, MU, outp);
    k_decov<<<1, 64, 0, stream>>>(S, MU, outp);
}

// Round 9
// 621.869 us; speedup vs baseline: 1.3954x; 1.2817x over previous
//
#include <hip/hip_runtime.h>
#include <math.h>

#define B_ 128
#define T_ 128
#define NF 76
#define HD 64
#define LQ 77

typedef __attribute__((ext_vector_type(8))) short short8v;
typedef __attribute__((ext_vector_type(4))) short short4v;
typedef __attribute__((ext_vector_type(4))) float f32x4;

__device__ __forceinline__ float sigmf(float x) { return 1.0f / (1.0f + __expf(-x)); }
__device__ __forceinline__ float tanh_fast(float x) { return 2.0f / (1.0f + __expf(-2.0f * x)) - 1.0f; }
__device__ __forceinline__ short tobf(float x) {
    unsigned u = __float_as_uint(x);
    u += 0x7FFF + ((u >> 16) & 1);   // RNE to bf16
    return (short)(u >> 16);
}
__device__ __forceinline__ float bflo(unsigned u) { return __uint_as_float(u << 16); }
__device__ __forceinline__ float bfhi(unsigned u) { return __uint_as_float(u & 0xffff0000u); }

// ---------------------------------------------------------------------------
// K1a: GRU recurrence via MFMA (R8 structure, unchanged).
// ---------------------------------------------------------------------------
__global__ __launch_bounds__(256) void k_gru0(
    const float* __restrict__ X, const float* __restrict__ Wih,
    const float* __restrict__ Whh, const float* __restrict__ bih,
    const float* __restrict__ bhh,
    const float* __restrict__ Wt, const float* __restrict__ bt,
    const float* __restrict__ Wx, const float* __restrict__ bx,
    short* __restrict__ Hsg, float* __restrict__ qxg, float* __restrict__ qbg)
{
    __shared__ short As[2][16 * 72];
    __shared__ float xs[16 * 129];
    __shared__ float q1[16 * 65];
    __shared__ float q2[16 * 65];

    const int nf = blockIdx.y;
    const int chunk = blockIdx.x;
    const int cbase = chunk * 16;
    const int tid = threadIdx.x;
    const int w = tid >> 6;
    const int lane = tid & 63;
    const int col = lane & 15;
    const int quad = lane >> 4;

    for (int i = tid; i < 16 * T_; i += 256) {
        int b = i >> 7, t = i & 127;
        xs[b * 129 + t] = X[((size_t)(cbase + b) * T_ + t) * NF + nf];
    }

    short8v bfr[3][2];
    const float* wbase = Whh + (size_t)nf * 12288;
#pragma unroll
    for (int g3 = 0; g3 < 3; ++g3)
#pragma unroll
        for (int k2 = 0; k2 < 2; ++k2) {
            int g = 64 * g3 + 16 * w + col;
            const float* src = wbase + g * 64 + 32 * k2 + quad * 8;
            float4 f0 = *(const float4*)src;
            float4 f1 = *(const float4*)(src + 4);
            short8v fr;
            fr[0] = tobf(f0.x); fr[1] = tobf(f0.y); fr[2] = tobf(f0.z); fr[3] = tobf(f0.w);
            fr[4] = tobf(f1.x); fr[5] = tobf(f1.y); fr[6] = tobf(f1.z); fr[7] = tobf(f1.w);
            bfr[g3][k2] = fr;
        }

    const int c = 16 * w + col;
    const int base = nf * 192;
    const float wr = Wih[base + c], wz = Wih[base + 64 + c], wn = Wih[base + 128 + c];
    const float br = bih[base + c] + bhh[base + c];
    const float bz = bih[base + 64 + c] + bhh[base + 64 + c];
    const float bnn = bih[base + 128 + c], bhn = bhh[base + 128 + c];

    for (int i = tid; i < 16 * 72; i += 256) As[0][i] = 0;
    float hold[4];
#pragma unroll
    for (int r = 0; r < 4; ++r) hold[r] = 0.0f;
    __syncthreads();

    const int crow = tid >> 4, cs = tid & 15;

    for (int t = 0; t < T_; ++t) {
        const int rb = t & 1;
        const int wb = 1 - rb;
        short8v A0 = *(const short8v*)&As[rb][col * 72 + quad * 8];
        short8v A1 = *(const short8v*)&As[rb][col * 72 + 32 + quad * 8];

        f32x4 acc[3];
#pragma unroll
        for (int g3 = 0; g3 < 3; ++g3) {
            f32x4 a = {0.0f, 0.0f, 0.0f, 0.0f};
            a = __builtin_amdgcn_mfma_f32_16x16x32_bf16(A0, bfr[g3][0], a, 0, 0, 0);
            a = __builtin_amdgcn_mfma_f32_16x16x32_bf16(A1, bfr[g3][1], a, 0, 0, 0);
            acc[g3] = a;
        }

#pragma unroll
        for (int r = 0; r < 4; ++r) {
            float xv = xs[(quad * 4 + r) * 129 + t];
            float rr = sigmf(xv * wr + br + acc[0][r]);
            float zz = sigmf(xv * wz + bz + acc[1][r]);
            float nn = tanh_fast(xv * wn + bnn + rr * (acc[2][r] + bhn));
            hold[r] = (1.0f - zz) * nn + zz * hold[r];
        }

#pragma unroll
        for (int r = 0; r < 4; ++r)
            As[wb][(quad * 4 + r) * 72 + c] = tobf(hold[r]);
        __syncthreads();
        {
            uint2 pk = *(const uint2*)&As[wb][crow * 72 + cs * 4];
            size_t go = (((size_t)nf * 128 + cbase + crow) * 128 + t) * 64 + cs * 4;
            *(uint2*)(Hsg + go) = pk;
        }
    }

#pragma unroll
    for (int r = 0; r < 4; ++r)
        q1[(quad * 4 + r) * 65 + c] = hold[r];
    __syncthreads();
    for (int o = tid; o < 16 * 64; o += 256) {
        int b = o >> 6, k = o & 63;
        const float* wrow = Wt + ((size_t)nf * 64 + k) * 64;
        float a = bt[nf * 64 + k];
#pragma unroll 8
        for (int h = 0; h < 64; h += 4) {
            float4 wv = *(const float4*)&wrow[h];
            a += q1[b * 65 + h] * wv.x + q1[b * 65 + h + 1] * wv.y
               + q1[b * 65 + h + 2] * wv.z + q1[b * 65 + h + 3] * wv.w;
        }
        q2[b * 65 + k] = a;
    }
    __syncthreads();
    for (int o = tid; o < 16 * 64; o += 256) {
        int b = o >> 6, h = o & 63;
        float a = 0.0f;
#pragma unroll 8
        for (int k = 0; k < 64; ++k)
            a += q2[b * 65 + k] * Wx[((size_t)nf * 64 + k) * 64 + h];
        qxg[((size_t)nf * 128 + cbase + b) * 64 + h] = a;
    }
    for (int b = tid; b < 16; b += 256) {
        float a = 0.0f;
        for (int k = 0; k < 64; ++k) a += q2[b * 65 + k] * bx[nf * 64 + k];
        qbg[nf * 128 + cbase + b] = a;
    }
}

// ---------------------------------------------------------------------------
// K1b: time attention + demo row + S/MU/counter zeroing. grid (77,128).
// ---------------------------------------------------------------------------
__global__ __launch_bounds__(128) void k_att(
    const short* __restrict__ Hsg, const float* __restrict__ qxg,
    const float* __restrict__ qbg, const float* __restrict__ rate,
    const float* __restrict__ D, const float* __restrict__ dW,
    const float* __restrict__ db, float* __restrict__ Sz,
    float* __restrict__ Fin)
{
    const int nf = blockIdx.x, b = blockIdx.y;
    const int tid = threadIdx.x;

    if (nf == NF) {   // demo row + zero S(4096)+MU(64)+counter(1)
        if (tid < 64) {
            float acc = db[tid];
            for (int j = 0; j < 12; ++j) acc += D[b * 12 + j] * dW[tid * 12 + j];
            Fin[((size_t)b * LQ + 76) * HD + tid] = tanh_fast(acc);
        }
        int s0 = b * 33;
        for (int k = tid; k < 33; k += 128) {
            int idx = s0 + k;
            if (idx < 4161) Sz[idx] = 0.0f;
        }
        return;
    }

    __shared__ float wsum[128 * 69];
    __shared__ float wl[128];
    __shared__ float qxl[64];
    __shared__ float pn[2][68];
    __shared__ float pd[2];
    if (tid < 64) qxl[tid] = qxg[((size_t)nf * 128 + b) * 64 + tid];
    const float qb = qbg[nf * 128 + b];
    const float sigr = sigmf(rate[nf]);

    uint4 rv[8];
    const uint4* src = (const uint4*)(Hsg + (((size_t)nf * 128 + b) * 128 + tid) * 64);
#pragma unroll
    for (int k = 0; k < 8; ++k) rv[k] = src[k];
    __syncthreads();

    float a = qb;
#pragma unroll
    for (int k = 0; k < 8; ++k) {
        a += bflo(rv[k].x) * qxl[k * 8 + 0] + bfhi(rv[k].x) * qxl[k * 8 + 1]
           + bflo(rv[k].y) * qxl[k * 8 + 2] + bfhi(rv[k].y) * qxl[k * 8 + 3]
           + bflo(rv[k].z) * qxl[k * 8 + 4] + bfhi(rv[k].z) * qxl[k * 8 + 5]
           + bflo(rv[k].w) * qxl[k * 8 + 6] + bfhi(rv[k].w) * qxl[k * 8 + 7];
    }
    float ds = sigmf(a);
    float dn = fmaxf(sigr * __logf(2.72f + (1.0f - ds)) * (float)(tid + 1), 1e-6f);
    float e = fmaxf(ds / dn, 0.0f);
    float w = __expf(e);
    wl[tid] = w;
#pragma unroll
    for (int k = 0; k < 8; ++k) {
        float* d = &wsum[tid * 69 + k * 8];
        d[0] = w * bflo(rv[k].x); d[1] = w * bfhi(rv[k].x);
        d[2] = w * bflo(rv[k].y); d[3] = w * bfhi(rv[k].y);
        d[4] = w * bflo(rv[k].z); d[5] = w * bfhi(rv[k].z);
        d[6] = w * bflo(rv[k].w); d[7] = w * bfhi(rv[k].w);
    }
    __syncthreads();
    {
        int ch = tid & 63, half = tid >> 6;
        float acc = 0.0f, den = 0.0f;
        int t0 = half * 64;
        for (int t = t0; t < t0 + 64; ++t) {
            acc += wsum[t * 69 + ch];
            den += wl[t];
        }
        pn[half][ch] = acc;
        if (ch == 0) pd[half] = den;
    }
    __syncthreads();
    if (tid < 64) {
        float num = pn[0][tid] + pn[1][tid];
        float den = pd[0] + pd[1];
        Fin[((size_t)b * LQ + nf) * HD + tid] = num / den;
    }
}

// ---------------------------------------------------------------------------
// K4: MHA per (b, head, variant). grid (128,4,2), block 256. (R8, unchanged)
// ---------------------------------------------------------------------------
__global__ __launch_bounds__(256) void k_mha2(
    const float* __restrict__ Fin,
    const float* __restrict__ Wq, const float* __restrict__ bq,
    const float* __restrict__ Wk, const float* __restrict__ bk,
    const float* __restrict__ Wv, const float* __restrict__ bv,
    const float* __restrict__ g1, const float* __restrict__ b1,
    float* __restrict__ M1, float* __restrict__ M2)
{
    __shared__ float xl[LQ * 68];
    __shared__ float qh[LQ * 20], kh[LQ * 20], vh[LQ * 20];
    __shared__ float os[2][LQ][17];
    const int b = blockIdx.x, hd = blockIdx.y, v = blockIdx.z;
    const int tid = threadIdx.x;
    const float* xsrc = Fin + (size_t)b * LQ * HD;

    for (int idx = tid; idx < LQ * HD; idx += 256)
        xl[(idx >> 6) * 68 + (idx & 63)] = xsrc[idx];
    __syncthreads();
    if (v == 1) {
        if (tid < LQ) {
            float mu = 0.0f;
            for (int h = 0; h < 64; ++h) mu += xl[tid * 68 + h];
            mu *= (1.0f / 64.0f);
            float var = 0.0f;
            for (int h = 0; h < 64; ++h) { float d = xl[tid * 68 + h] - mu; var += d * d; }
            var *= (1.0f / 64.0f);
            float rs = rsqrtf(var + 1e-7f);
            for (int h = 0; h < 64; ++h)
                xl[tid * 68 + h] = (xl[tid * 68 + h] - mu) * rs * g1[h] + b1[h];
        }
        __syncthreads();
    }

    for (int idx = tid; idx < LQ * 16; idx += 256) {
        int l = idx >> 4, d = idx & 15, ch = hd * 16 + d;
        float aq = bq[ch], ak = bk[ch], av = bv[ch];
        const float4* wq = (const float4*)(Wq + ch * 64);
        const float4* wk = (const float4*)(Wk + ch * 64);
        const float4* wv = (const float4*)(Wv + ch * 64);
        const float4* xr = (const float4*)&xl[l * 68];
#pragma unroll 4
        for (int c4 = 0; c4 < 16; ++c4) {
            float4 xv = xr[c4];
            float4 a = wq[c4], bb = wk[c4], cc = wv[c4];
            aq += xv.x * a.x + xv.y * a.y + xv.z * a.z + xv.w * a.w;
            ak += xv.x * bb.x + xv.y * bb.y + xv.z * bb.z + xv.w * bb.w;
            av += xv.x * cc.x + xv.y * cc.y + xv.z * cc.z + xv.w * cc.w;
        }
        qh[l * 20 + d] = aq; kh[l * 20 + d] = ak; vh[l * 20 + d] = av;
    }
    __syncthreads();

    {
        int l = tid & 127, half = tid >> 7;
        if (l < LQ) {
            float4 qf0 = *(const float4*)&qh[l * 20 + 0];
            float4 qf1 = *(const float4*)&qh[l * 20 + 4];
            float4 qf2 = *(const float4*)&qh[l * 20 + 8];
            float4 qf3 = *(const float4*)&qh[l * 20 + 12];
            int j0 = half ? 39 : 0, j1 = half ? LQ : 39;
            float o[16];
#pragma unroll
            for (int d = 0; d < 16; ++d) o[d] = 0.0f;
            float ss = 0.0f;
            for (int j = j0; j < j1; ++j) {
                const float4* kp = (const float4*)&kh[j * 20];
                float4 k0 = kp[0], k1 = kp[1], k2 = kp[2], k3 = kp[3];
                float sc = qf0.x * k0.x + qf0.y * k0.y + qf0.z * k0.z + qf0.w * k0.w
                         + qf1.x * k1.x + qf1.y * k1.y + qf1.z * k1.z + qf1.w * k1.w
                         + qf2.x * k2.x + qf2.y * k2.y + qf2.z * k2.z + qf2.w * k2.w
                         + qf3.x * k3.x + qf3.y * k3.y + qf3.z * k3.z + qf3.w * k3.w;
                float p = __expf(sc * 0.25f);
                ss += p;
                const float4* vp = (const float4*)&vh[j * 20];
                float4 v0 = vp[0], v1 = vp[1], v2 = vp[2], v3 = vp[3];
                o[0] += p * v0.x; o[1] += p * v0.y; o[2] += p * v0.z; o[3] += p * v0.w;
                o[4] += p * v1.x; o[5] += p * v1.y; o[6] += p * v1.z; o[7] += p * v1.w;
                o[8] += p * v2.x; o[9] += p * v2.y; o[10] += p * v2.z; o[11] += p * v2.w;
                o[12] += p * v3.x; o[13] += p * v3.y; o[14] += p * v3.z; o[15] += p * v3.w;
            }
#pragma unroll
            for (int d = 0; d < 16; ++d) os[half][l][d] = o[d];
            os[half][l][16] = ss;
        }
    }
    __syncthreads();
    if (tid < LQ) {
        float inv = 1.0f / (os[0][tid][16] + os[1][tid][16]);
        float* Mout = (v == 1) ? M2 : M1;
#pragma unroll
        for (int d = 0; d < 16; ++d)
            Mout[((size_t)b * LQ + tid) * HD + hd * 16 + d]
                = (os[0][tid][d] + os[1][tid][d]) * inv;
    }
}

// ---------------------------------------------------------------------------
// K5: row-parallel fused Y + LN2 + FFN + final-QKV + score. grid 616 (16 rows),
// block 256. V overwrites M2 rows (read first); scores -> scout.
// ---------------------------------------------------------------------------
__global__ __launch_bounds__(256) void k_zff(
    const float* __restrict__ Fin, float* __restrict__ M2,
    const float* __restrict__ Wo, const float* __restrict__ bo,
    const float* __restrict__ g2, const float* __restrict__ b2,
    const float* __restrict__ W1, const float* __restrict__ bb1,
    const float* __restrict__ W2, const float* __restrict__ bb2,
    const float* __restrict__ faWq, const float* __restrict__ fabq,
    const float* __restrict__ faWk, const float* __restrict__ fabk,
    const float* __restrict__ faWv, const float* __restrict__ fabv,
    const float* __restrict__ faWout, const float* __restrict__ fabout,
    float* __restrict__ scout)
{
    __shared__ float m2l[16 * 68];
    __shared__ float yl[16 * 68];     // Y, then Z
    __shared__ float zl[16 * 68];     // LN2(Y)
    __shared__ float ul[16 * 260];    // FFN hidden; then qk products (stride 68)
    const int tid = threadIdx.x;
    const size_t base = (size_t)blockIdx.x * 16;   // global row base
    const size_t eb = base * 64;
    const int h = tid & 63, rq = tid >> 6;

    for (int idx = tid; idx < 1024; idx += 256)
        m2l[(idx >> 6) * 68 + (idx & 63)] = M2[eb + idx];
    __syncthreads();

    {   // Y = Fin + M2 Wo^T + bo
        float acc[4];
#pragma unroll
        for (int rr = 0; rr < 4; ++rr) acc[rr] = bo[h];
        const float4* wo = (const float4*)(Wo + h * 64);
#pragma unroll 4
        for (int c4 = 0; c4 < 16; ++c4) {
            float4 wv = wo[c4];
#pragma unroll
            for (int rr = 0; rr < 4; ++rr) {
                float4 mv = *(const float4*)&m2l[(rq * 4 + rr) * 68 + c4 * 4];
                acc[rr] += mv.x * wv.x + mv.y * wv.y + mv.z * wv.z + mv.w * wv.w;
            }
        }
#pragma unroll
        for (int rr = 0; rr < 4; ++rr) {
            int r = rq * 4 + rr;
            yl[r * 68 + h] = Fin[eb + r * 64 + h] + acc[rr];
        }
    }
    __syncthreads();
    if (tid < 16) {   // LN2
        float mu = 0.0f;
        for (int c = 0; c < 64; ++c) mu += yl[tid * 68 + c];
        mu *= (1.0f / 64.0f);
        float var = 0.0f;
        for (int c = 0; c < 64; ++c) { float d = yl[tid * 68 + c] - mu; var += d * d; }
        var *= (1.0f / 64.0f);
        float rs = rsqrtf(var + 1e-7f);
        for (int c = 0; c < 64; ++c)
            zl[tid * 68 + c] = (yl[tid * 68 + c] - mu) * rs * g2[c] + b2[c];
    }
    __syncthreads();

    {   // FFN W1: thread = f
        const int f = tid;
        float acc[16];
#pragma unroll
        for (int r = 0; r < 16; ++r) acc[r] = bb1[f];
        const float4* w1r = (const float4*)(W1 + f * 64);
#pragma unroll
        for (int c = 0; c < 4; ++c) {
            float4 w0 = w1r[c * 4 + 0], w1 = w1r[c * 4 + 1];
            float4 w2 = w1r[c * 4 + 2], w3 = w1r[c * 4 + 3];
#pragma unroll
            for (int r = 0; r < 16; ++r) {
                const float4* zr = (const float4*)&zl[r * 68 + c * 16];
                float4 z0 = zr[0], z1 = zr[1], z2 = zr[2], z3 = zr[3];
                acc[r] += z0.x * w0.x + z0.y * w0.y + z0.z * w0.z + z0.w * w0.w
                        + z1.x * w1.x + z1.y * w1.y + z1.z * w1.z + z1.w * w1.w
                        + z2.x * w2.x + z2.y * w2.y + z2.z * w2.z + z2.w * w2.w
                        + z3.x * w3.x + z3.y * w3.y + z3.z * w3.z + z3.w * w3.w;
            }
        }
#pragma unroll
        for (int r = 0; r < 16; ++r) ul[r * 260 + f] = fmaxf(acc[r], 0.0f);
    }
    __syncthreads();
    {   // FFN W2: thread (h, 4 rows) -> Z in yl
        float acc[4];
#pragma unroll
        for (int rr = 0; rr < 4; ++rr) acc[rr] = bb2[h];
        const float4* w2r = (const float4*)(W2 + h * 256);
#pragma unroll 4
        for (int c = 0; c < 16; ++c) {
            float4 w0 = w2r[c * 4 + 0], w1 = w2r[c * 4 + 1];
            float4 w2 = w2r[c * 4 + 2], w3 = w2r[c * 4 + 3];
#pragma unroll
            for (int rr = 0; rr < 4; ++rr) {
                const float4* ur = (const float4*)&ul[(rq * 4 + rr) * 260 + c * 16];
                float4 u0 = ur[0], u1 = ur[1], u2 = ur[2], u3 = ur[3];
                acc[rr] += u0.x * w0.x + u0.y * w0.y + u0.z * w0.z + u0.w * w0.w
                         + u1.x * w1.x + u1.y * w1.y + u1.z * w1.z + u1.w * w1.w
                         + u2.x * w2.x + u2.y * w2.y + u2.z * w2.z + u2.w * w2.w
                         + u3.x * w3.x + u3.y * w3.y + u3.z * w3.z + u3.w * w3.w;
            }
        }
#pragma unroll
        for (int rr = 0; rr < 4; ++rr)
            yl[(rq * 4 + rr) * 68 + h] += acc[rr];
    }
    __syncthreads();

    {   // final QKV: per (row,h) compute q,k,v; qk -> ul (stride 68); V -> M2
        const float4* wq = (const float4*)(faWq + h * 64);
        const float4* wk = (const float4*)(faWk + h * 64);
        const float4* wv = (const float4*)(faWv + h * 64);
        float q[4], k[4], v[4];
#pragma unroll
        for (int rr = 0; rr < 4; ++rr) { q[rr] = fabq[h]; k[rr] = fabk[h]; v[rr] = fabv[h]; }
#pragma unroll 4
        for (int c4 = 0; c4 < 16; ++c4) {
            float4 a = wq[c4], bb = wk[c4], cc = wv[c4];
#pragma unroll
            for (int rr = 0; rr < 4; ++rr) {
                float4 zv = *(const float4*)&yl[(rq * 4 + rr) * 68 + c4 * 4];
                q[rr] += zv.x * a.x + zv.y * a.y + zv.z * a.z + zv.w * a.w;
                k[rr] += zv.x * bb.x + zv.y * bb.y + zv.z * bb.z + zv.w * bb.w;
                v[rr] += zv.x * cc.x + zv.y * cc.y + zv.z * cc.z + zv.w * cc.w;
            }
        }
        float fw = faWout[h];
#pragma unroll
        for (int rr = 0; rr < 4; ++rr) {
            int r = rq * 4 + rr;
            ul[r * 68 + h] = q[rr] * k[rr] * fw;
            M2[eb + r * 64 + h] = v[rr];   // V overwrites M2 rows (already consumed)
        }
    }
    __syncthreads();
    if (tid < 16) {
        float a = fabout[0];
        for (int c = 0; c < 64; ++c) a += ul[tid * 68 + c];
        scout[base + tid] = a;
    }
}

// ---------------------------------------------------------------------------
// K6: covariance accumulators + last-block decov. grid (16,8), block 256.
// ---------------------------------------------------------------------------
__global__ __launch_bounds__(256) void k_cov(
    const float* __restrict__ M1, float* __restrict__ S, float* __restrict__ MU,
    unsigned* __restrict__ cnt, float* __restrict__ out)
{
    const int tid = threadIdx.x;
    const int ig = tid >> 6, j = tid & 63;
    const int i = blockIdx.x * 4 + ig;
    const int l0 = blockIdx.y * 1232, l1 = l0 + 1232;
    float acc = 0.0f, mua = 0.0f;
    for (int l = l0; l < l1; ++l) {
        float v = M1[(size_t)l * 64 + j];
        acc += M1[(size_t)l * 64 + i] * v;
        mua += v;
    }
    atomicAdd(&S[i * 64 + j], acc);
    if (blockIdx.x == 0 && ig == 0) atomicAdd(&MU[j], mua);
    __threadfence();
    __syncthreads();
    __shared__ int last;
    if (tid == 0) last = (atomicAdd(cnt, 1u) == 127u);
    __syncthreads();
    if (last) {
        __shared__ float mus[64];
        __shared__ float pa[4], pd[4];
        if (tid < 64) mus[tid] = atomicAdd(&MU[tid], 0.0f);
        __syncthreads();
        const float invM = 1.0f / 9856.0f;
        float asum = 0.0f, dsum = 0.0f;
        for (int idx = tid; idx < 4096; idx += 256) {
            int ii = idx >> 6, jj = idx & 63;
            float c = atomicAdd(&S[idx], 0.0f) * invM - (mus[ii] * invM) * (mus[jj] * invM);
            asum += c * c;
            if (ii == jj) dsum += c * c;
        }
        for (int o = 32; o; o >>= 1) {
            asum += __shfl_xor(asum, o, 64);
            dsum += __shfl_xor(dsum, o, 64);
        }
        if ((tid & 63) == 0) { pa[tid >> 6] = asum; pd[tid >> 6] = dsum; }
        __syncthreads();
        if (tid == 0)
            out[128] = 0.5f * ((pa[0] + pa[1] + pa[2] + pa[3])
                             - (pd[0] + pd[1] + pd[2] + pd[3]));
    }
}

// ---------------------------------------------------------------------------
// K7: final softmax + s = alpha.V + output head. grid 128, block 128.
// ---------------------------------------------------------------------------
__global__ __launch_bounds__(128) void k_head(
    const float* __restrict__ Vg, const float* __restrict__ scout,
    const float* __restrict__ o0W, const float* __restrict__ o0b,
    const float* __restrict__ o1W, const float* __restrict__ o1b,
    float* __restrict__ out)
{
    __shared__ float sl[LQ + 3];
    __shared__ float pn[2][64];
    __shared__ float sv[64], h1[64];
    __shared__ float red0;
    const int b = blockIdx.x, tid = threadIdx.x;

    if (tid < LQ) sl[tid] = scout[b * LQ + tid];
    __syncthreads();
    if (tid < 64) {
        float v0 = sl[tid];
        float v1 = (tid < LQ - 64) ? sl[tid + 64] : -1e30f;
        float m = fmaxf(v0, v1);
        for (int o = 32; o; o >>= 1) m = fmaxf(m, __shfl_xor(m, o, 64));
        float e0 = __expf(v0 - m);
        float e1 = (tid < LQ - 64) ? __expf(v1 - m) : 0.0f;
        float s = e0 + e1;
        for (int o = 32; o; o >>= 1) s += __shfl_xor(s, o, 64);
        sl[tid] = e0;
        if (tid < LQ - 64) sl[tid + 64] = e1;
        if (tid == 0) red0 = s;
    }
    __syncthreads();
    {
        int h = tid & 63, half = tid >> 6;
        int l0 = half ? 39 : 0, l1 = half ? LQ : 39;
        float acc = 0.0f;
        for (int l = l0; l < l1; ++l)
            acc += sl[l] * Vg[((size_t)b * LQ + l) * 64 + h];
        pn[half][h] = acc;
    }
    __syncthreads();
    if (tid < 64) sv[tid] = (pn[0][tid] + pn[1][tid]) / red0;
    __syncthreads();
    if (tid < 64) {
        float acc = o0b[tid];
        const float4* w = (const float4*)(o0W + tid * 64);
#pragma unroll 4
        for (int c4 = 0; c4 < 16; ++c4) {
            float4 wv = w[c4];
            const float4* sp = (const float4*)&sv[c4 * 4];
            float4 s0 = sp[0];
            acc += s0.x * wv.x + s0.y * wv.y + s0.z * wv.z + s0.w * wv.w;
        }
        h1[tid] = fmaxf(acc, 0.0f);
    }
    __syncthreads();
    if (tid < 64) {
        float p = h1[tid] * o1W[tid];
        for (int o = 32; o; o >>= 1) p += __shfl_xor(p, o, 64);
        if (tid == 0) out[b] = sigmf(p + o1b[0]);
    }
}

// ---------------------------------------------------------------------------
// Fallback path kernels (ws too small).
// ---------------------------------------------------------------------------
__global__ void k_demo(const float* __restrict__ D, const float* __restrict__ dW,
                       const float* __restrict__ db, float* __restrict__ Fin)
{
    int b = blockIdx.x, h = threadIdx.x;
    float acc = db[h];
    for (int j = 0; j < 12; ++j) acc += D[b * 12 + j] * dW[h * 12 + j];
    Fin[((size_t)b * LQ + 76) * HD + h] = tanh_fast(acc);
}

__global__ void k_zero(float* __restrict__ p)
{
    for (int i = threadIdx.x; i < 4161; i += 256) p[i] = 0.0f;
}

__global__ __launch_bounds__(128) void k_gru_mfma(
    const float* __restrict__ X, const float* __restrict__ Wih,
    const float* __restrict__ Whh, const float* __restrict__ bih,
    const float* __restrict__ bhh,
    const float* __restrict__ Wt, const float* __restrict__ bt,
    const float* __restrict__ Wx, const float* __restrict__ bx,
    const float* __restrict__ rate, float* __restrict__ Fin)
{
    __shared__ short As[2][16 * 68];
    __shared__ float xs[16 * 129];
    __shared__ float q1[16 * 65];
    __shared__ float q2[16 * 65];
    __shared__ float qbs[16];
    __shared__ float dotw[2][2][16];

    const int nf = blockIdx.y;
    const int cbase = blockIdx.x * 16;
    const int tid = threadIdx.x;
    const int w = tid >> 6;
    const int lane = tid & 63;
    const int col = lane & 15;
    const int quad = lane >> 4;

    for (int i = tid; i < 16 * T_; i += 128) {
        int b = i >> 7, t = i & 127;
        xs[b * 129 + t] = X[((size_t)(cbase + b) * T_ + t) * NF + nf];
    }
    short8v bfr[3][2][2];
    const float* wbase = Whh + (size_t)nf * 12288;
#pragma unroll
    for (int g3 = 0; g3 < 3; ++g3)
#pragma unroll
        for (int s = 0; s < 2; ++s)
#pragma unroll
            for (int k2 = 0; k2 < 2; ++k2) {
                int g = 64 * g3 + 32 * w + 16 * s + col;
                const float* src = wbase + g * 64 + 32 * k2 + quad * 8;
                float4 f0 = *(const float4*)src;
                float4 f1 = *(const float4*)(src + 4);
                short8v fr;
                fr[0] = tobf(f0.x); fr[1] = tobf(f0.y); fr[2] = tobf(f0.z); fr[3] = tobf(f0.w);
                fr[4] = tobf(f1.x); fr[5] = tobf(f1.y); fr[6] = tobf(f1.z); fr[7] = tobf(f1.w);
                bfr[g3][s][k2] = fr;
            }
    float wr[2], wz[2], wn[2], br[2], bz[2], bnn[2], bhn[2];
#pragma unroll
    for (int s = 0; s < 2; ++s) {
        int c = 32 * w + 16 * s + col;
        int base = nf * 192;
        wr[s] = Wih[base + c]; wz[s] = Wih[base + 64 + c]; wn[s] = Wih[base + 128 + c];
        br[s] = bih[base + c] + bhh[base + c];
        bz[s] = bih[base + 64 + c] + bhh[base + 64 + c];
        bnn[s] = bih[base + 128 + c]; bhn[s] = bhh[base + 128 + c];
    }
    const float sigr = sigmf(rate[nf]);
    float hold[2][4], num[2][4], den[4], qxv[2][4], qbv[4];
#pragma unroll
    for (int r = 0; r < 4; ++r) {
        den[r] = 0.0f; qbv[r] = 0.0f;
        num[0][r] = 0.0f; num[1][r] = 0.0f;
        qxv[0][r] = 0.0f; qxv[1][r] = 0.0f;
    }
    for (int pass = 0; pass < 2; ++pass) {
        for (int i = tid; i < 16 * 68; i += 128) As[0][i] = 0;
#pragma unroll
        for (int s = 0; s < 2; ++s)
#pragma unroll
            for (int r = 0; r < 4; ++r) hold[s][r] = 0.0f;
        __syncthreads();
        for (int t = 0; t < T_; ++t) {
            const int rb = t & 1;
            const int wb = 1 - rb;
            const short* ap = &As[rb][col * 68 + quad * 8];
            short4v a0 = *(const short4v*)ap;
            short4v a1 = *(const short4v*)(ap + 4);
            short4v a2 = *(const short4v*)(ap + 32);
            short4v a3 = *(const short4v*)(ap + 36);
            short8v A0 = {a0[0], a0[1], a0[2], a0[3], a1[0], a1[1], a1[2], a1[3]};
            short8v A1 = {a2[0], a2[1], a2[2], a2[3], a3[0], a3[1], a3[2], a3[3]};
            f32x4 acc[3][2];
#pragma unroll
            for (int g3 = 0; g3 < 3; ++g3)
#pragma unroll
                for (int s = 0; s < 2; ++s) {
                    f32x4 a = {0.0f, 0.0f, 0.0f, 0.0f};
                    a = __builtin_amdgcn_mfma_f32_16x16x32_bf16(A0, bfr[g3][s][0], a, 0, 0, 0);
                    a = __builtin_amdgcn_mfma_f32_16x16x32_bf16(A1, bfr[g3][s][1], a, 0, 0, 0);
                    acc[g3][s] = a;
                }
            float xv[4];
#pragma unroll
            for (int r = 0; r < 4; ++r) xv[r] = xs[(quad * 4 + r) * 129 + t];
            float hnew[2][4];
#pragma unroll
            for (int s = 0; s < 2; ++s)
#pragma unroll
                for (int r = 0; r < 4; ++r) {
                    float rr = sigmf(xv[r] * wr[s] + br[s] + acc[0][s][r]);
                    float zz = sigmf(xv[r] * wz[s] + bz[s] + acc[1][s][r]);
                    float nn = tanh_fast(xv[r] * wn[s] + bnn[s] + rr * (acc[2][s][r] + bhn[s]));
                    hnew[s][r] = (1.0f - zz) * nn + zz * hold[s][r];
                    hold[s][r] = hnew[s][r];
                }
#pragma unroll
            for (int s = 0; s < 2; ++s)
#pragma unroll
                for (int r = 0; r < 4; ++r)
                    As[wb][(quad * 4 + r) * 68 + 32 * w + 16 * s + col] = tobf(hnew[s][r]);
            if (pass == 1) {
                float p[4];
#pragma unroll
                for (int r = 0; r < 4; ++r)
                    p[r] = qxv[0][r] * hnew[0][r] + qxv[1][r] * hnew[1][r];
#pragma unroll
                for (int m = 1; m < 16; m <<= 1) {
                    p[0] += __shfl_xor(p[0], m, 64);
                    p[1] += __shfl_xor(p[1], m, 64);
                    p[2] += __shfl_xor(p[2], m, 64);
                    p[3] += __shfl_xor(p[3], m, 64);
                }
                if (col == 0) {
#pragma unroll
                    for (int r = 0; r < 4; ++r) dotw[rb][w][quad * 4 + r] = p[r];
                }
                __syncthreads();
                float tf = (float)(t + 1);
#pragma unroll
                for (int r = 0; r < 4; ++r) {
                    float dot = p[r] + dotw[rb][1 - w][quad * 4 + r] + qbv[r];
                    float ds = sigmf(dot);
                    float dn = fmaxf(sigr * __logf(2.72f + (1.0f - ds)) * tf, 1e-6f);
                    float e = fmaxf(ds / dn, 0.0f);
                    float wt = __expf(e);
                    den[r] += wt;
                    num[0][r] += wt * hnew[0][r];
                    num[1][r] += wt * hnew[1][r];
                }
            } else {
                __syncthreads();
            }
        }
        if (pass == 0) {
#pragma unroll
            for (int s = 0; s < 2; ++s)
#pragma unroll
                for (int r = 0; r < 4; ++r)
                    q1[(quad * 4 + r) * 65 + 32 * w + 16 * s + col] = hold[s][r];
            __syncthreads();
            for (int o = tid; o < 16 * 64; o += 128) {
                int b = o >> 6, k = o & 63;
                const float* wrow = Wt + ((size_t)nf * 64 + k) * 64;
                float a = bt[nf * 64 + k];
#pragma unroll 8
                for (int h = 0; h < 64; h += 4) {
                    float4 wv = *(const float4*)&wrow[h];
                    a += q1[b * 65 + h] * wv.x + q1[b * 65 + h + 1] * wv.y
                       + q1[b * 65 + h + 2] * wv.z + q1[b * 65 + h + 3] * wv.w;
                }
                q2[b * 65 + k] = a;
            }
            __syncthreads();
            for (int o = tid; o < 16 * 64; o += 128) {
                int b = o >> 6, h = o & 63;
                float a = 0.0f;
#pragma unroll 8
                for (int k = 0; k < 64; ++k)
                    a += q2[b * 65 + k] * Wx[((size_t)nf * 64 + k) * 64 + h];
                q1[b * 65 + h] = a;
            }
            for (int b = tid; b < 16; b += 128) {
                float a = 0.0f;
                for (int k = 0; k < 64; ++k) a += q2[b * 65 + k] * bx[nf * 64 + k];
                qbs[b] = a;
            }
            __syncthreads();
#pragma unroll
            for (int r = 0; r < 4; ++r) {
                qbv[r] = qbs[quad * 4 + r];
#pragma unroll
                for (int s = 0; s < 2; ++s)
                    qxv[s][r] = q1[(quad * 4 + r) * 65 + 32 * w + 16 * s + col];
                den[r] = 0.0f; num[0][r] = 0.0f; num[1][r] = 0.0f;
            }
            __syncthreads();
        }
    }
#pragma unroll
    for (int s = 0; s < 2; ++s)
#pragma unroll
        for (int r = 0; r < 4; ++r) {
            int b = cbase + quad * 4 + r;
            int c = 32 * w + 16 * s + col;
            Fin[((size_t)b * LQ + nf) * HD + c] = num[s][r] / den[r];
        }
}

extern "C" void kernel_launch(void* const* d_in, const int* in_sizes, int n_in,
                              void* d_out, int out_size, void* d_ws, size_t ws_size,
                              hipStream_t stream)
{
    (void)in_sizes; (void)n_in; (void)out_size;
    const float* X     = (const float*)d_in[0];
    const float* D     = (const float*)d_in[1];
    const float* gWih  = (const float*)d_in[2];
    const float* gWhh  = (const float*)d_in[3];
    const float* gbih  = (const float*)d_in[4];
    const float* gbhh  = (const float*)d_in[5];
    const float* aWt   = (const float*)d_in[6];
    const float* abt   = (const float*)d_in[7];
    const float* aWx   = (const float*)d_in[8];
    const float* abx   = (const float*)d_in[9];
    const float* arate = (const float*)d_in[10];
    const float* dW    = (const float*)d_in[11];
    const float* db    = (const float*)d_in[12];
    const float* mWq   = (const float*)d_in[13]; const float* mbq = (const float*)d_in[14];
    const float* mWk   = (const float*)d_in[15]; const float* mbk = (const float*)d_in[16];
    const float* mWv   = (const float*)d_in[17]; const float* mbv = (const float*)d_in[18];
    const float* mWo   = (const float*)d_in[19]; const float* mbo = (const float*)d_in[20];
    const float* l1g   = (const float*)d_in[21]; const float* l1b = (const float*)d_in[22];
    const float* fW1   = (const float*)d_in[23]; const float* fb1 = (const float*)d_in[24];
    const float* fW2   = (const float*)d_in[25]; const float* fb2 = (const float*)d_in[26];
    const float* l2g   = (const float*)d_in[27]; const float* l2b = (const float*)d_in[28];
    const float* faWq  = (const float*)d_in[29]; const float* fabq = (const float*)d_in[30];
    const float* faWk  = (const float*)d_in[31]; const float* fabk = (const float*)d_in[32];
    const float* faWv  = (const float*)d_in[33]; const float* fabv = (const float*)d_in[34];
    const float* faWo  = (const float*)d_in[35]; const float* fabo = (const float*)d_in[36];
    const float* o0W   = (const float*)d_in[37]; const float* o0b  = (const float*)d_in[38];
    const float* o1W   = (const float*)d_in[39]; const float* o1b  = (const float*)d_in[40];

    float* ws  = (float*)d_ws;
    float* Fin = ws;                               // 630,784
    float* M1  = Fin + 630784;                     // 630,784
    float* M2  = M1  + 630784;                     // 630,784 (later reused as V)
    float* S   = M2  + 630784;                     // 4096
    float* MU  = S   + 4096;                       // 64
    unsigned* cnt = (unsigned*)(MU + 64);          // 1 (+63 pad)
    float* qxg = MU + 128;                         // 622,592
    float* scout = qxg + 622592;                   // 9,856 (also used as qbg)
    short* Hsg = (short*)(scout + 9856);           // 79,691,776 shorts (bf16)
    const size_t need = (size_t)(630784 * 3 + 4096 + 128 + 622592 + 9856) * 4
                        + (size_t)79691776 * 2;
    float* outp = (float*)d_out;
    float* qbg = scout;                            // alias: qbg consumed before scout written

    if (ws_size >= need) {
        k_gru0<<<dim3(8, NF), 256, 0, stream>>>(X, gWih, gWhh, gbih, gbhh,
                                                aWt, abt, aWx, abx, Hsg, qxg, qbg);
        k_att<<<dim3(NF + 1, B_), 128, 0, stream>>>(Hsg, qxg, qbg, arate,
                                                    D, dW, db, S, Fin);
    } else {
        k_gru_mfma<<<dim3(8, NF), 128, 0, stream>>>(X, gWih, gWhh, gbih, gbhh,
                                                    aWt, abt, aWx, abx, arate, Fin);
        k_demo<<<B_, 64, 0, stream>>>(D, dW, db, Fin);
        k_zero<<<1, 256, 0, stream>>>(S);
    }
    k_mha2<<<dim3(B_, 4, 2), 256, 0, stream>>>(Fin, mWq, mbq, mWk, mbk, mWv, mbv,
                                               l1g, l1b, M1, M2);
    k_zff<<<616, 256, 0, stream>>>(Fin, M2, mWo, mbo, l2g, l2b,
                                   fW1, fb1, fW2, fb2,
                                   faWq, fabq, faWk, fabk, faWv, fabv,
                                   faWo, fabo, scout);
    k_cov<<<dim3(16, 8), 256, 0, stream>>>(M1, S, MU, cnt, outp);
    k_head<<<B_, 128, 0, stream>>>(M2, scout, o0W, o0b, o1W, o1b, outp);
}

// Round 10
// 552.907 us; speedup vs baseline: 1.5694x; 1.1247x over previous
//
#include <hip/hip_runtime.h>
#include <math.h>

#define B_ 128
#define T_ 128
#define NF 76
#define HD 64
#define LQ 77

typedef __attribute__((ext_vector_type(8))) short short8v;
typedef __attribute__((ext_vector_type(4))) short short4v;
typedef __attribute__((ext_vector_type(4))) float f32x4;

__device__ __forceinline__ float frcp(float x) { return __builtin_amdgcn_rcpf(x); }
__device__ __forceinline__ float sigmf(float x) { return frcp(1.0f + __expf(-x)); }
__device__ __forceinline__ float tanh_fast(float x) { return 2.0f * frcp(1.0f + __expf(-2.0f * x)) - 1.0f; }
__device__ __forceinline__ short tobf(float x) {
    unsigned u = __float_as_uint(x);
    u += 0x7FFF + ((u >> 16) & 1);   // RNE to bf16
    return (short)(u >> 16);
}
__device__ __forceinline__ float bflo(unsigned u) { return __uint_as_float(u << 16); }
__device__ __forceinline__ float bfhi(unsigned u) { return __uint_as_float(u & 0xffff0000u); }

// ---------------------------------------------------------------------------
// K1a: GRU recurrence via MFMA (R9 structure; fast-math sigmoid/tanh).
// ---------------------------------------------------------------------------
__global__ __launch_bounds__(256) void k_gru0(
    const float* __restrict__ X, const float* __restrict__ Wih,
    const float* __restrict__ Whh, const float* __restrict__ bih,
    const float* __restrict__ bhh,
    const float* __restrict__ Wt, const float* __restrict__ bt,
    const float* __restrict__ Wx, const float* __restrict__ bx,
    short* __restrict__ Hsg, float* __restrict__ qxg, float* __restrict__ qbg)
{
    __shared__ short As[2][16 * 72];
    __shared__ float xs[16 * 129];
    __shared__ float q1[16 * 65];
    __shared__ float q2[16 * 65];

    const int nf = blockIdx.y;
    const int chunk = blockIdx.x;
    const int cbase = chunk * 16;
    const int tid = threadIdx.x;
    const int w = tid >> 6;
    const int lane = tid & 63;
    const int col = lane & 15;
    const int quad = lane >> 4;

    for (int i = tid; i < 16 * T_; i += 256) {
        int b = i >> 7, t = i & 127;
        xs[b * 129 + t] = X[((size_t)(cbase + b) * T_ + t) * NF + nf];
    }

    short8v bfr[3][2];
    const float* wbase = Whh + (size_t)nf * 12288;
#pragma unroll
    for (int g3 = 0; g3 < 3; ++g3)
#pragma unroll
        for (int k2 = 0; k2 < 2; ++k2) {
            int g = 64 * g3 + 16 * w + col;
            const float* src = wbase + g * 64 + 32 * k2 + quad * 8;
            float4 f0 = *(const float4*)src;
            float4 f1 = *(const float4*)(src + 4);
            short8v fr;
            fr[0] = tobf(f0.x); fr[1] = tobf(f0.y); fr[2] = tobf(f0.z); fr[3] = tobf(f0.w);
            fr[4] = tobf(f1.x); fr[5] = tobf(f1.y); fr[6] = tobf(f1.z); fr[7] = tobf(f1.w);
            bfr[g3][k2] = fr;
        }

    const int c = 16 * w + col;
    const int base = nf * 192;
    const float wr = Wih[base + c], wz = Wih[base + 64 + c], wn = Wih[base + 128 + c];
    const float br = bih[base + c] + bhh[base + c];
    const float bz = bih[base + 64 + c] + bhh[base + 64 + c];
    const float bnn = bih[base + 128 + c], bhn = bhh[base + 128 + c];

    for (int i = tid; i < 16 * 72; i += 256) As[0][i] = 0;
    float hold[4];
#pragma unroll
    for (int r = 0; r < 4; ++r) hold[r] = 0.0f;
    __syncthreads();

    const int crow = tid >> 4, cs = tid & 15;

    for (int t = 0; t < T_; ++t) {
        const int rb = t & 1;
        const int wb = 1 - rb;
        short8v A0 = *(const short8v*)&As[rb][col * 72 + quad * 8];
        short8v A1 = *(const short8v*)&As[rb][col * 72 + 32 + quad * 8];

        f32x4 acc[3];
#pragma unroll
        for (int g3 = 0; g3 < 3; ++g3) {
            f32x4 a = {0.0f, 0.0f, 0.0f, 0.0f};
            a = __builtin_amdgcn_mfma_f32_16x16x32_bf16(A0, bfr[g3][0], a, 0, 0, 0);
            a = __builtin_amdgcn_mfma_f32_16x16x32_bf16(A1, bfr[g3][1], a, 0, 0, 0);
            acc[g3] = a;
        }

#pragma unroll
        for (int r = 0; r < 4; ++r) {
            float xv = xs[(quad * 4 + r) * 129 + t];
            float rr = sigmf(xv * wr + br + acc[0][r]);
            float zz = sigmf(xv * wz + bz + acc[1][r]);
            float nn = tanh_fast(xv * wn + bnn + rr * (acc[2][r] + bhn));
            hold[r] = (1.0f - zz) * nn + zz * hold[r];
        }

#pragma unroll
        for (int r = 0; r < 4; ++r)
            As[wb][(quad * 4 + r) * 72 + c] = tobf(hold[r]);
        __syncthreads();
        {
            uint2 pk = *(const uint2*)&As[wb][crow * 72 + cs * 4];
            size_t go = (((size_t)nf * 128 + cbase + crow) * 128 + t) * 64 + cs * 4;
            *(uint2*)(Hsg + go) = pk;
        }
    }

#pragma unroll
    for (int r = 0; r < 4; ++r)
        q1[(quad * 4 + r) * 65 + c] = hold[r];
    __syncthreads();
    for (int o = tid; o < 16 * 64; o += 256) {
        int b = o >> 6, k = o & 63;
        const float* wrow = Wt + ((size_t)nf * 64 + k) * 64;
        float a = bt[nf * 64 + k];
#pragma unroll 8
        for (int h = 0; h < 64; h += 4) {
            float4 wv = *(const float4*)&wrow[h];
            a += q1[b * 65 + h] * wv.x + q1[b * 65 + h + 1] * wv.y
               + q1[b * 65 + h + 2] * wv.z + q1[b * 65 + h + 3] * wv.w;
        }
        q2[b * 65 + k] = a;
    }
    __syncthreads();
    for (int o = tid; o < 16 * 64; o += 256) {
        int b = o >> 6, h = o & 63;
        float a = 0.0f;
#pragma unroll 8
        for (int k = 0; k < 64; ++k)
            a += q2[b * 65 + k] * Wx[((size_t)nf * 64 + k) * 64 + h];
        qxg[((size_t)nf * 128 + cbase + b) * 64 + h] = a;
    }
    for (int b = tid; b < 16; b += 256) {
        float a = 0.0f;
        for (int k = 0; k < 64; ++k) a += q2[b * 65 + k] * bx[nf * 64 + k];
        qbg[nf * 128 + cbase + b] = a;
    }
}

// ---------------------------------------------------------------------------
// K1b: time attention + demo row + S/MU/counter zeroing. grid (77,128).
// ---------------------------------------------------------------------------
__global__ __launch_bounds__(128) void k_att(
    const short* __restrict__ Hsg, const float* __restrict__ qxg,
    const float* __restrict__ qbg, const float* __restrict__ rate,
    const float* __restrict__ D, const float* __restrict__ dW,
    const float* __restrict__ db, float* __restrict__ Sz,
    float* __restrict__ Fin)
{
    const int nf = blockIdx.x, b = blockIdx.y;
    const int tid = threadIdx.x;

    if (nf == NF) {
        if (tid < 64) {
            float acc = db[tid];
            for (int j = 0; j < 12; ++j) acc += D[b * 12 + j] * dW[tid * 12 + j];
            Fin[((size_t)b * LQ + 76) * HD + tid] = tanh_fast(acc);
        }
        int s0 = b * 33;
        for (int k = tid; k < 33; k += 128) {
            int idx = s0 + k;
            if (idx < 4161) Sz[idx] = 0.0f;
        }
        return;
    }

    __shared__ float wsum[128 * 69];
    __shared__ float wl[128];
    __shared__ float qxl[64];
    __shared__ float pn[2][68];
    __shared__ float pd[2];
    if (tid < 64) qxl[tid] = qxg[((size_t)nf * 128 + b) * 64 + tid];
    const float qb = qbg[nf * 128 + b];
    const float sigr = sigmf(rate[nf]);

    uint4 rv[8];
    const uint4* src = (const uint4*)(Hsg + (((size_t)nf * 128 + b) * 128 + tid) * 64);
#pragma unroll
    for (int k = 0; k < 8; ++k) rv[k] = src[k];
    __syncthreads();

    float a = qb;
#pragma unroll
    for (int k = 0; k < 8; ++k) {
        a += bflo(rv[k].x) * qxl[k * 8 + 0] + bfhi(rv[k].x) * qxl[k * 8 + 1]
           + bflo(rv[k].y) * qxl[k * 8 + 2] + bfhi(rv[k].y) * qxl[k * 8 + 3]
           + bflo(rv[k].z) * qxl[k * 8 + 4] + bfhi(rv[k].z) * qxl[k * 8 + 5]
           + bflo(rv[k].w) * qxl[k * 8 + 6] + bfhi(rv[k].w) * qxl[k * 8 + 7];
    }
    float ds = sigmf(a);
    float dn = fmaxf(sigr * __logf(2.72f + (1.0f - ds)) * (float)(tid + 1), 1e-6f);
    float e = fmaxf(ds * frcp(dn), 0.0f);
    float w = __expf(e);
    wl[tid] = w;
#pragma unroll
    for (int k = 0; k < 8; ++k) {
        float* d = &wsum[tid * 69 + k * 8];
        d[0] = w * bflo(rv[k].x); d[1] = w * bfhi(rv[k].x);
        d[2] = w * bflo(rv[k].y); d[3] = w * bfhi(rv[k].y);
        d[4] = w * bflo(rv[k].z); d[5] = w * bfhi(rv[k].z);
        d[6] = w * bflo(rv[k].w); d[7] = w * bfhi(rv[k].w);
    }
    __syncthreads();
    {
        int ch = tid & 63, half = tid >> 6;
        float acc = 0.0f, den = 0.0f;
        int t0 = half * 64;
        for (int t = t0; t < t0 + 64; ++t) {
            acc += wsum[t * 69 + ch];
            den += wl[t];
        }
        pn[half][ch] = acc;
        if (ch == 0) pd[half] = den;
    }
    __syncthreads();
    if (tid < 64) {
        float num = pn[0][tid] + pn[1][tid];
        float den = pd[0] + pd[1];
        Fin[((size_t)b * LQ + nf) * HD + tid] = num * frcp(den);
    }
}

// ---------------------------------------------------------------------------
// K4: MHA per (b, head, variant). grid (128,4,2), block 256.
// Attention j-loop split in thirds (231 active threads); os aliased into xl.
// ---------------------------------------------------------------------------
__global__ __launch_bounds__(256) void k_mha2(
    const float* __restrict__ Fin,
    const float* __restrict__ Wq, const float* __restrict__ bq,
    const float* __restrict__ Wk, const float* __restrict__ bk,
    const float* __restrict__ Wv, const float* __restrict__ bv,
    const float* __restrict__ g1, const float* __restrict__ b1,
    float* __restrict__ M1, float* __restrict__ M2)
{
    __shared__ float xl[LQ * 68];       // later reused as os[231][17]
    __shared__ float qh[LQ * 20], kh[LQ * 20], vh[LQ * 20];
    float (*os)[17] = (float (*)[17])xl;
    const int b = blockIdx.x, hd = blockIdx.y, v = blockIdx.z;
    const int tid = threadIdx.x;
    const float* xsrc = Fin + (size_t)b * LQ * HD;

    for (int idx = tid; idx < LQ * HD; idx += 256)
        xl[(idx >> 6) * 68 + (idx & 63)] = xsrc[idx];
    __syncthreads();
    if (v == 1) {
        if (tid < LQ) {
            float mu = 0.0f;
            for (int h = 0; h < 64; ++h) mu += xl[tid * 68 + h];
            mu *= (1.0f / 64.0f);
            float var = 0.0f;
            for (int h = 0; h < 64; ++h) { float d = xl[tid * 68 + h] - mu; var += d * d; }
            var *= (1.0f / 64.0f);
            float rs = rsqrtf(var + 1e-7f);
            for (int h = 0; h < 64; ++h)
                xl[tid * 68 + h] = (xl[tid * 68 + h] - mu) * rs * g1[h] + b1[h];
        }
        __syncthreads();
    }

    for (int idx = tid; idx < LQ * 16; idx += 256) {
        int l = idx >> 4, d = idx & 15, ch = hd * 16 + d;
        float aq = bq[ch], ak = bk[ch], av = bv[ch];
        const float4* wq = (const float4*)(Wq + ch * 64);
        const float4* wk = (const float4*)(Wk + ch * 64);
        const float4* wv = (const float4*)(Wv + ch * 64);
        const float4* xr = (const float4*)&xl[l * 68];
#pragma unroll 4
        for (int c4 = 0; c4 < 16; ++c4) {
            float4 xv = xr[c4];
            float4 a = wq[c4], bb = wk[c4], cc = wv[c4];
            aq += xv.x * a.x + xv.y * a.y + xv.z * a.z + xv.w * a.w;
            ak += xv.x * bb.x + xv.y * bb.y + xv.z * bb.z + xv.w * bb.w;
            av += xv.x * cc.x + xv.y * cc.y + xv.z * cc.z + xv.w * cc.w;
        }
        qh[l * 20 + d] = aq; kh[l * 20 + d] = ak; vh[l * 20 + d] = av;
    }
    __syncthreads();   // QKV done; xl dead -> reuse as os

    if (tid < 231) {
        int l = tid % 77, third = tid / 77;
        float4 qf0 = *(const float4*)&qh[l * 20 + 0];
        float4 qf1 = *(const float4*)&qh[l * 20 + 4];
        float4 qf2 = *(const float4*)&qh[l * 20 + 8];
        float4 qf3 = *(const float4*)&qh[l * 20 + 12];
        int j0 = third * 26;
        int j1 = (third == 2) ? LQ : j0 + 26;
        float o[16];
#pragma unroll
        for (int d = 0; d < 16; ++d) o[d] = 0.0f;
        float ss = 0.0f;
        for (int j = j0; j < j1; ++j) {
            const float4* kp = (const float4*)&kh[j * 20];
            float4 k0 = kp[0], k1 = kp[1], k2 = kp[2], k3 = kp[3];
            float sc = qf0.x * k0.x + qf0.y * k0.y + qf0.z * k0.z + qf0.w * k0.w
                     + qf1.x * k1.x + qf1.y * k1.y + qf1.z * k1.z + qf1.w * k1.w
                     + qf2.x * k2.x + qf2.y * k2.y + qf2.z * k2.z + qf2.w * k2.w
                     + qf3.x * k3.x + qf3.y * k3.y + qf3.z * k3.z + qf3.w * k3.w;
            float p = __expf(sc * 0.25f);   // scores tiny: no max-shift
            ss += p;
            const float4* vp = (const float4*)&vh[j * 20];
            float4 v0 = vp[0], v1 = vp[1], v2 = vp[2], v3 = vp[3];
            o[0] += p * v0.x; o[1] += p * v0.y; o[2] += p * v0.z; o[3] += p * v0.w;
            o[4] += p * v1.x; o[5] += p * v1.y; o[6] += p * v1.z; o[7] += p * v1.w;
            o[8] += p * v2.x; o[9] += p * v2.y; o[10] += p * v2.z; o[11] += p * v2.w;
            o[12] += p * v3.x; o[13] += p * v3.y; o[14] += p * v3.z; o[15] += p * v3.w;
        }
#pragma unroll
        for (int d = 0; d < 16; ++d) os[tid][d] = o[d];
        os[tid][16] = ss;
    }
    __syncthreads();
    if (tid < LQ) {
        float inv = frcp(os[tid][16] + os[77 + tid][16] + os[154 + tid][16]);
        float* Mout = (v == 1) ? M2 : M1;
#pragma unroll
        for (int d = 0; d < 16; ++d)
            Mout[((size_t)b * LQ + tid) * HD + hd * 16 + d]
                = (os[tid][d] + os[77 + tid][d] + os[154 + tid][d]) * inv;
    }
}

// ---------------------------------------------------------------------------
// K5: row-parallel fused Y + LN2 + FFN + final-QKV + score. grid 616, block 256.
// ---------------------------------------------------------------------------
__global__ __launch_bounds__(256) void k_zff(
    const float* __restrict__ Fin, float* __restrict__ M2,
    const float* __restrict__ Wo, const float* __restrict__ bo,
    const float* __restrict__ g2, const float* __restrict__ b2,
    const float* __restrict__ W1, const float* __restrict__ bb1,
    const float* __restrict__ W2, const float* __restrict__ bb2,
    const float* __restrict__ faWq, const float* __restrict__ fabq,
    const float* __restrict__ faWk, const float* __restrict__ fabk,
    const float* __restrict__ faWv, const float* __restrict__ fabv,
    const float* __restrict__ faWout, const float* __restrict__ fabout,
    float* __restrict__ scout)
{
    __shared__ float m2l[16 * 68];
    __shared__ float yl[16 * 68];
    __shared__ float zl[16 * 68];
    __shared__ float ul[16 * 260];
    const int tid = threadIdx.x;
    const size_t base = (size_t)blockIdx.x * 16;
    const size_t eb = base * 64;
    const int h = tid & 63, rq = tid >> 6;

    for (int idx = tid; idx < 1024; idx += 256)
        m2l[(idx >> 6) * 68 + (idx & 63)] = M2[eb + idx];
    __syncthreads();

    {
        float acc[4];
#pragma unroll
        for (int rr = 0; rr < 4; ++rr) acc[rr] = bo[h];
        const float4* wo = (const float4*)(Wo + h * 64);
#pragma unroll 4
        for (int c4 = 0; c4 < 16; ++c4) {
            float4 wv = wo[c4];
#pragma unroll
            for (int rr = 0; rr < 4; ++rr) {
                float4 mv = *(const float4*)&m2l[(rq * 4 + rr) * 68 + c4 * 4];
                acc[rr] += mv.x * wv.x + mv.y * wv.y + mv.z * wv.z + mv.w * wv.w;
            }
        }
#pragma unroll
        for (int rr = 0; rr < 4; ++rr) {
            int r = rq * 4 + rr;
            yl[r * 68 + h] = Fin[eb + r * 64 + h] + acc[rr];
        }
    }
    __syncthreads();
    if (tid < 16) {
        float mu = 0.0f;
        for (int c = 0; c < 64; ++c) mu += yl[tid * 68 + c];
        mu *= (1.0f / 64.0f);
        float var = 0.0f;
        for (int c = 0; c < 64; ++c) { float d = yl[tid * 68 + c] - mu; var += d * d; }
        var *= (1.0f / 64.0f);
        float rs = rsqrtf(var + 1e-7f);
        for (int c = 0; c < 64; ++c)
            zl[tid * 68 + c] = (yl[tid * 68 + c] - mu) * rs * g2[c] + b2[c];
    }
    __syncthreads();

    {
        const int f = tid;
        float acc[16];
#pragma unroll
        for (int r = 0; r < 16; ++r) acc[r] = bb1[f];
        const float4* w1r = (const float4*)(W1 + f * 64);
#pragma unroll
        for (int c = 0; c < 4; ++c) {
            float4 w0 = w1r[c * 4 + 0], w1 = w1r[c * 4 + 1];
            float4 w2 = w1r[c * 4 + 2], w3 = w1r[c * 4 + 3];
#pragma unroll
            for (int r = 0; r < 16; ++r) {
                const float4* zr = (const float4*)&zl[r * 68 + c * 16];
                float4 z0 = zr[0], z1 = zr[1], z2 = zr[2], z3 = zr[3];
                acc[r] += z0.x * w0.x + z0.y * w0.y + z0.z * w0.z + z0.w * w0.w
                        + z1.x * w1.x + z1.y * w1.y + z1.z * w1.z + z1.w * w1.w
                        + z2.x * w2.x + z2.y * w2.y + z2.z * w2.z + z2.w * w2.w
                        + z3.x * w3.x + z3.y * w3.y + z3.z * w3.z + z3.w * w3.w;
            }
        }
#pragma unroll
        for (int r = 0; r < 16; ++r) ul[r * 260 + f] = fmaxf(acc[r], 0.0f);
    }
    __syncthreads();
    {
        float acc[4];
#pragma unroll
        for (int rr = 0; rr < 4; ++rr) acc[rr] = bb2[h];
        const float4* w2r = (const float4*)(W2 + h * 256);
#pragma unroll 4
        for (int c = 0; c < 16; ++c) {
            float4 w0 = w2r[c * 4 + 0], w1 = w2r[c * 4 + 1];
            float4 w2 = w2r[c * 4 + 2], w3 = w2r[c * 4 + 3];
#pragma unroll
            for (int rr = 0; rr < 4; ++rr) {
                const float4* ur = (const float4*)&ul[(rq * 4 + rr) * 260 + c * 16];
                float4 u0 = ur[0], u1 = ur[1], u2 = ur[2], u3 = ur[3];
                acc[rr] += u0.x * w0.x + u0.y * w0.y + u0.z * w0.z + u0.w * w0.w
                         + u1.x * w1.x + u1.y * w1.y + u1.z * w1.z + u1.w * w1.w
                         + u2.x * w2.x + u2.y * w2.y + u2.z * w2.z + u2.w * w2.w
                         + u3.x * w3.x + u3.y * w3.y + u3.z * w3.z + u3.w * w3.w;
            }
        }
#pragma unroll
        for (int rr = 0; rr < 4; ++rr)
            yl[(rq * 4 + rr) * 68 + h] += acc[rr];
    }
    __syncthreads();

    {
        const float4* wq = (const float4*)(faWq + h * 64);
        const float4* wk = (const float4*)(faWk + h * 64);
        const float4* wv = (const float4*)(faWv + h * 64);
        float q[4], k[4], v[4];
#pragma unroll
        for (int rr = 0; rr < 4; ++rr) { q[rr] = fabq[h]; k[rr] = fabk[h]; v[rr] = fabv[h]; }
#pragma unroll 4
        for (int c4 = 0; c4 < 16; ++c4) {
            float4 a = wq[c4], bb = wk[c4], cc = wv[c4];
#pragma unroll
            for (int rr = 0; rr < 4; ++rr) {
                float4 zv = *(const float4*)&yl[(rq * 4 + rr) * 68 + c4 * 4];
                q[rr] += zv.x * a.x + zv.y * a.y + zv.z * a.z + zv.w * a.w;
                k[rr] += zv.x * bb.x + zv.y * bb.y + zv.z * bb.z + zv.w * bb.w;
                v[rr] += zv.x * cc.x + zv.y * cc.y + zv.z * cc.z + zv.w * cc.w;
            }
        }
        float fw = faWout[h];
#pragma unroll
        for (int rr = 0; rr < 4; ++rr) {
            int r = rq * 4 + rr;
            ul[r * 68 + h] = q[rr] * k[rr] * fw;
            M2[eb + r * 64 + h] = v[rr];
        }
    }
    __syncthreads();
    if (tid < 16) {
        float a = fabout[0];
        for (int c = 0; c < 64; ++c) a += ul[tid * 68 + c];
        scout[base + tid] = a;
    }
}

// ---------------------------------------------------------------------------
// K6: covariance accumulators + last-block decov. grid (16,8), block 256.
// ---------------------------------------------------------------------------
__global__ __launch_bounds__(256) void k_cov(
    const float* __restrict__ M1, float* __restrict__ S, float* __restrict__ MU,
    unsigned* __restrict__ cnt, float* __restrict__ out)
{
    const int tid = threadIdx.x;
    const int ig = tid >> 6, j = tid & 63;
    const int i = blockIdx.x * 4 + ig;
    const int l0 = blockIdx.y * 1232, l1 = l0 + 1232;
    float acc = 0.0f, mua = 0.0f;
    for (int l = l0; l < l1; ++l) {
        float v = M1[(size_t)l * 64 + j];
        acc += M1[(size_t)l * 64 + i] * v;
        mua += v;
    }
    atomicAdd(&S[i * 64 + j], acc);
    if (blockIdx.x == 0 && ig == 0) atomicAdd(&MU[j], mua);
    __threadfence();
    __syncthreads();
    __shared__ int last;
    if (tid == 0) last = (atomicAdd(cnt, 1u) == 127u);
    __syncthreads();
    if (last) {
        __shared__ float mus[64];
        __shared__ float pa[4], pd[4];
        if (tid < 64) mus[tid] = atomicAdd(&MU[tid], 0.0f);
        __syncthreads();
        const float invM = 1.0f / 9856.0f;
        float asum = 0.0f, dsum = 0.0f;
        for (int idx = tid; idx < 4096; idx += 256) {
            int ii = idx >> 6, jj = idx & 63;
            float c = atomicAdd(&S[idx], 0.0f) * invM - (mus[ii] * invM) * (mus[jj] * invM);
            asum += c * c;
            if (ii == jj) dsum += c * c;
        }
        for (int o = 32; o; o >>= 1) {
            asum += __shfl_xor(asum, o, 64);
            dsum += __shfl_xor(dsum, o, 64);
        }
        if ((tid & 63) == 0) { pa[tid >> 6] = asum; pd[tid >> 6] = dsum; }
        __syncthreads();
        if (tid == 0)
            out[128] = 0.5f * ((pa[0] + pa[1] + pa[2] + pa[3])
                             - (pd[0] + pd[1] + pd[2] + pd[3]));
    }
}

// ---------------------------------------------------------------------------
// K7: final softmax + s = alpha.V + output head. grid 128, block 128.
// ---------------------------------------------------------------------------
__global__ __launch_bounds__(128) void k_head(
    const float* __restrict__ Vg, const float* __restrict__ scout,
    const float* __restrict__ o0W, const float* __restrict__ o0b,
    const float* __restrict__ o1W, const float* __restrict__ o1b,
    float* __restrict__ out)
{
    __shared__ float sl[LQ + 3];
    __shared__ float pn[2][64];
    __shared__ float sv[64], h1[64];
    __shared__ float red0;
    const int b = blockIdx.x, tid = threadIdx.x;

    if (tid < LQ) sl[tid] = scout[b * LQ + tid];
    __syncthreads();
    if (tid < 64) {
        float v0 = sl[tid];
        float v1 = (tid < LQ - 64) ? sl[tid + 64] : -1e30f;
        float m = fmaxf(v0, v1);
        for (int o = 32; o; o >>= 1) m = fmaxf(m, __shfl_xor(m, o, 64));
        float e0 = __expf(v0 - m);
        float e1 = (tid < LQ - 64) ? __expf(v1 - m) : 0.0f;
        float s = e0 + e1;
        for (int o = 32; o; o >>= 1) s += __shfl_xor(s, o, 64);
        sl[tid] = e0;
        if (tid < LQ - 64) sl[tid + 64] = e1;
        if (tid == 0) red0 = s;
    }
    __syncthreads();
    {
        int h = tid & 63, half = tid >> 6;
        int l0 = half ? 39 : 0, l1 = half ? LQ : 39;
        float acc = 0.0f;
        for (int l = l0; l < l1; ++l)
            acc += sl[l] * Vg[((size_t)b * LQ + l) * 64 + h];
        pn[half][h] = acc;
    }
    __syncthreads();
    if (tid < 64) sv[tid] = (pn[0][tid] + pn[1][tid]) * frcp(red0);
    __syncthreads();
    if (tid < 64) {
        float acc = o0b[tid];
        const float4* w = (const float4*)(o0W + tid * 64);
#pragma unroll 4
        for (int c4 = 0; c4 < 16; ++c4) {
            float4 wv = w[c4];
            const float4* sp = (const float4*)&sv[c4 * 4];
            float4 s0 = sp[0];
            acc += s0.x * wv.x + s0.y * wv.y + s0.z * wv.z + s0.w * wv.w;
        }
        h1[tid] = fmaxf(acc, 0.0f);
    }
    __syncthreads();
    if (tid < 64) {
        float p = h1[tid] * o1W[tid];
        for (int o = 32; o; o >>= 1) p += __shfl_xor(p, o, 64);
        if (tid == 0) out[b] = sigmf(p + o1b[0]);
    }
}

// ---------------------------------------------------------------------------
// Fallback path kernels (ws too small).
// ---------------------------------------------------------------------------
__global__ void k_demo(const float* __restrict__ D, const float* __restrict__ dW,
                       const float* __restrict__ db, float* __restrict__ Fin)
{
    int b = blockIdx.x, h = threadIdx.x;
    float acc = db[h];
    for (int j = 0; j < 12; ++j) acc += D[b * 12 + j] * dW[h * 12 + j];
    Fin[((size_t)b * LQ + 76) * HD + h] = tanh_fast(acc);
}

__global__ void k_zero(float* __restrict__ p)
{
    for (int i = threadIdx.x; i < 4161; i += 256) p[i] = 0.0f;
}

__global__ __launch_bounds__(128) void k_gru_mfma(
    const float* __restrict__ X, const float* __restrict__ Wih,
    const float* __restrict__ Whh, const float* __restrict__ bih,
    const float* __restrict__ bhh,
    const float* __restrict__ Wt, const float* __restrict__ bt,
    const float* __restrict__ Wx, const float* __restrict__ bx,
    const float* __restrict__ rate, float* __restrict__ Fin)
{
    __shared__ short As[2][16 * 68];
    __shared__ float xs[16 * 129];
    __shared__ float q1[16 * 65];
    __shared__ float q2[16 * 65];
    __shared__ float qbs[16];
    __shared__ float dotw[2][2][16];

    const int nf = blockIdx.y;
    const int cbase = blockIdx.x * 16;
    const int tid = threadIdx.x;
    const int w = tid >> 6;
    const int lane = tid & 63;
    const int col = lane & 15;
    const int quad = lane >> 4;

    for (int i = tid; i < 16 * T_; i += 128) {
        int b = i >> 7, t = i & 127;
        xs[b * 129 + t] = X[((size_t)(cbase + b) * T_ + t) * NF + nf];
    }
    short8v bfr[3][2][2];
    const float* wbase = Whh + (size_t)nf * 12288;
#pragma unroll
    for (int g3 = 0; g3 < 3; ++g3)
#pragma unroll
        for (int s = 0; s < 2; ++s)
#pragma unroll
            for (int k2 = 0; k2 < 2; ++k2) {
                int g = 64 * g3 + 32 * w + 16 * s + col;
                const float* src = wbase + g * 64 + 32 * k2 + quad * 8;
                float4 f0 = *(const float4*)src;
                float4 f1 = *(const float4*)(src + 4);
                short8v fr;
                fr[0] = tobf(f0.x); fr[1] = tobf(f0.y); fr[2] = tobf(f0.z); fr[3] = tobf(f0.w);
                fr[4] = tobf(f1.x); fr[5] = tobf(f1.y); fr[6] = tobf(f1.z); fr[7] = tobf(f1.w);
                bfr[g3][s][k2] = fr;
            }
    float wr[2], wz[2], wn[2], br[2], bz[2], bnn[2], bhn[2];
#pragma unroll
    for (int s = 0; s < 2; ++s) {
        int c = 32 * w + 16 * s + col;
        int base = nf * 192;
        wr[s] = Wih[base + c]; wz[s] = Wih[base + 64 + c]; wn[s] = Wih[base + 128 + c];
        br[s] = bih[base + c] + bhh[base + c];
        bz[s] = bih[base + 64 + c] + bhh[base + 64 + c];
        bnn[s] = bih[base + 128 + c]; bhn[s] = bhh[base + 128 + c];
    }
    const float sigr = sigmf(rate[nf]);
    float hold[2][4], num[2][4], den[4], qxv[2][4], qbv[4];
#pragma unroll
    for (int r = 0; r < 4; ++r) {
        den[r] = 0.0f; qbv[r] = 0.0f;
        num[0][r] = 0.0f; num[1][r] = 0.0f;
        qxv[0][r] = 0.0f; qxv[1][r] = 0.0f;
    }
    for (int pass = 0; pass < 2; ++pass) {
        for (int i = tid; i < 16 * 68; i += 128) As[0][i] = 0;
#pragma unroll
        for (int s = 0; s < 2; ++s)
#pragma unroll
            for (int r = 0; r < 4; ++r) hold[s][r] = 0.0f;
        __syncthreads();
        for (int t = 0; t < T_; ++t) {
            const int rb = t & 1;
            const int wb = 1 - rb;
            const short* ap = &As[rb][col * 68 + quad * 8];
            short4v a0 = *(const short4v*)ap;
            short4v a1 = *(const short4v*)(ap + 4);
            short4v a2 = *(const short4v*)(ap + 32);
            short4v a3 = *(const short4v*)(ap + 36);
            short8v A0 = {a0[0], a0[1], a0[2], a0[3], a1[0], a1[1], a1[2], a1[3]};
            short8v A1 = {a2[0], a2[1], a2[2], a2[3], a3[0], a3[1], a3[2], a3[3]};
            f32x4 acc[3][2];
#pragma unroll
            for (int g3 = 0; g3 < 3; ++g3)
#pragma unroll
                for (int s = 0; s < 2; ++s) {
                    f32x4 a = {0.0f, 0.0f, 0.0f, 0.0f};
                    a = __builtin_amdgcn_mfma_f32_16x16x32_bf16(A0, bfr[g3][s][0], a, 0, 0, 0);
                    a = __builtin_amdgcn_mfma_f32_16x16x32_bf16(A1, bfr[g3][s][1], a, 0, 0, 0);
                    acc[g3][s] = a;
                }
            float xv[4];
#pragma unroll
            for (int r = 0; r < 4; ++r) xv[r] = xs[(quad * 4 + r) * 129 + t];
            float hnew[2][4];
#pragma unroll
            for (int s = 0; s < 2; ++s)
#pragma unroll
                for (int r = 0; r < 4; ++r) {
                    float rr = sigmf(xv[r] * wr[s] + br[s] + acc[0][s][r]);
                    float zz = sigmf(xv[r] * wz[s] + bz[s] + acc[1][s][r]);
                    float nn = tanh_fast(xv[r] * wn[s] + bnn[s] + rr * (acc[2][s][r] + bhn[s]));
                    hnew[s][r] = (1.0f - zz) * nn + zz * hold[s][r];
                    hold[s][r] = hnew[s][r];
                }
#pragma unroll
            for (int s = 0; s < 2; ++s)
#pragma unroll
                for (int r = 0; r < 4; ++r)
                    As[wb][(quad * 4 + r) * 68 + 32 * w + 16 * s + col] = tobf(hnew[s][r]);
            if (pass == 1) {
                float p[4];
#pragma unroll
                for (int r = 0; r < 4; ++r)
                    p[r] = qxv[0][r] * hnew[0][r] + qxv[1][r] * hnew[1][r];
#pragma unroll
                for (int m = 1; m < 16; m <<= 1) {
                    p[0] += __shfl_xor(p[0], m, 64);
                    p[1] += __shfl_xor(p[1], m, 64);
                    p[2] += __shfl_xor(p[2], m, 64);
                    p[3] += __shfl_xor(p[3], m, 64);
                }
                if (col == 0) {
#pragma unroll
                    for (int r = 0; r < 4; ++r) dotw[rb][w][quad * 4 + r] = p[r];
                }
                __syncthreads();
                float tf = (float)(t + 1);
#pragma unroll
                for (int r = 0; r < 4; ++r) {
                    float dot = p[r] + dotw[rb][1 - w][quad * 4 + r] + qbv[r];
                    float ds = sigmf(dot);
                    float dn = fmaxf(sigr * __logf(2.72f + (1.0f - ds)) * tf, 1e-6f);
                    float e = fmaxf(ds * frcp(dn), 0.0f);
                    float wt = __expf(e);
                    den[r] += wt;
                    num[0][r] += wt * hnew[0][r];
                    num[1][r] += wt * hnew[1][r];
                }
            } else {
                __syncthreads();
            }
        }
        if (pass == 0) {
#pragma unroll
            for (int s = 0; s < 2; ++s)
#pragma unroll
                for (int r = 0; r < 4; ++r)
                    q1[(quad * 4 + r) * 65 + 32 * w + 16 * s + col] = hold[s][r];
            __syncthreads();
            for (int o = tid; o < 16 * 64; o += 128) {
                int b = o >> 6, k = o & 63;
                const float* wrow = Wt + ((size_t)nf * 64 + k) * 64;
                float a = bt[nf * 64 + k];
#pragma unroll 8
                for (int h = 0; h < 64; h += 4) {
                    float4 wv = *(const float4*)&wrow[h];
                    a += q1[b * 65 + h] * wv.x + q1[b * 65 + h + 1] * wv.y
                       + q1[b * 65 + h + 2] * wv.z + q1[b * 65 + h + 3] * wv.w;
                }
                q2[b * 65 + k] = a;
            }
            __syncthreads();
            for (int o = tid; o < 16 * 64; o += 128) {
                int b = o >> 6, h = o & 63;
                float a = 0.0f;
#pragma unroll 8
                for (int k = 0; k < 64; ++k)
                    a += q2[b * 65 + k] * Wx[((size_t)nf * 64 + k) * 64 + h];
                q1[b * 65 + h] = a;
            }
            for (int b = tid; b < 16; b += 128) {
                float a = 0.0f;
                for (int k = 0; k < 64; ++k) a += q2[b * 65 + k] * bx[nf * 64 + k];
                qbs[b] = a;
            }
            __syncthreads();
#pragma unroll
            for (int r = 0; r < 4; ++r) {
                qbv[r] = qbs[quad * 4 + r];
#pragma unroll
                for (int s = 0; s < 2; ++s)
                    qxv[s][r] = q1[(quad * 4 + r) * 65 + 32 * w + 16 * s + col];
                den[r] = 0.0f; num[0][r] = 0.0f; num[1][r] = 0.0f;
            }
            __syncthreads();
        }
    }
#pragma unroll
    for (int s = 0; s < 2; ++s)
#pragma unroll
        for (int r = 0; r < 4; ++r) {
            int b = cbase + quad * 4 + r;
            int c = 32 * w + 16 * s + col;
            Fin[((size_t)b * LQ + nf) * HD + c] = num[s][r] * frcp(den[r]);
        }
}

extern "C" void kernel_launch(void* const* d_in, const int* in_sizes, int n_in,
                              void* d_out, int out_size, void* d_ws, size_t ws_size,
                              hipStream_t stream)
{
    (void)in_sizes; (void)n_in; (void)out_size;
    const float* X     = (const float*)d_in[0];
    const float* D     = (const float*)d_in[1];
    const float* gWih  = (const float*)d_in[2];
    const float* gWhh  = (const float*)d_in[3];
    const float* gbih  = (const float*)d_in[4];
    const float* gbhh  = (const float*)d_in[5];
    const float* aWt   = (const float*)d_in[6];
    const float* abt   = (const float*)d_in[7];
    const float* aWx   = (const float*)d_in[8];
    const float* abx   = (const float*)d_in[9];
    const float* arate = (const float*)d_in[10];
    const float* dW    = (const float*)d_in[11];
    const float* db    = (const float*)d_in[12];
    const float* mWq   = (const float*)d_in[13]; const float* mbq = (const float*)d_in[14];
    const float* mWk   = (const float*)d_in[15]; const float* mbk = (const float*)d_in[16];
    const float* mWv   = (const float*)d_in[17]; const float* mbv = (const float*)d_in[18];
    const float* mWo   = (const float*)d_in[19]; const float* mbo = (const float*)d_in[20];
    const float* l1g   = (const float*)d_in[21]; const float* l1b = (const float*)d_in[22];
    const float* fW1   = (const float*)d_in[23]; const float* fb1 = (const float*)d_in[24];
    const float* fW2   = (const float*)d_in[25]; const float* fb2 = (const float*)d_in[26];
    const float* l2g   = (const float*)d_in[27]; const float* l2b = (const float*)d_in[28];
    const float* faWq  = (const float*)d_in[29]; const float* fabq = (const float*)d_in[30];
    const float* faWk  = (const float*)d_in[31]; const float* fabk = (const float*)d_in[32];
    const float* faWv  = (const float*)d_in[33]; const float* fabv = (const float*)d_in[34];
    const float* faWo  = (const float*)d_in[35]; const float* fabo = (const float*)d_in[36];
    const float* o0W   = (const float*)d_in[37]; const float* o0b  = (const float*)d_in[38];
    const float* o1W   = (const float*)d_in[39]; const float* o1b  = (const float*)d_in[40];

    float* ws  = (float*)d_ws;
    float* Fin = ws;                               // 630,784
    float* M1  = Fin + 630784;                     // 630,784
    float* M2  = M1  + 630784;                     // 630,784 (later reused as V)
    float* S   = M2  + 630784;                     // 4096
    float* MU  = S   + 4096;                       // 64
    unsigned* cnt = (unsigned*)(MU + 64);          // 1 (+63 pad)
    float* qxg = MU + 128;                         // 622,592
    float* scout = qxg + 622592;                   // 9,856 (also used as qbg)
    short* Hsg = (short*)(scout + 9856);           // 79,691,776 shorts (bf16)
    const size_t need = (size_t)(630784 * 3 + 4096 + 128 + 622592 + 9856) * 4
                        + (size_t)79691776 * 2;
    float* outp = (float*)d_out;
    float* qbg = scout;                            // alias: qbg consumed before scout written

    if (ws_size >= need) {
        k_gru0<<<dim3(8, NF), 256, 0, stream>>>(X, gWih, gWhh, gbih, gbhh,
                                                aWt, abt, aWx, abx, Hsg, qxg, qbg);
        k_att<<<dim3(NF + 1, B_), 128, 0, stream>>>(Hsg, qxg, qbg, arate,
                                                    D, dW, db, S, Fin);
    } else {
        k_gru_mfma<<<dim3(8, NF), 128, 0, stream>>>(X, gWih, gWhh, gbih, gbhh,
                                                    aWt, abt, aWx, abx, arate, Fin);
        k_demo<<<B_, 64, 0, stream>>>(D, dW, db, Fin);
        k_zero<<<1, 256, 0, stream>>>(S);
    }
    k_mha2<<<dim3(B_, 4, 2), 256, 0, stream>>>(Fin, mWq, mbq, mWk, mbk, mWv, mbv,
                                               l1g, l1b, M1, M2);
    k_zff<<<616, 256, 0, stream>>>(Fin, M2, mWo, mbo, l2g, l2b,
                                   fW1, fb1, fW2, fb2,
                                   faWq, fabq, faWk, fabk, faWv, fabv,
                                   faWo, fabo, scout);
    k_cov<<<dim3(16, 8), 256, 0, stream>>>(M1, S, MU, cnt, outp);
    k_head<<<B_, 128, 0, stream>>>(M2, scout, o0W, o0b, o1W, o1b, outp);
}

// Round 11
// 532.120 us; speedup vs baseline: 1.6307x; 1.0391x over previous
//
#include <hip/hip_runtime.h>
#include <math.h>

#define B_ 128
#define T_ 128
#define NF 76
#define HD 64
#define LQ 77

typedef __attribute__((ext_vector_type(8))) short short8v;
typedef __attribute__((ext_vector_type(4))) short short4v;
typedef __attribute__((ext_vector_type(4))) float f32x4;

__device__ __forceinline__ float frcp(float x) { return __builtin_amdgcn_rcpf(x); }
__device__ __forceinline__ float sigmf(float x) { return frcp(1.0f + __expf(-x)); }
__device__ __forceinline__ float tanh_fast(float x) { return 2.0f * frcp(1.0f + __expf(-2.0f * x)) - 1.0f; }
__device__ __forceinline__ short tobf(float x) {
    unsigned u = __float_as_uint(x);
    u += 0x7FFF + ((u >> 16) & 1);   // RNE to bf16
    return (short)(u >> 16);
}
__device__ __forceinline__ float bflo(unsigned u) { return __uint_as_float(u << 16); }
__device__ __forceinline__ float bfhi(unsigned u) { return __uint_as_float(u & 0xffff0000u); }

// ---------------------------------------------------------------------------
// K1a: GRU recurrence via MFMA (R10 structure; fast-math sigmoid/tanh).
// ---------------------------------------------------------------------------
__global__ __launch_bounds__(256) void k_gru0(
    const float* __restrict__ X, const float* __restrict__ Wih,
    const float* __restrict__ Whh, const float* __restrict__ bih,
    const float* __restrict__ bhh,
    const float* __restrict__ Wt, const float* __restrict__ bt,
    const float* __restrict__ Wx, const float* __restrict__ bx,
    short* __restrict__ Hsg, float* __restrict__ qxg, float* __restrict__ qbg)
{
    __shared__ short As[2][16 * 72];
    __shared__ float xs[16 * 129];
    __shared__ float q1[16 * 65];
    __shared__ float q2[16 * 65];

    const int nf = blockIdx.y;
    const int chunk = blockIdx.x;
    const int cbase = chunk * 16;
    const int tid = threadIdx.x;
    const int w = tid >> 6;
    const int lane = tid & 63;
    const int col = lane & 15;
    const int quad = lane >> 4;

    for (int i = tid; i < 16 * T_; i += 256) {
        int b = i >> 7, t = i & 127;
        xs[b * 129 + t] = X[((size_t)(cbase + b) * T_ + t) * NF + nf];
    }

    short8v bfr[3][2];
    const float* wbase = Whh + (size_t)nf * 12288;
#pragma unroll
    for (int g3 = 0; g3 < 3; ++g3)
#pragma unroll
        for (int k2 = 0; k2 < 2; ++k2) {
            int g = 64 * g3 + 16 * w + col;
            const float* src = wbase + g * 64 + 32 * k2 + quad * 8;
            float4 f0 = *(const float4*)src;
            float4 f1 = *(const float4*)(src + 4);
            short8v fr;
            fr[0] = tobf(f0.x); fr[1] = tobf(f0.y); fr[2] = tobf(f0.z); fr[3] = tobf(f0.w);
            fr[4] = tobf(f1.x); fr[5] = tobf(f1.y); fr[6] = tobf(f1.z); fr[7] = tobf(f1.w);
            bfr[g3][k2] = fr;
        }

    const int c = 16 * w + col;
    const int base = nf * 192;
    const float wr = Wih[base + c], wz = Wih[base + 64 + c], wn = Wih[base + 128 + c];
    const float br = bih[base + c] + bhh[base + c];
    const float bz = bih[base + 64 + c] + bhh[base + 64 + c];
    const float bnn = bih[base + 128 + c], bhn = bhh[base + 128 + c];

    for (int i = tid; i < 16 * 72; i += 256) As[0][i] = 0;
    float hold[4];
#pragma unroll
    for (int r = 0; r < 4; ++r) hold[r] = 0.0f;
    __syncthreads();

    const int crow = tid >> 4, cs = tid & 15;

    for (int t = 0; t < T_; ++t) {
        const int rb = t & 1;
        const int wb = 1 - rb;
        short8v A0 = *(const short8v*)&As[rb][col * 72 + quad * 8];
        short8v A1 = *(const short8v*)&As[rb][col * 72 + 32 + quad * 8];

        f32x4 acc[3];
#pragma unroll
        for (int g3 = 0; g3 < 3; ++g3) {
            f32x4 a = {0.0f, 0.0f, 0.0f, 0.0f};
            a = __builtin_amdgcn_mfma_f32_16x16x32_bf16(A0, bfr[g3][0], a, 0, 0, 0);
            a = __builtin_amdgcn_mfma_f32_16x16x32_bf16(A1, bfr[g3][1], a, 0, 0, 0);
            acc[g3] = a;
        }

#pragma unroll
        for (int r = 0; r < 4; ++r) {
            float xv = xs[(quad * 4 + r) * 129 + t];
            float rr = sigmf(xv * wr + br + acc[0][r]);
            float zz = sigmf(xv * wz + bz + acc[1][r]);
            float nn = tanh_fast(xv * wn + bnn + rr * (acc[2][r] + bhn));
            hold[r] = (1.0f - zz) * nn + zz * hold[r];
        }

#pragma unroll
        for (int r = 0; r < 4; ++r)
            As[wb][(quad * 4 + r) * 72 + c] = tobf(hold[r]);
        __syncthreads();
        {
            uint2 pk = *(const uint2*)&As[wb][crow * 72 + cs * 4];
            size_t go = (((size_t)nf * 128 + cbase + crow) * 128 + t) * 64 + cs * 4;
            *(uint2*)(Hsg + go) = pk;
        }
    }

#pragma unroll
    for (int r = 0; r < 4; ++r)
        q1[(quad * 4 + r) * 65 + c] = hold[r];
    __syncthreads();
    for (int o = tid; o < 16 * 64; o += 256) {
        int b = o >> 6, k = o & 63;
        const float* wrow = Wt + ((size_t)nf * 64 + k) * 64;
        float a = bt[nf * 64 + k];
#pragma unroll 8
        for (int h = 0; h < 64; h += 4) {
            float4 wv = *(const float4*)&wrow[h];
            a += q1[b * 65 + h] * wv.x + q1[b * 65 + h + 1] * wv.y
               + q1[b * 65 + h + 2] * wv.z + q1[b * 65 + h + 3] * wv.w;
        }
        q2[b * 65 + k] = a;
    }
    __syncthreads();
    for (int o = tid; o < 16 * 64; o += 256) {
        int b = o >> 6, h = o & 63;
        float a = 0.0f;
#pragma unroll 8
        for (int k = 0; k < 64; ++k)
            a += q2[b * 65 + k] * Wx[((size_t)nf * 64 + k) * 64 + h];
        qxg[((size_t)nf * 128 + cbase + b) * 64 + h] = a;
    }
    for (int b = tid; b < 16; b += 256) {
        float a = 0.0f;
        for (int k = 0; k < 64; ++k) a += q2[b * 65 + k] * bx[nf * 64 + k];
        qbg[nf * 128 + cbase + b] = a;
    }
}

// ---------------------------------------------------------------------------
// K1b: time attention + demo row + S/MU/counter zeroing. grid (77,128).
// ---------------------------------------------------------------------------
__global__ __launch_bounds__(128) void k_att(
    const short* __restrict__ Hsg, const float* __restrict__ qxg,
    const float* __restrict__ qbg, const float* __restrict__ rate,
    const float* __restrict__ D, const float* __restrict__ dW,
    const float* __restrict__ db, float* __restrict__ Sz,
    float* __restrict__ Fin)
{
    const int nf = blockIdx.x, b = blockIdx.y;
    const int tid = threadIdx.x;

    if (nf == NF) {
        if (tid < 64) {
            float acc = db[tid];
            for (int j = 0; j < 12; ++j) acc += D[b * 12 + j] * dW[tid * 12 + j];
            Fin[((size_t)b * LQ + 76) * HD + tid] = tanh_fast(acc);
        }
        int s0 = b * 33;
        for (int k = tid; k < 33; k += 128) {
            int idx = s0 + k;
            if (idx < 4161) Sz[idx] = 0.0f;
        }
        return;
    }

    __shared__ float wsum[128 * 69];
    __shared__ float wl[128];
    __shared__ float qxl[64];
    __shared__ float pn[2][68];
    __shared__ float pd[2];
    if (tid < 64) qxl[tid] = qxg[((size_t)nf * 128 + b) * 64 + tid];
    const float qb = qbg[nf * 128 + b];
    const float sigr = sigmf(rate[nf]);

    uint4 rv[8];
    const uint4* src = (const uint4*)(Hsg + (((size_t)nf * 128 + b) * 128 + tid) * 64);
#pragma unroll
    for (int k = 0; k < 8; ++k) rv[k] = src[k];
    __syncthreads();

    float a = qb;
#pragma unroll
    for (int k = 0; k < 8; ++k) {
        a += bflo(rv[k].x) * qxl[k * 8 + 0] + bfhi(rv[k].x) * qxl[k * 8 + 1]
           + bflo(rv[k].y) * qxl[k * 8 + 2] + bfhi(rv[k].y) * qxl[k * 8 + 3]
           + bflo(rv[k].z) * qxl[k * 8 + 4] + bfhi(rv[k].z) * qxl[k * 8 + 5]
           + bflo(rv[k].w) * qxl[k * 8 + 6] + bfhi(rv[k].w) * qxl[k * 8 + 7];
    }
    float ds = sigmf(a);
    float dn = fmaxf(sigr * __logf(2.72f + (1.0f - ds)) * (float)(tid + 1), 1e-6f);
    float e = fmaxf(ds * frcp(dn), 0.0f);
    float w = __expf(e);
    wl[tid] = w;
#pragma unroll
    for (int k = 0; k < 8; ++k) {
        float* d = &wsum[tid * 69 + k * 8];
        d[0] = w * bflo(rv[k].x); d[1] = w * bfhi(rv[k].x);
        d[2] = w * bflo(rv[k].y); d[3] = w * bfhi(rv[k].y);
        d[4] = w * bflo(rv[k].z); d[5] = w * bfhi(rv[k].z);
        d[6] = w * bflo(rv[k].w); d[7] = w * bfhi(rv[k].w);
    }
    __syncthreads();
    {
        int ch = tid & 63, half = tid >> 6;
        float acc = 0.0f, den = 0.0f;
        int t0 = half * 64;
        for (int t = t0; t < t0 + 64; ++t) {
            acc += wsum[t * 69 + ch];
            den += wl[t];
        }
        pn[half][ch] = acc;
        if (ch == 0) pd[half] = den;
    }
    __syncthreads();
    if (tid < 64) {
        float num = pn[0][tid] + pn[1][tid];
        float den = pd[0] + pd[1];
        Fin[((size_t)b * LQ + nf) * HD + tid] = num * frcp(den);
    }
}

// ---------------------------------------------------------------------------
// K4: MHA per (b, head, variant). grid (128,4,2), block 256.
// ---------------------------------------------------------------------------
__global__ __launch_bounds__(256) void k_mha2(
    const float* __restrict__ Fin,
    const float* __restrict__ Wq, const float* __restrict__ bq,
    const float* __restrict__ Wk, const float* __restrict__ bk,
    const float* __restrict__ Wv, const float* __restrict__ bv,
    const float* __restrict__ g1, const float* __restrict__ b1,
    float* __restrict__ M1, float* __restrict__ M2)
{
    __shared__ float xl[LQ * 68];       // later reused as os[231][17]
    __shared__ float qh[LQ * 20], kh[LQ * 20], vh[LQ * 20];
    float (*os)[17] = (float (*)[17])xl;
    const int b = blockIdx.x, hd = blockIdx.y, v = blockIdx.z;
    const int tid = threadIdx.x;
    const float* xsrc = Fin + (size_t)b * LQ * HD;

    for (int idx = tid; idx < LQ * HD; idx += 256)
        xl[(idx >> 6) * 68 + (idx & 63)] = xsrc[idx];
    __syncthreads();
    if (v == 1) {
        if (tid < LQ) {
            float mu = 0.0f;
            for (int h = 0; h < 64; ++h) mu += xl[tid * 68 + h];
            mu *= (1.0f / 64.0f);
            float var = 0.0f;
            for (int h = 0; h < 64; ++h) { float d = xl[tid * 68 + h] - mu; var += d * d; }
            var *= (1.0f / 64.0f);
            float rs = rsqrtf(var + 1e-7f);
            for (int h = 0; h < 64; ++h)
                xl[tid * 68 + h] = (xl[tid * 68 + h] - mu) * rs * g1[h] + b1[h];
        }
        __syncthreads();
    }

    for (int idx = tid; idx < LQ * 16; idx += 256) {
        int l = idx >> 4, d = idx & 15, ch = hd * 16 + d;
        float aq = bq[ch], ak = bk[ch], av = bv[ch];
        const float4* wq = (const float4*)(Wq + ch * 64);
        const float4* wk = (const float4*)(Wk + ch * 64);
        const float4* wv = (const float4*)(Wv + ch * 64);
        const float4* xr = (const float4*)&xl[l * 68];
#pragma unroll 4
        for (int c4 = 0; c4 < 16; ++c4) {
            float4 xv = xr[c4];
            float4 a = wq[c4], bb = wk[c4], cc = wv[c4];
            aq += xv.x * a.x + xv.y * a.y + xv.z * a.z + xv.w * a.w;
            ak += xv.x * bb.x + xv.y * bb.y + xv.z * bb.z + xv.w * bb.w;
            av += xv.x * cc.x + xv.y * cc.y + xv.z * cc.z + xv.w * cc.w;
        }
        qh[l * 20 + d] = aq; kh[l * 20 + d] = ak; vh[l * 20 + d] = av;
    }
    __syncthreads();   // QKV done; xl dead -> reuse as os

    if (tid < 231) {
        int l = tid % 77, third = tid / 77;
        float4 qf0 = *(const float4*)&qh[l * 20 + 0];
        float4 qf1 = *(const float4*)&qh[l * 20 + 4];
        float4 qf2 = *(const float4*)&qh[l * 20 + 8];
        float4 qf3 = *(const float4*)&qh[l * 20 + 12];
        int j0 = third * 26;
        int j1 = (third == 2) ? LQ : j0 + 26;
        float o[16];
#pragma unroll
        for (int d = 0; d < 16; ++d) o[d] = 0.0f;
        float ss = 0.0f;
        for (int j = j0; j < j1; ++j) {
            const float4* kp = (const float4*)&kh[j * 20];
            float4 k0 = kp[0], k1 = kp[1], k2 = kp[2], k3 = kp[3];
            float sc = qf0.x * k0.x + qf0.y * k0.y + qf0.z * k0.z + qf0.w * k0.w
                     + qf1.x * k1.x + qf1.y * k1.y + qf1.z * k1.z + qf1.w * k1.w
                     + qf2.x * k2.x + qf2.y * k2.y + qf2.z * k2.z + qf2.w * k2.w
                     + qf3.x * k3.x + qf3.y * k3.y + qf3.z * k3.z + qf3.w * k3.w;
            float p = __expf(sc * 0.25f);   // scores tiny: no max-shift
            ss += p;
            const float4* vp = (const float4*)&vh[j * 20];
            float4 v0 = vp[0], v1 = vp[1], v2 = vp[2], v3 = vp[3];
            o[0] += p * v0.x; o[1] += p * v0.y; o[2] += p * v0.z; o[3] += p * v0.w;
            o[4] += p * v1.x; o[5] += p * v1.y; o[6] += p * v1.z; o[7] += p * v1.w;
            o[8] += p * v2.x; o[9] += p * v2.y; o[10] += p * v2.z; o[11] += p * v2.w;
            o[12] += p * v3.x; o[13] += p * v3.y; o[14] += p * v3.z; o[15] += p * v3.w;
        }
#pragma unroll
        for (int d = 0; d < 16; ++d) os[tid][d] = o[d];
        os[tid][16] = ss;
    }
    __syncthreads();
    if (tid < LQ) {
        float inv = frcp(os[tid][16] + os[77 + tid][16] + os[154 + tid][16]);
        float* Mout = (v == 1) ? M2 : M1;
#pragma unroll
        for (int d = 0; d < 16; ++d)
            Mout[((size_t)b * LQ + tid) * HD + hd * 16 + d]
                = (os[tid][d] + os[77 + tid][d] + os[154 + tid][d]) * inv;
    }
}

// ---------------------------------------------------------------------------
// K5: row-parallel fused Y + LN2 + FFN + final-QKV + score. grid 616, block 256.
// ---------------------------------------------------------------------------
__global__ __launch_bounds__(256) void k_zff(
    const float* __restrict__ Fin, float* __restrict__ M2,
    const float* __restrict__ Wo, const float* __restrict__ bo,
    const float* __restrict__ g2, const float* __restrict__ b2,
    const float* __restrict__ W1, const float* __restrict__ bb1,
    const float* __restrict__ W2, const float* __restrict__ bb2,
    const float* __restrict__ faWq, const float* __restrict__ fabq,
    const float* __restrict__ faWk, const float* __restrict__ fabk,
    const float* __restrict__ faWv, const float* __restrict__ fabv,
    const float* __restrict__ faWout, const float* __restrict__ fabout,
    float* __restrict__ scout)
{
    __shared__ float m2l[16 * 68];
    __shared__ float yl[16 * 68];
    __shared__ float zl[16 * 68];
    __shared__ float ul[16 * 260];
    const int tid = threadIdx.x;
    const size_t base = (size_t)blockIdx.x * 16;
    const size_t eb = base * 64;
    const int h = tid & 63, rq = tid >> 6;

    for (int idx = tid; idx < 1024; idx += 256)
        m2l[(idx >> 6) * 68 + (idx & 63)] = M2[eb + idx];
    __syncthreads();

    {
        float acc[4];
#pragma unroll
        for (int rr = 0; rr < 4; ++rr) acc[rr] = bo[h];
        const float4* wo = (const float4*)(Wo + h * 64);
#pragma unroll 4
        for (int c4 = 0; c4 < 16; ++c4) {
            float4 wv = wo[c4];
#pragma unroll
            for (int rr = 0; rr < 4; ++rr) {
                float4 mv = *(const float4*)&m2l[(rq * 4 + rr) * 68 + c4 * 4];
                acc[rr] += mv.x * wv.x + mv.y * wv.y + mv.z * wv.z + mv.w * wv.w;
            }
        }
#pragma unroll
        for (int rr = 0; rr < 4; ++rr) {
            int r = rq * 4 + rr;
            yl[r * 68 + h] = Fin[eb + r * 64 + h] + acc[rr];
        }
    }
    __syncthreads();
    if (tid < 16) {
        float mu = 0.0f;
        for (int c = 0; c < 64; ++c) mu += yl[tid * 68 + c];
        mu *= (1.0f / 64.0f);
        float var = 0.0f;
        for (int c = 0; c < 64; ++c) { float d = yl[tid * 68 + c] - mu; var += d * d; }
        var *= (1.0f / 64.0f);
        float rs = rsqrtf(var + 1e-7f);
        for (int c = 0; c < 64; ++c)
            zl[tid * 68 + c] = (yl[tid * 68 + c] - mu) * rs * g2[c] + b2[c];
    }
    __syncthreads();

    {
        const int f = tid;
        float acc[16];
#pragma unroll
        for (int r = 0; r < 16; ++r) acc[r] = bb1[f];
        const float4* w1r = (const float4*)(W1 + f * 64);
#pragma unroll
        for (int c = 0; c < 4; ++c) {
            float4 w0 = w1r[c * 4 + 0], w1 = w1r[c * 4 + 1];
            float4 w2 = w1r[c * 4 + 2], w3 = w1r[c * 4 + 3];
#pragma unroll
            for (int r = 0; r < 16; ++r) {
                const float4* zr = (const float4*)&zl[r * 68 + c * 16];
                float4 z0 = zr[0], z1 = zr[1], z2 = zr[2], z3 = zr[3];
                acc[r] += z0.x * w0.x + z0.y * w0.y + z0.z * w0.z + z0.w * w0.w
                        + z1.x * w1.x + z1.y * w1.y + z1.z * w1.z + z1.w * w1.w
                        + z2.x * w2.x + z2.y * w2.y + z2.z * w2.z + z2.w * w2.w
                        + z3.x * w3.x + z3.y * w3.y + z3.z * w3.z + z3.w * w3.w;
            }
        }
#pragma unroll
        for (int r = 0; r < 16; ++r) ul[r * 260 + f] = fmaxf(acc[r], 0.0f);
    }
    __syncthreads();
    {
        float acc[4];
#pragma unroll
        for (int rr = 0; rr < 4; ++rr) acc[rr] = bb2[h];
        const float4* w2r = (const float4*)(W2 + h * 256);
#pragma unroll 4
        for (int c = 0; c < 16; ++c) {
            float4 w0 = w2r[c * 4 + 0], w1 = w2r[c * 4 + 1];
            float4 w2 = w2r[c * 4 + 2], w3 = w2r[c * 4 + 3];
#pragma unroll
            for (int rr = 0; rr < 4; ++rr) {
                const float4* ur = (const float4*)&ul[(rq * 4 + rr) * 260 + c * 16];
                float4 u0 = ur[0], u1 = ur[1], u2 = ur[2], u3 = ur[3];
                acc[rr] += u0.x * w0.x + u0.y * w0.y + u0.z * w0.z + u0.w * w0.w
                         + u1.x * w1.x + u1.y * w1.y + u1.z * w1.z + u1.w * w1.w
                         + u2.x * w2.x + u2.y * w2.y + u2.z * w2.z + u2.w * w2.w
                         + u3.x * w3.x + u3.y * w3.y + u3.z * w3.z + u3.w * w3.w;
            }
        }
#pragma unroll
        for (int rr = 0; rr < 4; ++rr)
            yl[(rq * 4 + rr) * 68 + h] += acc[rr];
    }
    __syncthreads();

    {
        const float4* wq = (const float4*)(faWq + h * 64);
        const float4* wk = (const float4*)(faWk + h * 64);
        const float4* wv = (const float4*)(faWv + h * 64);
        float q[4], k[4], v[4];
#pragma unroll
        for (int rr = 0; rr < 4; ++rr) { q[rr] = fabq[h]; k[rr] = fabk[h]; v[rr] = fabv[h]; }
#pragma unroll 4
        for (int c4 = 0; c4 < 16; ++c4) {
            float4 a = wq[c4], bb = wk[c4], cc = wv[c4];
#pragma unroll
            for (int rr = 0; rr < 4; ++rr) {
                float4 zv = *(const float4*)&yl[(rq * 4 + rr) * 68 + c4 * 4];
                q[rr] += zv.x * a.x + zv.y * a.y + zv.z * a.z + zv.w * a.w;
                k[rr] += zv.x * bb.x + zv.y * bb.y + zv.z * bb.z + zv.w * bb.w;
                v[rr] += zv.x * cc.x + zv.y * cc.y + zv.z * cc.z + zv.w * cc.w;
            }
        }
        float fw = faWout[h];
#pragma unroll
        for (int rr = 0; rr < 4; ++rr) {
            int r = rq * 4 + rr;
            ul[r * 68 + h] = q[rr] * k[rr] * fw;
            M2[eb + r * 64 + h] = v[rr];
        }
    }
    __syncthreads();
    if (tid < 16) {
        float a = fabout[0];
        for (int c = 0; c < 64; ++c) a += ul[tid * 68 + c];
        scout[base + tid] = a;
    }
}

// ---------------------------------------------------------------------------
// K6: covariance via LDS-staged tiles + last-block decov. grid (16,32),
// block 256 (2 blocks/CU; pipelined LDS reads instead of dependent global
// loads at 1 wave/SIMD — the R10 k_cov latency pathology).
// ---------------------------------------------------------------------------
__global__ __launch_bounds__(256) void k_cov(
    const float* __restrict__ M1, float* __restrict__ S, float* __restrict__ MU,
    unsigned* __restrict__ cnt, float* __restrict__ out)
{
    __shared__ float tile[64 * 64];
    const int tid = threadIdx.x;
    const int ig = tid >> 6, j = tid & 63;
    const int i = blockIdx.x * 4 + ig;
    const int l0 = blockIdx.y * 308;           // 32 * 308 = 9856
    float acc = 0.0f, mua = 0.0f;
    for (int c0 = 0; c0 < 308; c0 += 64) {
        int rows = (308 - c0 < 64) ? (308 - c0) : 64;
        __syncthreads();
        const float4* gsrc = (const float4*)(M1 + (size_t)(l0 + c0) * 64);
        for (int idx = tid; idx < rows * 16; idx += 256)
            *(float4*)&tile[idx * 4] = gsrc[idx];
        __syncthreads();
#pragma unroll 4
        for (int l = 0; l < rows; ++l) {
            float v = tile[l * 64 + j];
            acc += tile[l * 64 + i] * v;       // i uniform per 64-group: broadcast
            mua += v;
        }
    }
    atomicAdd(&S[i * 64 + j], acc);
    if (blockIdx.x == 0 && ig == 0) atomicAdd(&MU[j], mua);
    __threadfence();
    __syncthreads();
    __shared__ unsigned lastf;
    if (tid == 0) lastf = (atomicAdd(cnt, 1u) == 511u);
    __syncthreads();
    if (lastf) {
        __shared__ float mus[64];
        __shared__ float pa[4], pd[4];
        if (tid < 64) mus[tid] = atomicAdd(&MU[tid], 0.0f);
        __syncthreads();
        const float invM = 1.0f / 9856.0f;
        float asum = 0.0f, dsum = 0.0f;
        for (int idx = tid; idx < 4096; idx += 256) {
            int ii = idx >> 6, jj = idx & 63;
            float c = atomicAdd(&S[idx], 0.0f) * invM - (mus[ii] * invM) * (mus[jj] * invM);
            asum += c * c;
            if (ii == jj) dsum += c * c;
        }
        for (int o = 32; o; o >>= 1) {
            asum += __shfl_xor(asum, o, 64);
            dsum += __shfl_xor(dsum, o, 64);
        }
        if ((tid & 63) == 0) { pa[tid >> 6] = asum; pd[tid >> 6] = dsum; }
        __syncthreads();
        if (tid == 0)
            out[128] = 0.5f * ((pa[0] + pa[1] + pa[2] + pa[3])
                             - (pd[0] + pd[1] + pd[2] + pd[3]));
    }
}

// ---------------------------------------------------------------------------
// K7: final softmax + s = alpha.V + output head. grid 128, block 128.
// ---------------------------------------------------------------------------
__global__ __launch_bounds__(128) void k_head(
    const float* __restrict__ Vg, const float* __restrict__ scout,
    const float* __restrict__ o0W, const float* __restrict__ o0b,
    const float* __restrict__ o1W, const float* __restrict__ o1b,
    float* __restrict__ out)
{
    __shared__ float sl[LQ + 3];
    __shared__ float pn[2][64];
    __shared__ float sv[64], h1[64];
    __shared__ float red0;
    const int b = blockIdx.x, tid = threadIdx.x;

    if (tid < LQ) sl[tid] = scout[b * LQ + tid];
    __syncthreads();
    if (tid < 64) {
        float v0 = sl[tid];
        float v1 = (tid < LQ - 64) ? sl[tid + 64] : -1e30f;
        float m = fmaxf(v0, v1);
        for (int o = 32; o; o >>= 1) m = fmaxf(m, __shfl_xor(m, o, 64));
        float e0 = __expf(v0 - m);
        float e1 = (tid < LQ - 64) ? __expf(v1 - m) : 0.0f;
        float s = e0 + e1;
        for (int o = 32; o; o >>= 1) s += __shfl_xor(s, o, 64);
        sl[tid] = e0;
        if (tid < LQ - 64) sl[tid + 64] = e1;
        if (tid == 0) red0 = s;
    }
    __syncthreads();
    {
        int h = tid & 63, half = tid >> 6;
        int l0 = half ? 39 : 0, l1 = half ? LQ : 39;
        float acc = 0.0f;
#pragma unroll 4
        for (int l = l0; l < l1; ++l)
            acc += sl[l] * Vg[((size_t)b * LQ + l) * 64 + h];
        pn[half][h] = acc;
    }
    __syncthreads();
    if (tid < 64) sv[tid] = (pn[0][tid] + pn[1][tid]) * frcp(red0);
    __syncthreads();
    if (tid < 64) {
        float acc = o0b[tid];
        const float4* w = (const float4*)(o0W + tid * 64);
#pragma unroll 4
        for (int c4 = 0; c4 < 16; ++c4) {
            float4 wv = w[c4];
            const float4* sp = (const float4*)&sv[c4 * 4];
            float4 s0 = sp[0];
            acc += s0.x * wv.x + s0.y * wv.y + s0.z * wv.z + s0.w * wv.w;
        }
        h1[tid] = fmaxf(acc, 0.0f);
    }
    __syncthreads();
    if (tid < 64) {
        float p = h1[tid] * o1W[tid];
        for (int o = 32; o; o >>= 1) p += __shfl_xor(p, o, 64);
        if (tid == 0) out[b] = sigmf(p + o1b[0]);
    }
}

// ---------------------------------------------------------------------------
// Fallback path kernels (ws too small).
// ---------------------------------------------------------------------------
__global__ void k_demo(const float* __restrict__ D, const float* __restrict__ dW,
                       const float* __restrict__ db, float* __restrict__ Fin)
{
    int b = blockIdx.x, h = threadIdx.x;
    float acc = db[h];
    for (int j = 0; j < 12; ++j) acc += D[b * 12 + j] * dW[h * 12 + j];
    Fin[((size_t)b * LQ + 76) * HD + h] = tanh_fast(acc);
}

__global__ void k_zero(float* __restrict__ p)
{
    for (int i = threadIdx.x; i < 4161; i += 256) p[i] = 0.0f;
}

__global__ __launch_bounds__(128) void k_gru_mfma(
    const float* __restrict__ X, const float* __restrict__ Wih,
    const float* __restrict__ Whh, const float* __restrict__ bih,
    const float* __restrict__ bhh,
    const float* __restrict__ Wt, const float* __restrict__ bt,
    const float* __restrict__ Wx, const float* __restrict__ bx,
    const float* __restrict__ rate, float* __restrict__ Fin)
{
    __shared__ short As[2][16 * 68];
    __shared__ float xs[16 * 129];
    __shared__ float q1[16 * 65];
    __shared__ float q2[16 * 65];
    __shared__ float qbs[16];
    __shared__ float dotw[2][2][16];

    const int nf = blockIdx.y;
    const int cbase = blockIdx.x * 16;
    const int tid = threadIdx.x;
    const int w = tid >> 6;
    const int lane = tid & 63;
    const int col = lane & 15;
    const int quad = lane >> 4;

    for (int i = tid; i < 16 * T_; i += 128) {
        int b = i >> 7, t = i & 127;
        xs[b * 129 + t] = X[((size_t)(cbase + b) * T_ + t) * NF + nf];
    }
    short8v bfr[3][2][2];
    const float* wbase = Whh + (size_t)nf * 12288;
#pragma unroll
    for (int g3 = 0; g3 < 3; ++g3)
#pragma unroll
        for (int s = 0; s < 2; ++s)
#pragma unroll
            for (int k2 = 0; k2 < 2; ++k2) {
                int g = 64 * g3 + 32 * w + 16 * s + col;
                const float* src = wbase + g * 64 + 32 * k2 + quad * 8;
                float4 f0 = *(const float4*)src;
                float4 f1 = *(const float4*)(src + 4);
                short8v fr;
                fr[0] = tobf(f0.x); fr[1] = tobf(f0.y); fr[2] = tobf(f0.z); fr[3] = tobf(f0.w);
                fr[4] = tobf(f1.x); fr[5] = tobf(f1.y); fr[6] = tobf(f1.z); fr[7] = tobf(f1.w);
                bfr[g3][s][k2] = fr;
            }
    float wr[2], wz[2], wn[2], br[2], bz[2], bnn[2], bhn[2];
#pragma unroll
    for (int s = 0; s < 2; ++s) {
        int c = 32 * w + 16 * s + col;
        int base = nf * 192;
        wr[s] = Wih[base + c]; wz[s] = Wih[base + 64 + c]; wn[s] = Wih[base + 128 + c];
        br[s] = bih[base + c] + bhh[base + c];
        bz[s] = bih[base + 64 + c] + bhh[base + 64 + c];
        bnn[s] = bih[base + 128 + c]; bhn[s] = bhh[base + 128 + c];
    }
    const float sigr = sigmf(rate[nf]);
    float hold[2][4], num[2][4], den[4], qxv[2][4], qbv[4];
#pragma unroll
    for (int r = 0; r < 4; ++r) {
        den[r] = 0.0f; qbv[r] = 0.0f;
        num[0][r] = 0.0f; num[1][r] = 0.0f;
        qxv[0][r] = 0.0f; qxv[1][r] = 0.0f;
    }
    for (int pass = 0; pass < 2; ++pass) {
        for (int i = tid; i < 16 * 68; i += 128) As[0][i] = 0;
#pragma unroll
        for (int s = 0; s < 2; ++s)
#pragma unroll
            for (int r = 0; r < 4; ++r) hold[s][r] = 0.0f;
        __syncthreads();
        for (int t = 0; t < T_; ++t) {
            const int rb = t & 1;
            const int wb = 1 - rb;
            const short* ap = &As[rb][col * 68 + quad * 8];
            short4v a0 = *(const short4v*)ap;
            short4v a1 = *(const short4v*)(ap + 4);
            short4v a2 = *(const short4v*)(ap + 32);
            short4v a3 = *(const short4v*)(ap + 36);
            short8v A0 = {a0[0], a0[1], a0[2], a0[3], a1[0], a1[1], a1[2], a1[3]};
            short8v A1 = {a2[0], a2[1], a2[2], a2[3], a3[0], a3[1], a3[2], a3[3]};
            f32x4 acc[3][2];
#pragma unroll
            for (int g3 = 0; g3 < 3; ++g3)
#pragma unroll
                for (int s = 0; s < 2; ++s) {
                    f32x4 a = {0.0f, 0.0f, 0.0f, 0.0f};
                    a = __builtin_amdgcn_mfma_f32_16x16x32_bf16(A0, bfr[g3][s][0], a, 0, 0, 0);
                    a = __builtin_amdgcn_mfma_f32_16x16x32_bf16(A1, bfr[g3][s][1], a, 0, 0, 0);
                    acc[g3][s] = a;
                }
            float xv[4];
#pragma unroll
            for (int r = 0; r < 4; ++r) xv[r] = xs[(quad * 4 + r) * 129 + t];
            float hnew[2][4];
#pragma unroll
            for (int s = 0; s < 2; ++s)
#pragma unroll
                for (int r = 0; r < 4; ++r) {
                    float rr = sigmf(xv[r] * wr[s] + br[s] + acc[0][s][r]);
                    float zz = sigmf(xv[r] * wz[s] + bz[s] + acc[1][s][r]);
                    float nn = tanh_fast(xv[r] * wn[s] + bnn[s] + rr * (acc[2][s][r] + bhn[s]));
                    hnew[s][r] = (1.0f - zz) * nn + zz * hold[s][r];
                    hold[s][r] = hnew[s][r];
                }
#pragma unroll
            for (int s = 0; s < 2; ++s)
#pragma unroll
                for (int r = 0; r < 4; ++r)
                    As[wb][(quad * 4 + r) * 68 + 32 * w + 16 * s + col] = tobf(hnew[s][r]);
            if (pass == 1) {
                float p[4];
#pragma unroll
                for (int r = 0; r < 4; ++r)
                    p[r] = qxv[0][r] * hnew[0][r] + qxv[1][r] * hnew[1][r];
#pragma unroll
                for (int m = 1; m < 16; m <<= 1) {
                    p[0] += __shfl_xor(p[0], m, 64);
                    p[1] += __shfl_xor(p[1], m, 64);
                    p[2] += __shfl_xor(p[2], m, 64);
                    p[3] += __shfl_xor(p[3], m, 64);
                }
                if (col == 0) {
#pragma unroll
                    for (int r = 0; r < 4; ++r) dotw[rb][w][quad * 4 + r] = p[r];
                }
                __syncthreads();
                float tf = (float)(t + 1);
#pragma unroll
                for (int r = 0; r < 4; ++r) {
                    float dot = p[r] + dotw[rb][1 - w][quad * 4 + r] + qbv[r];
                    float ds = sigmf(dot);
                    float dn = fmaxf(sigr * __logf(2.72f + (1.0f - ds)) * tf, 1e-6f);
                    float e = fmaxf(ds * frcp(dn), 0.0f);
                    float wt = __expf(e);
                    den[r] += wt;
                    num[0][r] += wt * hnew[0][r];
                    num[1][r] += wt * hnew[1][r];
                }
            } else {
                __syncthreads();
            }
        }
        if (pass == 0) {
#pragma unroll
            for (int s = 0; s < 2; ++s)
#pragma unroll
                for (int r = 0; r < 4; ++r)
                    q1[(quad * 4 + r) * 65 + 32 * w + 16 * s + col] = hold[s][r];
            __syncthreads();
            for (int o = tid; o < 16 * 64; o += 128) {
                int b = o >> 6, k = o & 63;
                const float* wrow = Wt + ((size_t)nf * 64 + k) * 64;
                float a = bt[nf * 64 + k];
#pragma unroll 8
                for (int h = 0; h < 64; h += 4) {
                    float4 wv = *(const float4*)&wrow[h];
                    a += q1[b * 65 + h] * wv.x + q1[b * 65 + h + 1] * wv.y
                       + q1[b * 65 + h + 2] * wv.z + q1[b * 65 + h + 3] * wv.w;
                }
                q2[b * 65 + k] = a;
            }
            __syncthreads();
            for (int o = tid; o < 16 * 64; o += 128) {
                int b = o >> 6, h = o & 63;
                float a = 0.0f;
#pragma unroll 8
                for (int k = 0; k < 64; ++k)
                    a += q2[b * 65 + k] * Wx[((size_t)nf * 64 + k) * 64 + h];
                q1[b * 65 + h] = a;
            }
            for (int b = tid; b < 16; b += 128) {
                float a = 0.0f;
                for (int k = 0; k < 64; ++k) a += q2[b * 65 + k] * bx[nf * 64 + k];
                qbs[b] = a;
            }
            __syncthreads();
#pragma unroll
            for (int r = 0; r < 4; ++r) {
                qbv[r] = qbs[quad * 4 + r];
#pragma unroll
                for (int s = 0; s < 2; ++s)
                    qxv[s][r] = q1[(quad * 4 + r) * 65 + 32 * w + 16 * s + col];
                den[r] = 0.0f; num[0][r] = 0.0f; num[1][r] = 0.0f;
            }
            __syncthreads();
        }
    }
#pragma unroll
    for (int s = 0; s < 2; ++s)
#pragma unroll
        for (int r = 0; r < 4; ++r) {
            int b = cbase + quad * 4 + r;
            int c = 32 * w + 16 * s + col;
            Fin[((size_t)b * LQ + nf) * HD + c] = num[s][r] * frcp(den[r]);
        }
}

extern "C" void kernel_launch(void* const* d_in, const int* in_sizes, int n_in,
                              void* d_out, int out_size, void* d_ws, size_t ws_size,
                              hipStream_t stream)
{
    (void)in_sizes; (void)n_in; (void)out_size;
    const float* X     = (const float*)d_in[0];
    const float* D     = (const float*)d_in[1];
    const float* gWih  = (const float*)d_in[2];
    const float* gWhh  = (const float*)d_in[3];
    const float* gbih  = (const float*)d_in[4];
    const float* gbhh  = (const float*)d_in[5];
    const float* aWt   = (const float*)d_in[6];
    const float* abt   = (const float*)d_in[7];
    const float* aWx   = (const float*)d_in[8];
    const float* abx   = (const float*)d_in[9];
    const float* arate = (const float*)d_in[10];
    const float* dW    = (const float*)d_in[11];
    const float* db    = (const float*)d_in[12];
    const float* mWq   = (const float*)d_in[13]; const float* mbq = (const float*)d_in[14];
    const float* mWk   = (const float*)d_in[15]; const float* mbk = (const float*)d_in[16];
    const float* mWv   = (const float*)d_in[17]; const float* mbv = (const float*)d_in[18];
    const float* mWo   = (const float*)d_in[19]; const float* mbo = (const float*)d_in[20];
    const float* l1g   = (const float*)d_in[21]; const float* l1b = (const float*)d_in[22];
    const float* fW1   = (const float*)d_in[23]; const float* fb1 = (const float*)d_in[24];
    const float* fW2   = (const float*)d_in[25]; const float* fb2 = (const float*)d_in[26];
    const float* l2g   = (const float*)d_in[27]; const float* l2b = (const float*)d_in[28];
    const float* faWq  = (const float*)d_in[29]; const float* fabq = (const float*)d_in[30];
    const float* faWk  = (const float*)d_in[31]; const float* fabk = (const float*)d_in[32];
    const float* faWv  = (const float*)d_in[33]; const float* fabv = (const float*)d_in[34];
    const float* faWo  = (const float*)d_in[35]; const float* fabo = (const float*)d_in[36];
    const float* o0W   = (const float*)d_in[37]; const float* o0b  = (const float*)d_in[38];
    const float* o1W   = (const float*)d_in[39]; const float* o1b  = (const float*)d_in[40];

    float* ws  = (float*)d_ws;
    float* Fin = ws;                               // 630,784
    float* M1  = Fin + 630784;                     // 630,784
    float* M2  = M1  + 630784;                     // 630,784 (later reused as V)
    float* S   = M2  + 630784;                     // 4096
    float* MU  = S   + 4096;                       // 64
    unsigned* cnt = (unsigned*)(MU + 64);          // 1 (+63 pad)
    float* qxg = MU + 128;                         // 622,592
    float* scout = qxg + 622592;                   // 9,856 (also used as qbg)
    short* Hsg = (short*)(scout + 9856);           // 79,691,776 shorts (bf16)
    const size_t need = (size_t)(630784 * 3 + 4096 + 128 + 622592 + 9856) * 4
                        + (size_t)79691776 * 2;
    float* outp = (float*)d_out;
    float* qbg = scout;                            // alias: qbg consumed before scout written

    if (ws_size >= need) {
        k_gru0<<<dim3(8, NF), 256, 0, stream>>>(X, gWih, gWhh, gbih, gbhh,
                                                aWt, abt, aWx, abx, Hsg, qxg, qbg);
        k_att<<<dim3(NF + 1, B_), 128, 0, stream>>>(Hsg, qxg, qbg, arate,
                                                    D, dW, db, S, Fin);
    } else {
        k_gru_mfma<<<dim3(8, NF), 128, 0, stream>>>(X, gWih, gWhh, gbih, gbhh,
                                                    aWt, abt, aWx, abx, arate, Fin);
        k_demo<<<B_, 64, 0, stream>>>(D, dW, db, Fin);
        k_zero<<<1, 256, 0, stream>>>(S);
    }
    k_mha2<<<dim3(B_, 4, 2), 256, 0, stream>>>(Fin, mWq, mbq, mWk, mbk, mWv, mbv,
                                               l1g, l1b, M1, M2);
    k_zff<<<616, 256, 0, stream>>>(Fin, M2, mWo, mbo, l2g, l2b,
                                   fW1, fb1, fW2, fb2,
                                   faWq, fabq, faWk, fabk, faWv, fabv,
                                   faWo, fabo, scout);
    k_cov<<<dim3(16, 32), 256, 0, stream>>>(M1, S, MU, cnt, outp);
    k_head<<<B_, 128, 0, stream>>>(M2, scout, o0W, o0b, o1W, o1b, outp);
}